// Round 1
// baseline (3762.065 us; speedup 1.0000x reference)
//
#include <hip/hip_runtime.h>
#include <math.h>

#define NB 512
#define LIN 640
#define NLEADS 3
#define L1O 322
#define L2O 161
#define L3O 79
#define C1N 64
#define C2N 128
#define C3N 256
#define FLATSZ 20224   // 256*79
#define NUMK 100
#define DIMK 5

__device__ __forceinline__ float block_reduce_sum(float val, float* red){
#pragma unroll
  for(int off=32; off>0; off>>=1) val += __shfl_down(val, off, 64);
  int lane = threadIdx.x & 63;
  int wv = threadIdx.x >> 6;
  if(lane==0) red[wv] = val;
  __syncthreads();
  int nw = blockDim.x >> 6;
  float r = red[0];
  for(int i=1;i<nw;i++) r += red[i];
  __syncthreads();
  return r;
}

// ---------- spectral norm: scale[b] = 1/sigma for each conv weight ----------
__global__ void sn_kernel(const float* __restrict__ w1, const float* __restrict__ u1,
                          const float* __restrict__ w2, const float* __restrict__ u2,
                          const float* __restrict__ w3, const float* __restrict__ u3,
                          float* __restrict__ scale){
  __shared__ float v[1152];
  __shared__ float red[4];
  const float* w; const float* u; int O, C;
  if(blockIdx.x==0){ w=w1; u=u1; O=64;  C=15;   }
  else if(blockIdx.x==1){ w=w2; u=u2; O=128; C=448;  }
  else { w=w3; u=u3; O=256; C=1152; }
  int tid = threadIdx.x;
  float ss = 0.f;
  for(int c=tid;c<C;c+=256){
    float s = 0.f;
    for(int o=0;o<O;o++) s += w[o*C+c]*u[o];
    v[c] = s; ss += s*s;
  }
  ss = block_reduce_sum(ss, red);
  float inv_nv = 1.f/(sqrtf(ss)+1e-12f);
  float S = 0.f;
  for(int o=tid;o<O;o+=256){
    float t = 0.f;
    for(int c=0;c<C;c++) t += w[o*C+c]*v[c];
    t *= inv_nv;
    S += t*t;
  }
  S = block_reduce_sum(S, red);
  // sigma = S/(sqrt(S)+eps)  ->  1/sigma = (sqrt(S)+eps)/S
  if(tid==0) scale[blockIdx.x] = (sqrtf(S)+1e-12f)/S;
}

// ---------- conv1: (NB,3,640) -> (NB,64,322), stride2 pad4 K5, leaky ----------
__global__ void conv1_kernel(const float* __restrict__ ecg, const float* __restrict__ w1,
                             const float* __restrict__ b1, const float* __restrict__ scale,
                             float* __restrict__ y1){
  __shared__ float xs[NLEADS*LIN];
  __shared__ float wsh[C1N*15];
  __shared__ float bsh[C1N];
  int n = blockIdx.x, tid = threadIdx.x;
  float s = scale[0];
  for(int idx=tid; idx<NLEADS*LIN; idx+=256){
    int lead = idx/LIN, l = idx-lead*LIN;
    // ecg layout (N, L, LEADS)
    xs[idx] = ecg[(n*LIN + l)*NLEADS + lead];
  }
  for(int idx=tid; idx<C1N*15; idx+=256) wsh[idx] = w1[idx]*s;
  if(tid<C1N) bsh[tid] = b1[tid];
  __syncthreads();
  for(int idx=tid; idx<C1N*L1O; idx+=256){
    int o = idx/L1O, t = idx-o*L1O;
    float acc = 0.f;
    int base = 2*t - 4;
#pragma unroll
    for(int i=0;i<NLEADS;i++){
#pragma unroll
      for(int k=0;k<5;k++){
        int p = base+k;
        if((unsigned)p < (unsigned)LIN) acc += xs[i*LIN+p]*wsh[o*15+i*5+k];
      }
    }
    acc += bsh[o];
    y1[(n*C1N+o)*L1O + t] = acc>=0.f ? acc : 0.2f*acc;
  }
}

// ---------- conv2: (NB,64,322) -> (NB,128,161), stride2 pad3 K7, leaky ----------
#define C2W 167
__global__ void conv2_kernel(const float* __restrict__ y1, const float* __restrict__ w2,
                             const float* __restrict__ b2, const float* __restrict__ scale,
                             float* __restrict__ y2){
  __shared__ float xs[C1N*C2W + 8];
  int n = blockIdx.x, tile = blockIdx.y, tid = threadIdx.x;
  int t0 = tile*81;
  int TT = tile ? 80 : 81;
  int W = 2*TT + 5;           // max input cols needed for this tile
  float s = scale[1];
  for(int idx=tid; idx<C1N*W; idx+=256){
    int i = idx/W, c = idx - i*W;
    int p = 2*t0 - 3 + c;
    xs[i*C2W + c] = ((unsigned)p < (unsigned)L1O) ? y1[(n*C1N+i)*L1O + p] : 0.f;
  }
  __syncthreads();
  int groups = (TT+3)>>2;
  for(int idx=tid; idx<C2N*groups; idx+=256){
    int o = idx/groups, g = idx - o*groups;
    int tt0 = g*4;
    float a0=0.f,a1=0.f,a2=0.f,a3=0.f;
    const float* wo = w2 + o*(C1N*7);
    for(int i=0;i<C1N;i++){
      const float* xr = xs + i*C2W + 2*tt0;
      const float* wi = wo + i*7;
#pragma unroll
      for(int k=0;k<7;k++){
        float wv = wi[k];
        a0 += wv*xr[k];
        a1 += wv*xr[k+2];
        a2 += wv*xr[k+4];
        a3 += wv*xr[k+6];
      }
    }
    float b = b2[o];
    int t = t0 + tt0;
    float* yo = y2 + (size_t)(n*C2N+o)*L2O + t;
    float r0 = a0*s + b, r1 = a1*s + b, r2 = a2*s + b, r3 = a3*s + b;
    if(tt0   < TT) yo[0] = r0>=0.f?r0:0.2f*r0;
    if(tt0+1 < TT) yo[1] = r1>=0.f?r1:0.2f*r1;
    if(tt0+2 < TT) yo[2] = r2>=0.f?r2:0.2f*r2;
    if(tt0+3 < TT) yo[3] = r3>=0.f?r3:0.2f*r3;
  }
}

// ---------- conv3: (NB,128,161) -> flat (NB, 256*79), stride2 pad2 K9, leaky ----------
#define C3W 87
__global__ void conv3_kernel(const float* __restrict__ y2, const float* __restrict__ w3,
                             const float* __restrict__ b3, const float* __restrict__ scale,
                             float* __restrict__ flat){
  __shared__ float xs[C2N*C3W + 8];
  int n = blockIdx.x, tile = blockIdx.y, tid = threadIdx.x;
  int t0 = tile*40;
  int TT = tile ? 39 : 40;
  int W = 2*TT + 7;
  float s = scale[2];
  for(int idx=tid; idx<C2N*W; idx+=256){
    int i = idx/W, c = idx - i*W;
    int p = 2*t0 - 2 + c;
    xs[i*C3W + c] = ((unsigned)p < (unsigned)L2O) ? y2[(size_t)(n*C2N+i)*L2O + p] : 0.f;
  }
  __syncthreads();
  const int groups = 10;
  for(int idx=tid; idx<C3N*groups; idx+=256){
    int o = idx/groups, g = idx - o*groups;
    int tt0 = g*4;
    float a0=0.f,a1=0.f,a2=0.f,a3=0.f;
    const float* wo = w3 + o*(C2N*9);
    for(int i=0;i<C2N;i++){
      const float* xr = xs + i*C3W + 2*tt0;
      const float* wi = wo + i*9;
#pragma unroll
      for(int k=0;k<9;k++){
        float wv = wi[k];
        a0 += wv*xr[k];
        a1 += wv*xr[k+2];
        a2 += wv*xr[k+4];
        a3 += wv*xr[k+6];
      }
    }
    float b = b3[o];
    int t = t0 + tt0;
    float* yo = flat + (size_t)n*FLATSZ + o*L3O + t;
    float r0 = a0*s + b, r1 = a1*s + b, r2 = a2*s + b, r3 = a3*s + b;
    if(tt0   < TT) yo[0] = r0>=0.f?r0:0.2f*r0;
    if(tt0+1 < TT) yo[1] = r1>=0.f?r1:0.2f*r1;
    if(tt0+2 < TT) yo[2] = r2>=0.f?r2:0.2f*r2;
    if(tt0+3 < TT) yo[3] = r3>=0.f?r3:0.2f*r3;
  }
}

// ---------- act = flat @ mb_w : (512 x 20224) @ (20224 x 500) ----------
__global__ void mb_gemm_kernel(const float* __restrict__ flat, const float* __restrict__ mbw,
                               float* __restrict__ act){
  __shared__ float As[32][34];  // [k][m] transposed, padded
  __shared__ float Bs[32][64];  // [k][n]
  int tid = threadIdx.x;
  int m0 = blockIdx.x*32, n0 = blockIdx.y*64;
  int tx = tid & 15, ty = tid >> 4;
  float acc[2][4] = {{0.f,0.f,0.f,0.f},{0.f,0.f,0.f,0.f}};
  int arow = tid >> 3;          // 0..31 (m)
  int acol = (tid & 7) * 4;     // k offset
  int brow = tid >> 4;          // 0..15 (k)
  int bcol = (tid & 15) * 4;    // n offset
  for(int k0=0; k0<FLATSZ; k0+=32){
    __syncthreads();
    float4 av = *(const float4*)(flat + (size_t)(m0+arow)*FLATSZ + k0 + acol);
    As[acol+0][arow] = av.x;
    As[acol+1][arow] = av.y;
    As[acol+2][arow] = av.z;
    As[acol+3][arow] = av.w;
#pragma unroll
    for(int r=0;r<2;r++){
      int k = brow + r*16;
      int col = n0 + bcol;
      const float* src = mbw + (size_t)(k0+k)*500 + col;
      if(col+3 < 500){
        float4 bv = *(const float4*)src;
        Bs[k][bcol+0]=bv.x; Bs[k][bcol+1]=bv.y; Bs[k][bcol+2]=bv.z; Bs[k][bcol+3]=bv.w;
      } else {
#pragma unroll
        for(int j=0;j<4;j++) Bs[k][bcol+j] = (col+j<500)? src[j] : 0.f;
      }
    }
    __syncthreads();
#pragma unroll 8
    for(int kk=0;kk<32;kk++){
      float a0 = As[kk][ty*2+0];
      float a1 = As[kk][ty*2+1];
      float4 bv = *(const float4*)&Bs[kk][tx*4];
      acc[0][0] += a0*bv.x; acc[0][1] += a0*bv.y; acc[0][2] += a0*bv.z; acc[0][3] += a0*bv.w;
      acc[1][0] += a1*bv.x; acc[1][1] += a1*bv.y; acc[1][2] += a1*bv.z; acc[1][3] += a1*bv.w;
    }
  }
#pragma unroll
  for(int mm=0;mm<2;mm++){
    int m = m0 + ty*2 + mm;
#pragma unroll
    for(int j=0;j<4;j++){
      int c = n0 + tx*4 + j;
      if(c < 500) act[(size_t)m*500 + c] = acc[mm][j];
    }
  }
}

// ---------- minibatch features ----------
__global__ void feats_kernel(const float* __restrict__ act, float* __restrict__ feats){
  int i = blockIdx.x, k = threadIdx.x;
  if(k >= NUMK) return;
  const float* ai = act + (size_t)i*500 + k*5;
  float a0=ai[0],a1=ai[1],a2=ai[2],a3=ai[3],a4=ai[4];
  float f = 0.f;
  for(int j=0;j<NB;j++){
    const float* aj = act + (size_t)j*500 + k*5;
    float l1 = fabsf(a0-aj[0]) + fabsf(a1-aj[1]) + fabsf(a2-aj[2])
             + fabsf(a3-aj[3]) + fabsf(a4-aj[4]);
    f += expf(-l1);
  }
  feats[i*NUMK + k] = f;
}

// ---------- final: out[n] = [flat|feats|cond] . fc_w + fc_b ----------
__global__ void final_kernel(const float* __restrict__ flat, const float* __restrict__ feats,
                             const int* __restrict__ condition, const float* __restrict__ emb,
                             const float* __restrict__ cond_w, const float* __restrict__ cond_b,
                             const float* __restrict__ fc_w, const float* __restrict__ fc_b,
                             float* __restrict__ out){
  __shared__ float red[4];
  int n = blockIdx.x, tid = threadIdx.x;
  float s = 0.f;
  const float* fr = flat + (size_t)n*FLATSZ;
  for(int q=tid; q<FLATSZ/4; q+=256){
    float4 f = *(const float4*)(fr + q*4);
    float4 w = *(const float4*)(fc_w + q*4);
    s += f.x*w.x + f.y*w.y + f.z*w.z + f.w*w.w;
  }
  for(int k=tid;k<NUMK;k+=256) s += feats[n*NUMK+k]*fc_w[FLATSZ+k];
  float ce = emb[condition[n]];   // COND_DIM = 1
  for(int j=tid;j<50;j+=256) s += (ce*cond_w[j]+cond_b[j])*fc_w[FLATSZ+NUMK+j];
  s = block_reduce_sum(s, red);
  if(tid==0) out[n] = s + fc_b[0];
}

extern "C" void kernel_launch(void* const* d_in, const int* in_sizes, int n_in,
                              void* d_out, int out_size, void* d_ws, size_t ws_size,
                              hipStream_t stream) {
  const float* ecg   = (const float*)d_in[0];
  const int*   cond  = (const int*)  d_in[1];
  const float* w1    = (const float*)d_in[2];
  const float* b1    = (const float*)d_in[3];
  const float* u1    = (const float*)d_in[4];
  const float* w2    = (const float*)d_in[5];
  const float* b2    = (const float*)d_in[6];
  const float* u2    = (const float*)d_in[7];
  const float* w3    = (const float*)d_in[8];
  const float* b3    = (const float*)d_in[9];
  const float* u3    = (const float*)d_in[10];
  const float* emb   = (const float*)d_in[11];
  const float* condw = (const float*)d_in[12];
  const float* condb = (const float*)d_in[13];
  const float* mbw   = (const float*)d_in[14];
  const float* fcw   = (const float*)d_in[15];
  const float* fcb   = (const float*)d_in[16];

  float* ws = (float*)d_ws;
  float* scale   = ws;                       // 16 floats (3 used)
  float* y1buf   = ws + 16;                  // NB*64*322 = 10,551,296 floats
  size_t y1sz    = (size_t)NB*C1N*L1O;
  float* y2buf   = y1buf + y1sz;             // NB*128*161 = 10,551,296 floats
  float* flatbuf = y1buf;                    // reuse y1 region (dead after conv2)
  float* actbuf  = y2buf;                    // reuse y2 region (dead after conv3)
  float* featsbuf= y2buf + 256000;           // after act (512*500)

  sn_kernel<<<3, 256, 0, stream>>>(w1,u1,w2,u2,w3,u3, scale);
  conv1_kernel<<<NB, 256, 0, stream>>>(ecg, w1, b1, scale, y1buf);
  conv2_kernel<<<dim3(NB,2), 256, 0, stream>>>(y1buf, w2, b2, scale, y2buf);
  conv3_kernel<<<dim3(NB,2), 256, 0, stream>>>(y2buf, w3, b3, scale, flatbuf);
  mb_gemm_kernel<<<dim3(16,8), 256, 0, stream>>>(flatbuf, mbw, actbuf);
  feats_kernel<<<NB, 128, 0, stream>>>(actbuf, featsbuf);
  final_kernel<<<NB, 256, 0, stream>>>(flatbuf, featsbuf, cond, emb, condw, condb, fcw, fcb, (float*)d_out);
}

// Round 2
// 2392.030 us; speedup vs baseline: 1.5728x; 1.5728x over previous
//
#include <hip/hip_runtime.h>
#include <math.h>

#define NB 512
#define LIN 640
#define NLEADS 3
#define L1O 322
#define L2O 161
#define L3O 79
#define C1N 64
#define C2N 128
#define C3N 256
#define FLATSZ 20224   // 256*79
#define NUMK 100
#define DIMK 5
#define SPLITK 16
#define KTILES 632     // FLATSZ/32

__device__ __forceinline__ float block_reduce_sum(float val, float* red){
#pragma unroll
  for(int off=32; off>0; off>>=1) val += __shfl_down(val, off, 64);
  int lane = threadIdx.x & 63;
  int wv = threadIdx.x >> 6;
  if(lane==0) red[wv] = val;
  __syncthreads();
  int nw = blockDim.x >> 6;
  float r = red[0];
  for(int i=1;i<nw;i++) r += red[i];
  __syncthreads();
  return r;
}

// ---------- spectral norm: scale[b] = 1/sigma for each conv weight ----------
__global__ void sn_kernel(const float* __restrict__ w1, const float* __restrict__ u1,
                          const float* __restrict__ w2, const float* __restrict__ u2,
                          const float* __restrict__ w3, const float* __restrict__ u3,
                          float* __restrict__ scale){
  __shared__ float v[1152];
  __shared__ float red[4];
  const float* w; const float* u; int O, C;
  if(blockIdx.x==0){ w=w1; u=u1; O=64;  C=15;   }
  else if(blockIdx.x==1){ w=w2; u=u2; O=128; C=448;  }
  else { w=w3; u=u3; O=256; C=1152; }
  int tid = threadIdx.x;
  float ss = 0.f;
  for(int c=tid;c<C;c+=256){
    float s = 0.f;
    for(int o=0;o<O;o++) s += w[o*C+c]*u[o];
    v[c] = s; ss += s*s;
  }
  ss = block_reduce_sum(ss, red);
  float inv_nv = 1.f/(sqrtf(ss)+1e-12f);
  float S = 0.f;
  for(int o=tid;o<O;o+=256){
    float t = 0.f;
    for(int c=0;c<C;c++) t += w[o*C+c]*v[c];
    t *= inv_nv;
    S += t*t;
  }
  S = block_reduce_sum(S, red);
  // sigma = S/(sqrt(S)+eps)  ->  1/sigma = (sqrt(S)+eps)/S
  if(tid==0) scale[blockIdx.x] = (sqrtf(S)+1e-12f)/S;
}

// ---------- conv1: (NB,3,640) -> (NB,64,322), stride2 pad4 K5, leaky ----------
__global__ void conv1_kernel(const float* __restrict__ ecg, const float* __restrict__ w1,
                             const float* __restrict__ b1, const float* __restrict__ scale,
                             float* __restrict__ y1){
  __shared__ float xs[NLEADS*LIN];
  __shared__ float wsh[C1N*15];
  __shared__ float bsh[C1N];
  int n = blockIdx.x, tid = threadIdx.x;
  float s = scale[0];
  for(int idx=tid; idx<NLEADS*LIN; idx+=256){
    int lead = idx/LIN, l = idx-lead*LIN;
    xs[idx] = ecg[(n*LIN + l)*NLEADS + lead];
  }
  for(int idx=tid; idx<C1N*15; idx+=256) wsh[idx] = w1[idx]*s;
  if(tid<C1N) bsh[tid] = b1[tid];
  __syncthreads();
  for(int idx=tid; idx<C1N*L1O; idx+=256){
    int o = idx/L1O, t = idx-o*L1O;
    float acc = 0.f;
    int base = 2*t - 4;
#pragma unroll
    for(int i=0;i<NLEADS;i++){
#pragma unroll
      for(int k=0;k<5;k++){
        int p = base+k;
        if((unsigned)p < (unsigned)LIN) acc += xs[i*LIN+p]*wsh[o*15+i*5+k];
      }
    }
    acc += bsh[o];
    y1[(n*C1N+o)*L1O + t] = acc>=0.f ? acc : 0.2f*acc;
  }
}

// ---------- conv2: (NB,64,322) -> (NB,128,161), stride2 pad3 K7, leaky ----------
#define C2W 167
__global__ void conv2_kernel(const float* __restrict__ y1, const float* __restrict__ w2,
                             const float* __restrict__ b2, const float* __restrict__ scale,
                             float* __restrict__ y2){
  __shared__ float xs[C1N*C2W + 8];
  int n = blockIdx.x, tile = blockIdx.y, tid = threadIdx.x;
  int t0 = tile*81;
  int TT = tile ? 80 : 81;
  int W = 2*TT + 5;
  float s = scale[1];
  for(int idx=tid; idx<C1N*W; idx+=256){
    int i = idx/W, c = idx - i*W;
    int p = 2*t0 - 3 + c;
    xs[i*C2W + c] = ((unsigned)p < (unsigned)L1O) ? y1[(n*C1N+i)*L1O + p] : 0.f;
  }
  __syncthreads();
  int groups = (TT+3)>>2;
  for(int idx=tid; idx<C2N*groups; idx+=256){
    int o = idx/groups, g = idx - o*groups;
    int tt0 = g*4;
    float a0=0.f,a1=0.f,a2=0.f,a3=0.f;
    const float* wo = w2 + o*(C1N*7);
    for(int i=0;i<C1N;i++){
      const float* xr = xs + i*C2W + 2*tt0;
      const float* wi = wo + i*7;
#pragma unroll
      for(int k=0;k<7;k++){
        float wv = wi[k];
        a0 += wv*xr[k];
        a1 += wv*xr[k+2];
        a2 += wv*xr[k+4];
        a3 += wv*xr[k+6];
      }
    }
    float b = b2[o];
    int t = t0 + tt0;
    float* yo = y2 + (size_t)(n*C2N+o)*L2O + t;
    float r0 = a0*s + b, r1 = a1*s + b, r2 = a2*s + b, r3 = a3*s + b;
    if(tt0   < TT) yo[0] = r0>=0.f?r0:0.2f*r0;
    if(tt0+1 < TT) yo[1] = r1>=0.f?r1:0.2f*r1;
    if(tt0+2 < TT) yo[2] = r2>=0.f?r2:0.2f*r2;
    if(tt0+3 < TT) yo[3] = r3>=0.f?r3:0.2f*r3;
  }
}

// ---------- conv3: (NB,128,161) -> flat (NB, 256*79), stride2 pad2 K9, leaky ----------
#define C3W 87
__global__ void conv3_kernel(const float* __restrict__ y2, const float* __restrict__ w3,
                             const float* __restrict__ b3, const float* __restrict__ scale,
                             float* __restrict__ flat){
  __shared__ float xs[C2N*C3W + 8];
  int n = blockIdx.x, tile = blockIdx.y, tid = threadIdx.x;
  int t0 = tile*40;
  int TT = tile ? 39 : 40;
  int W = 2*TT + 7;
  float s = scale[2];
  for(int idx=tid; idx<C2N*W; idx+=256){
    int i = idx/W, c = idx - i*W;
    int p = 2*t0 - 2 + c;
    xs[i*C3W + c] = ((unsigned)p < (unsigned)L2O) ? y2[(size_t)(n*C2N+i)*L2O + p] : 0.f;
  }
  __syncthreads();
  const int groups = 10;
  for(int idx=tid; idx<C3N*groups; idx+=256){
    int o = idx/groups, g = idx - o*groups;
    int tt0 = g*4;
    float a0=0.f,a1=0.f,a2=0.f,a3=0.f;
    const float* wo = w3 + o*(C2N*9);
    for(int i=0;i<C2N;i++){
      const float* xr = xs + i*C3W + 2*tt0;
      const float* wi = wo + i*9;
#pragma unroll
      for(int k=0;k<9;k++){
        float wv = wi[k];
        a0 += wv*xr[k];
        a1 += wv*xr[k+2];
        a2 += wv*xr[k+4];
        a3 += wv*xr[k+6];
      }
    }
    float b = b3[o];
    int t = t0 + tt0;
    float* yo = flat + (size_t)n*FLATSZ + o*L3O + t;
    float r0 = a0*s + b, r1 = a1*s + b, r2 = a2*s + b, r3 = a3*s + b;
    if(tt0   < TT) yo[0] = r0>=0.f?r0:0.2f*r0;
    if(tt0+1 < TT) yo[1] = r1>=0.f?r1:0.2f*r1;
    if(tt0+2 < TT) yo[2] = r2>=0.f?r2:0.2f*r2;
    if(tt0+3 < TT) yo[3] = r3>=0.f?r3:0.2f*r3;
  }
}

// ---------- split-K GEMM: part[z] += flat(64m x Kc) @ mbw(Kc x 64n) ----------
// grid (8 m-tiles, 8 n-tiles, 16 k-slices), 256 threads, 4x4 per thread
__global__ __launch_bounds__(256)
void mb_gemm_splitk(const float* __restrict__ flat, const float* __restrict__ mbw,
                    float* __restrict__ part){
  __shared__ float As[32][68];  // [k][m], padded
  __shared__ float Bs[32][68];  // [k][n], padded
  int tid = threadIdx.x;
  int m0 = blockIdx.x*64, n0 = blockIdx.y*64, bz = blockIdx.z;
  // K chunk in units of 32: first 8 slices get 40 tiles, rest 39 (8*40+8*39=632)
  int t_start = bz*39 + (bz<8 ? bz : 8);
  int t_count = 39 + (bz<8 ? 1 : 0);
  int k0 = t_start*32;

  int tx = tid & 15, ty = tid >> 4;        // tx: n dir, ty: m dir
  float acc[4][4];
#pragma unroll
  for(int i=0;i<4;i++)
#pragma unroll
    for(int j=0;j<4;j++) acc[i][j]=0.f;

  int arow = tid >> 3;          // 0..31  (m half-tile row)
  int acol = (tid & 7) * 4;     // k offset 0..28
  int brow = tid >> 4;          // 0..15  (k half-tile row)
  int bcol = (tid & 15) * 4;    // n offset 0..60

  for(int t=0; t<t_count; t++, k0+=32){
    __syncthreads();
    // stage A: flat[m0+arow(+32)][k0+acol..+3] -> As[k][m]
#pragma unroll
    for(int h=0; h<2; h++){
      int m = arow + h*32;
      float4 av = *(const float4*)(flat + (size_t)(m0+m)*FLATSZ + k0 + acol);
      As[acol+0][m] = av.x;
      As[acol+1][m] = av.y;
      As[acol+2][m] = av.z;
      As[acol+3][m] = av.w;
    }
    // stage B: mbw[k0+brow(+16)][n0+bcol..+3] -> Bs[k][n]
#pragma unroll
    for(int h=0; h<2; h++){
      int k = brow + h*16;
      int col = n0 + bcol;
      const float* src = mbw + (size_t)(k0+k)*500 + col;
      if(col+3 < 500){
        float4 bv = *(const float4*)src;
        Bs[k][bcol+0]=bv.x; Bs[k][bcol+1]=bv.y; Bs[k][bcol+2]=bv.z; Bs[k][bcol+3]=bv.w;
      } else {
#pragma unroll
        for(int j=0;j<4;j++) Bs[k][bcol+j] = (col+j<500)? src[j] : 0.f;
      }
    }
    __syncthreads();
#pragma unroll 4
    for(int kk=0;kk<32;kk++){
      float4 a = *(const float4*)&As[kk][ty*4];
      float4 b = *(const float4*)&Bs[kk][tx*4];
      acc[0][0]+=a.x*b.x; acc[0][1]+=a.x*b.y; acc[0][2]+=a.x*b.z; acc[0][3]+=a.x*b.w;
      acc[1][0]+=a.y*b.x; acc[1][1]+=a.y*b.y; acc[1][2]+=a.y*b.z; acc[1][3]+=a.y*b.w;
      acc[2][0]+=a.z*b.x; acc[2][1]+=a.z*b.y; acc[2][2]+=a.z*b.z; acc[2][3]+=a.z*b.w;
      acc[3][0]+=a.w*b.x; acc[3][1]+=a.w*b.y; acc[3][2]+=a.w*b.z; acc[3][3]+=a.w*b.w;
    }
  }
  float* po = part + (size_t)bz*NB*500;
#pragma unroll
  for(int i=0;i<4;i++){
    int m = m0 + ty*4 + i;
#pragma unroll
    for(int j=0;j<4;j++){
      int c = n0 + tx*4 + j;
      if(c < 500) po[(size_t)m*500 + c] = acc[i][j];
    }
  }
}

// ---------- reduce partials: act = sum_z part[z] ----------
__global__ void mb_reduce_kernel(const float* __restrict__ part, float* __restrict__ act){
  int idx = blockIdx.x*256 + threadIdx.x;   // 0..255999
  float s = 0.f;
#pragma unroll
  for(int z=0;z<SPLITK;z++) s += part[(size_t)z*NB*500 + idx];
  act[idx] = s;
}

// ---------- minibatch features ----------
__global__ void feats_kernel(const float* __restrict__ act, float* __restrict__ feats){
  int i = blockIdx.x, k = threadIdx.x;
  if(k >= NUMK) return;
  const float* ai = act + (size_t)i*500 + k*5;
  float a0=ai[0],a1=ai[1],a2=ai[2],a3=ai[3],a4=ai[4];
  float f = 0.f;
  for(int j=0;j<NB;j++){
    const float* aj = act + (size_t)j*500 + k*5;
    float l1 = fabsf(a0-aj[0]) + fabsf(a1-aj[1]) + fabsf(a2-aj[2])
             + fabsf(a3-aj[3]) + fabsf(a4-aj[4]);
    f += expf(-l1);
  }
  feats[i*NUMK + k] = f;
}

// ---------- final: out[n] = [flat|feats|cond] . fc_w + fc_b ----------
__global__ void final_kernel(const float* __restrict__ flat, const float* __restrict__ feats,
                             const int* __restrict__ condition, const float* __restrict__ emb,
                             const float* __restrict__ cond_w, const float* __restrict__ cond_b,
                             const float* __restrict__ fc_w, const float* __restrict__ fc_b,
                             float* __restrict__ out){
  __shared__ float red[4];
  int n = blockIdx.x, tid = threadIdx.x;
  float s = 0.f;
  const float* fr = flat + (size_t)n*FLATSZ;
  for(int q=tid; q<FLATSZ/4; q+=256){
    float4 f = *(const float4*)(fr + q*4);
    float4 w = *(const float4*)(fc_w + q*4);
    s += f.x*w.x + f.y*w.y + f.z*w.z + f.w*w.w;
  }
  for(int k=tid;k<NUMK;k+=256) s += feats[n*NUMK+k]*fc_w[FLATSZ+k];
  float ce = emb[condition[n]];   // COND_DIM = 1
  for(int j=tid;j<50;j+=256) s += (ce*cond_w[j]+cond_b[j])*fc_w[FLATSZ+NUMK+j];
  s = block_reduce_sum(s, red);
  if(tid==0) out[n] = s + fc_b[0];
}

extern "C" void kernel_launch(void* const* d_in, const int* in_sizes, int n_in,
                              void* d_out, int out_size, void* d_ws, size_t ws_size,
                              hipStream_t stream) {
  const float* ecg   = (const float*)d_in[0];
  const int*   cond  = (const int*)  d_in[1];
  const float* w1    = (const float*)d_in[2];
  const float* b1    = (const float*)d_in[3];
  const float* u1    = (const float*)d_in[4];
  const float* w2    = (const float*)d_in[5];
  const float* b2    = (const float*)d_in[6];
  const float* u2    = (const float*)d_in[7];
  const float* w3    = (const float*)d_in[8];
  const float* b3    = (const float*)d_in[9];
  const float* u3    = (const float*)d_in[10];
  const float* emb   = (const float*)d_in[11];
  const float* condw = (const float*)d_in[12];
  const float* condb = (const float*)d_in[13];
  const float* mbw   = (const float*)d_in[14];
  const float* fcw   = (const float*)d_in[15];
  const float* fcb   = (const float*)d_in[16];

  float* ws = (float*)d_ws;
  float* scale   = ws;                       // 16 floats (3 used)
  float* y1buf   = ws + 16;                  // NB*64*322 floats
  size_t y1sz    = (size_t)NB*C1N*L1O;
  float* y2buf   = y1buf + y1sz;             // NB*128*161 floats
  float* flatbuf = y1buf;                    // reuse y1 region (dead after conv2)
  float* actbuf  = y2buf;                    // reuse y2 region (dead after conv3)
  float* featsbuf= y2buf + 256000;           // after act (512*500)
  float* partbuf = y2buf + 256000 + NB*NUMK; // 16*512*500 floats, still inside y2 region

  sn_kernel<<<3, 256, 0, stream>>>(w1,u1,w2,u2,w3,u3, scale);
  conv1_kernel<<<NB, 256, 0, stream>>>(ecg, w1, b1, scale, y1buf);
  conv2_kernel<<<dim3(NB,2), 256, 0, stream>>>(y1buf, w2, b2, scale, y2buf);
  conv3_kernel<<<dim3(NB,2), 256, 0, stream>>>(y2buf, w3, b3, scale, flatbuf);
  mb_gemm_splitk<<<dim3(8,8,SPLITK), 256, 0, stream>>>(flatbuf, mbw, partbuf);
  mb_reduce_kernel<<<1000, 256, 0, stream>>>(partbuf, actbuf);
  feats_kernel<<<NB, 128, 0, stream>>>(actbuf, featsbuf);
  final_kernel<<<NB, 256, 0, stream>>>(flatbuf, featsbuf, cond, emb, condw, condb, fcw, fcb, (float*)d_out);
}

// Round 3
// 1006.543 us; speedup vs baseline: 3.7376x; 2.3765x over previous
//
#include <hip/hip_runtime.h>
#include <math.h>

#define NB 512
#define LIN 640
#define NLEADS 3
#define L1O 322
#define L2O 161
#define L3O 79
#define C1N 64
#define C2N 128
#define C3N 256
#define FLATSZ 20224   // 256*79
#define NUMK 100
#define DIMK 5
#define SPLITK 16

typedef __attribute__((ext_vector_type(8))) short short8;
typedef __attribute__((ext_vector_type(4))) float f32x4;

__device__ __forceinline__ unsigned short f2bf(float x){
  unsigned u = __builtin_bit_cast(unsigned, x);
  unsigned r = u + 0x7FFFu + ((u >> 16) & 1u);
  return (unsigned short)(r >> 16);
}

__device__ __forceinline__ float block_reduce_sum(float val, float* red){
#pragma unroll
  for(int off=32; off>0; off>>=1) val += __shfl_down(val, off, 64);
  int lane = threadIdx.x & 63;
  int wv = threadIdx.x >> 6;
  if(lane==0) red[wv] = val;
  __syncthreads();
  int nw = blockDim.x >> 6;
  float r = red[0];
  for(int i=1;i<nw;i++) r += red[i];
  __syncthreads();
  return r;
}

// ---------- spectral norm: scale[b] = 1/sigma ----------
__global__ void sn_kernel(const float* __restrict__ w1, const float* __restrict__ u1,
                          const float* __restrict__ w2, const float* __restrict__ u2,
                          const float* __restrict__ w3, const float* __restrict__ u3,
                          float* __restrict__ scale){
  __shared__ float v[1152];
  __shared__ float red[4];
  const float* w; const float* u; int O, C;
  if(blockIdx.x==0){ w=w1; u=u1; O=64;  C=15;   }
  else if(blockIdx.x==1){ w=w2; u=u2; O=128; C=448;  }
  else { w=w3; u=u3; O=256; C=1152; }
  int tid = threadIdx.x;
  float ss = 0.f;
  for(int c=tid;c<C;c+=256){
    float s = 0.f;
    for(int o=0;o<O;o++) s += w[o*C+c]*u[o];
    v[c] = s; ss += s*s;
  }
  ss = block_reduce_sum(ss, red);
  float inv_nv = 1.f/(sqrtf(ss)+1e-12f);
  float S = 0.f;
  for(int o=tid;o<O;o+=256){
    float t = 0.f;
    for(int c=0;c<C;c++) t += w[o*C+c]*v[c];
    t *= inv_nv;
    S += t*t;
  }
  S = block_reduce_sum(S, red);
  if(tid==0) scale[blockIdx.x] = (sqrtf(S)+1e-12f)/S;
}

// ---------- weight prep: bf16 copies of scaled w2, w3 ----------
__global__ void wprep_kernel(const float* __restrict__ w2, const float* __restrict__ w3,
                             const float* __restrict__ scale,
                             unsigned short* __restrict__ w2bf, unsigned short* __restrict__ w3bf){
  int idx = blockIdx.x*256 + threadIdx.x;
  float s2 = scale[1], s3 = scale[2];
  if(idx < C2N*448)   w2bf[idx] = f2bf(w2[idx]*s2);
  if(idx < C3N*1152)  w3bf[idx] = f2bf(w3[idx]*s3);
}

// ---------- conv1: (NB,3,640) -> y1bf (NB,64,322) bf16, stride2 pad4 K5, leaky ----------
__global__ void conv1_kernel(const float* __restrict__ ecg, const float* __restrict__ w1,
                             const float* __restrict__ b1, const float* __restrict__ scale,
                             unsigned short* __restrict__ y1bf){
  __shared__ float xs[NLEADS*LIN];
  __shared__ float wsh[C1N*15];
  __shared__ float bsh[C1N];
  int n = blockIdx.x, tid = threadIdx.x;
  float s = scale[0];
  for(int idx=tid; idx<NLEADS*LIN; idx+=256){
    int lead = idx/LIN, l = idx-lead*LIN;
    xs[idx] = ecg[(n*LIN + l)*NLEADS + lead];
  }
  for(int idx=tid; idx<C1N*15; idx+=256) wsh[idx] = w1[idx]*s;
  if(tid<C1N) bsh[tid] = b1[tid];
  __syncthreads();
  for(int idx=tid; idx<C1N*L1O; idx+=256){
    int o = idx/L1O, t = idx-o*L1O;
    float acc = 0.f;
    int base = 2*t - 4;
#pragma unroll
    for(int i=0;i<NLEADS;i++){
#pragma unroll
      for(int k=0;k<5;k++){
        int p = base+k;
        if((unsigned)p < (unsigned)LIN) acc += xs[i*LIN+p]*wsh[o*15+i*5+k];
      }
    }
    acc += bsh[o];
    float r = acc>=0.f ? acc : 0.2f*acc;
    y1bf[(size_t)n*20608 + o*L1O + t] = f2bf(r);
  }
}

// ---------- conv2 MFMA: per-batch GEMM  (128 x 448) @ (448 x 176pad) ----------
__global__ __launch_bounds__(256)
void conv2_mfma(const unsigned short* __restrict__ y1bf, const unsigned short* __restrict__ w2bf,
                const float* __restrict__ b2, unsigned short* __restrict__ y2bf){
  __shared__ unsigned short ys[C1N*L1O];      // 64*322 bf16 = 41216 B
  __shared__ unsigned short As[C2N*32];       // 8 KB
  __shared__ unsigned short Bs[176*32];       // 11 KB
  int n = blockIdx.x, tid = threadIdx.x;
  int lane = tid & 63, w = tid >> 6;
  // stage y1bf[n] -> LDS (flat copy, 2576 uint4)
  {
    const uint4* src = (const uint4*)(y1bf + (size_t)n*20608);
    uint4* dst = (uint4*)ys;
#pragma unroll
    for(int q=0;q<11;q++){
      int f = q*256 + tid;
      if(f < 2576) dst[f] = src[f];
    }
  }
  f32x4 zero = {0.f,0.f,0.f,0.f};
  f32x4 acc[2][11];
#pragma unroll
  for(int i=0;i<2;i++)
#pragma unroll
    for(int j=0;j<11;j++) acc[i][j] = zero;
  __syncthreads();

  for(int ck=0; ck<14; ck++){
    int kc = ck*32;
    __syncthreads();
    // stage A chunk: w2bf[0..127][kc..kc+31]  (512 uint4)
    {
      const char* wb = (const char*)w2bf;
      uint4* dst = (uint4*)As;
#pragma unroll
      for(int q=0;q<2;q++){
        int f = q*256 + tid;
        int row = f >> 2, col = f & 3;
        dst[f] = *(const uint4*)(wb + row*896 + kc*2 + col*16);
      }
    }
    // build B chunk (im2col gather): Bs[t][kk], 5632 elements
#pragma unroll
    for(int q=0;q<22;q++){
      int e = q*256 + tid;
      int t = e >> 5, kk = e & 31;
      int k = kc + kk;
      int i = k / 7;
      int r = k - i*7;
      int p = 2*t - 3 + r;
      unsigned short v = 0;
      if(t < L2O && (unsigned)p < (unsigned)L1O) v = ys[i*L1O + p];
      Bs[t*32 + kk] = v;
    }
    __syncthreads();
    short8 a[2], b[11];
#pragma unroll
    for(int mm=0;mm<2;mm++)
      a[mm] = *(const short8*)(As + ((w*2+mm)*16 + (lane&15))*32 + (lane>>4)*8);
#pragma unroll
    for(int nt=0;nt<11;nt++)
      b[nt] = *(const short8*)(Bs + (nt*16 + (lane&15))*32 + (lane>>4)*8);
#pragma unroll
    for(int mm=0;mm<2;mm++)
#pragma unroll
      for(int nt=0;nt<11;nt++)
        acc[mm][nt] = __builtin_amdgcn_mfma_f32_16x16x32_bf16(a[mm], b[nt], acc[mm][nt], 0, 0, 0);
  }
  // epilogue: bias + leaky + bf16 store. C/D: col=lane&15, row=(lane>>4)*4+reg
#pragma unroll
  for(int mm=0;mm<2;mm++){
#pragma unroll
    for(int reg=0;reg<4;reg++){
      int o = (w*2+mm)*16 + (lane>>4)*4 + reg;
      float bias = b2[o];
#pragma unroll
      for(int nt=0;nt<11;nt++){
        int t = nt*16 + (lane&15);
        if(t < L2O){
          float v = acc[mm][nt][reg] + bias;
          v = v>=0.f ? v : 0.2f*v;
          y2bf[(size_t)n*20608 + o*L2O + t] = f2bf(v);
        }
      }
    }
  }
}

// ---------- conv3 MFMA: per-batch GEMM  (256 x 1152) @ (1152 x 80pad) ----------
__global__ __launch_bounds__(256)
void conv3_mfma(const unsigned short* __restrict__ y2bf, const unsigned short* __restrict__ w3bf,
                const float* __restrict__ b3, float* __restrict__ flat){
  __shared__ unsigned short ys[C2N*L2O];      // 128*161 bf16 = 41216 B
  __shared__ unsigned short As[C3N*32];       // 16 KB
  __shared__ unsigned short Bs[80*32];        // 5 KB
  int n = blockIdx.x, tid = threadIdx.x;
  int lane = tid & 63, w = tid >> 6;
  {
    const uint4* src = (const uint4*)(y2bf + (size_t)n*20608);
    uint4* dst = (uint4*)ys;
#pragma unroll
    for(int q=0;q<11;q++){
      int f = q*256 + tid;
      if(f < 2576) dst[f] = src[f];
    }
  }
  f32x4 zero = {0.f,0.f,0.f,0.f};
  f32x4 acc[4][5];
#pragma unroll
  for(int i=0;i<4;i++)
#pragma unroll
    for(int j=0;j<5;j++) acc[i][j] = zero;
  __syncthreads();

  for(int ck=0; ck<36; ck++){
    int kc = ck*32;
    __syncthreads();
    // stage A chunk: w3bf[0..255][kc..kc+31]  (1024 uint4)
    {
      const char* wb = (const char*)w3bf;
      uint4* dst = (uint4*)As;
#pragma unroll
      for(int q=0;q<4;q++){
        int f = q*256 + tid;
        int row = f >> 2, col = f & 3;
        dst[f] = *(const uint4*)(wb + row*2304 + kc*2 + col*16);
      }
    }
    // build B chunk (im2col gather): 2560 elements
#pragma unroll
    for(int q=0;q<10;q++){
      int e = q*256 + tid;
      int t = e >> 5, kk = e & 31;
      int k = kc + kk;
      int i = k / 9;
      int r = k - i*9;
      int p = 2*t - 2 + r;
      unsigned short v = 0;
      if(t < L3O && (unsigned)p < (unsigned)L2O) v = ys[i*L2O + p];
      Bs[t*32 + kk] = v;
    }
    __syncthreads();
    short8 a[4], b[5];
#pragma unroll
    for(int mm=0;mm<4;mm++)
      a[mm] = *(const short8*)(As + ((w*4+mm)*16 + (lane&15))*32 + (lane>>4)*8);
#pragma unroll
    for(int nt=0;nt<5;nt++)
      b[nt] = *(const short8*)(Bs + (nt*16 + (lane&15))*32 + (lane>>4)*8);
#pragma unroll
    for(int mm=0;mm<4;mm++)
#pragma unroll
      for(int nt=0;nt<5;nt++)
        acc[mm][nt] = __builtin_amdgcn_mfma_f32_16x16x32_bf16(a[mm], b[nt], acc[mm][nt], 0, 0, 0);
  }
#pragma unroll
  for(int mm=0;mm<4;mm++){
#pragma unroll
    for(int reg=0;reg<4;reg++){
      int o = (w*4+mm)*16 + (lane>>4)*4 + reg;
      float bias = b3[o];
#pragma unroll
      for(int nt=0;nt<5;nt++){
        int t = nt*16 + (lane&15);
        if(t < L3O){
          float v = acc[mm][nt][reg] + bias;
          v = v>=0.f ? v : 0.2f*v;
          flat[(size_t)n*FLATSZ + o*L3O + t] = v;
        }
      }
    }
  }
}

// ---------- split-K GEMM: part[z] = flat(64m x Kc) @ mbw(Kc x 64n) ----------
__global__ __launch_bounds__(256)
void mb_gemm_splitk(const float* __restrict__ flat, const float* __restrict__ mbw,
                    float* __restrict__ part){
  __shared__ float As[32][68];
  __shared__ float Bs[32][68];
  int tid = threadIdx.x;
  int m0 = blockIdx.x*64, n0 = blockIdx.y*64, bz = blockIdx.z;
  int t_start = bz*39 + (bz<8 ? bz : 8);
  int t_count = 39 + (bz<8 ? 1 : 0);
  int k0 = t_start*32;

  int tx = tid & 15, ty = tid >> 4;
  float acc[4][4];
#pragma unroll
  for(int i=0;i<4;i++)
#pragma unroll
    for(int j=0;j<4;j++) acc[i][j]=0.f;

  int arow = tid >> 3;
  int acol = (tid & 7) * 4;
  int brow = tid >> 4;
  int bcol = (tid & 15) * 4;

  for(int t=0; t<t_count; t++, k0+=32){
    __syncthreads();
#pragma unroll
    for(int h=0; h<2; h++){
      int m = arow + h*32;
      float4 av = *(const float4*)(flat + (size_t)(m0+m)*FLATSZ + k0 + acol);
      As[acol+0][m] = av.x;
      As[acol+1][m] = av.y;
      As[acol+2][m] = av.z;
      As[acol+3][m] = av.w;
    }
#pragma unroll
    for(int h=0; h<2; h++){
      int k = brow + h*16;
      int col = n0 + bcol;
      const float* src = mbw + (size_t)(k0+k)*500 + col;
      if(col+3 < 500){
        float4 bv = *(const float4*)src;
        Bs[k][bcol+0]=bv.x; Bs[k][bcol+1]=bv.y; Bs[k][bcol+2]=bv.z; Bs[k][bcol+3]=bv.w;
      } else {
#pragma unroll
        for(int j=0;j<4;j++) Bs[k][bcol+j] = (col+j<500)? src[j] : 0.f;
      }
    }
    __syncthreads();
#pragma unroll 4
    for(int kk=0;kk<32;kk++){
      float4 a = *(const float4*)&As[kk][ty*4];
      float4 b = *(const float4*)&Bs[kk][tx*4];
      acc[0][0]+=a.x*b.x; acc[0][1]+=a.x*b.y; acc[0][2]+=a.x*b.z; acc[0][3]+=a.x*b.w;
      acc[1][0]+=a.y*b.x; acc[1][1]+=a.y*b.y; acc[1][2]+=a.y*b.z; acc[1][3]+=a.y*b.w;
      acc[2][0]+=a.z*b.x; acc[2][1]+=a.z*b.y; acc[2][2]+=a.z*b.z; acc[2][3]+=a.z*b.w;
      acc[3][0]+=a.w*b.x; acc[3][1]+=a.w*b.y; acc[3][2]+=a.w*b.z; acc[3][3]+=a.w*b.w;
    }
  }
  float* po = part + (size_t)bz*NB*500;
#pragma unroll
  for(int i=0;i<4;i++){
    int m = m0 + ty*4 + i;
#pragma unroll
    for(int j=0;j<4;j++){
      int c = n0 + tx*4 + j;
      if(c < 500) po[(size_t)m*500 + c] = acc[i][j];
    }
  }
}

__global__ void mb_reduce_kernel(const float* __restrict__ part, float* __restrict__ act){
  int idx = blockIdx.x*256 + threadIdx.x;
  float s = 0.f;
#pragma unroll
  for(int z=0;z<SPLITK;z++) s += part[(size_t)z*NB*500 + idx];
  act[idx] = s;
}

// ---------- minibatch features ----------
__global__ void feats_kernel(const float* __restrict__ act, float* __restrict__ feats){
  int i = blockIdx.x, k = threadIdx.x;
  if(k >= NUMK) return;
  const float* ai = act + (size_t)i*500 + k*5;
  float a0=ai[0],a1=ai[1],a2=ai[2],a3=ai[3],a4=ai[4];
  float f = 0.f;
  for(int j=0;j<NB;j++){
    const float* aj = act + (size_t)j*500 + k*5;
    float l1 = fabsf(a0-aj[0]) + fabsf(a1-aj[1]) + fabsf(a2-aj[2])
             + fabsf(a3-aj[3]) + fabsf(a4-aj[4]);
    f += expf(-l1);
  }
  feats[i*NUMK + k] = f;
}

// ---------- final ----------
__global__ void final_kernel(const float* __restrict__ flat, const float* __restrict__ feats,
                             const int* __restrict__ condition, const float* __restrict__ emb,
                             const float* __restrict__ cond_w, const float* __restrict__ cond_b,
                             const float* __restrict__ fc_w, const float* __restrict__ fc_b,
                             float* __restrict__ out){
  __shared__ float red[4];
  int n = blockIdx.x, tid = threadIdx.x;
  float s = 0.f;
  const float* fr = flat + (size_t)n*FLATSZ;
  for(int q=tid; q<FLATSZ/4; q+=256){
    float4 f = *(const float4*)(fr + q*4);
    float4 w = *(const float4*)(fc_w + q*4);
    s += f.x*w.x + f.y*w.y + f.z*w.z + f.w*w.w;
  }
  for(int k=tid;k<NUMK;k+=256) s += feats[n*NUMK+k]*fc_w[FLATSZ+k];
  float ce = emb[condition[n]];
  for(int j=tid;j<50;j+=256) s += (ce*cond_w[j]+cond_b[j])*fc_w[FLATSZ+NUMK+j];
  s = block_reduce_sum(s, red);
  if(tid==0) out[n] = s + fc_b[0];
}

extern "C" void kernel_launch(void* const* d_in, const int* in_sizes, int n_in,
                              void* d_out, int out_size, void* d_ws, size_t ws_size,
                              hipStream_t stream) {
  const float* ecg   = (const float*)d_in[0];
  const int*   cond  = (const int*)  d_in[1];
  const float* w1    = (const float*)d_in[2];
  const float* b1    = (const float*)d_in[3];
  const float* u1    = (const float*)d_in[4];
  const float* w2    = (const float*)d_in[5];
  const float* b2    = (const float*)d_in[6];
  const float* u2    = (const float*)d_in[7];
  const float* w3    = (const float*)d_in[8];
  const float* b3    = (const float*)d_in[9];
  const float* u3    = (const float*)d_in[10];
  const float* emb   = (const float*)d_in[11];
  const float* condw = (const float*)d_in[12];
  const float* condb = (const float*)d_in[13];
  const float* mbw   = (const float*)d_in[14];
  const float* fcw   = (const float*)d_in[15];
  const float* fcb   = (const float*)d_in[16];

  float* ws = (float*)d_ws;
  float* scale = ws;                                            // 16 floats
  unsigned short* w2bf = (unsigned short*)(ws + 16);            // 57344 shorts (28672 f)
  unsigned short* w3bf = (unsigned short*)(ws + 16 + 28672);    // 294912 shorts (147456 f)
  unsigned short* y1bf = (unsigned short*)(ws + 176144);        // 512*20608 shorts (5,275,648 f)
  float* part  = ws + 176144;                                   // overlay y1bf (dead after conv2)
  float* act   = ws + 176144 + 4096000;                         // 256000 f
  float* feats = ws + 176144 + 4096000 + 256000;                // 51200 f
  unsigned short* y2bf = (unsigned short*)(ws + 5451792);       // 512*20608 shorts
  float* flat  = ws + 10727440;                                 // 10,354,688 f -> ends 21,082,128

  sn_kernel<<<3, 256, 0, stream>>>(w1,u1,w2,u2,w3,u3, scale);
  wprep_kernel<<<1152, 256, 0, stream>>>(w2, w3, scale, w2bf, w3bf);
  conv1_kernel<<<NB, 256, 0, stream>>>(ecg, w1, b1, scale, y1bf);
  conv2_mfma<<<NB, 256, 0, stream>>>(y1bf, w2bf, b2, y2bf);
  conv3_mfma<<<NB, 256, 0, stream>>>(y2bf, w3bf, b3, flat);
  mb_gemm_splitk<<<dim3(8,8,SPLITK), 256, 0, stream>>>(flat, mbw, part);
  mb_reduce_kernel<<<1000, 256, 0, stream>>>(part, act);
  feats_kernel<<<NB, 128, 0, stream>>>(act, feats);
  final_kernel<<<NB, 256, 0, stream>>>(flat, feats, cond, emb, condw, condb, fcw, fcb, (float*)d_out);
}

// Round 4
// 447.795 us; speedup vs baseline: 8.4013x; 2.2478x over previous
//
#include <hip/hip_runtime.h>
#include <math.h>

#define NB 512
#define LIN 640
#define NLEADS 3
#define L1O 322
#define L2O 161
#define L3O 79
#define C1N 64
#define C2N 128
#define C3N 256
#define FLATSZ 20224   // 256*79
#define NUMK 100
#define DIMK 5
#define SPLITK 16

typedef __attribute__((ext_vector_type(8))) short short8;
typedef __attribute__((ext_vector_type(4))) float f32x4;

__device__ __forceinline__ unsigned short f2bf(float x){
  unsigned u = __builtin_bit_cast(unsigned, x);
  unsigned r = u + 0x7FFFu + ((u >> 16) & 1u);
  return (unsigned short)(r >> 16);
}
__device__ __forceinline__ float bf2f(unsigned short x){
  unsigned u = ((unsigned)x) << 16;
  return __builtin_bit_cast(float, u);
}

__device__ __forceinline__ float block_reduce_sum(float val, float* red){
#pragma unroll
  for(int off=32; off>0; off>>=1) val += __shfl_down(val, off, 64);
  int lane = threadIdx.x & 63;
  int wv = threadIdx.x >> 6;
  if(lane==0) red[wv] = val;
  __syncthreads();
  int nw = blockDim.x >> 6;
  float r = red[0];
  for(int i=1;i<nw;i++) r += red[i];
  __syncthreads();
  return r;
}

// ---------- SN pass 1: v = W^T u per weight, ss[w] = ||v||^2 ----------
// blocks: 0 -> w1(C=15), 1-2 -> w2(C=448), 3-7 -> w3(C=1152)
__global__ __launch_bounds__(256)
void sn_pass1(const float* __restrict__ w1, const float* __restrict__ u1,
              const float* __restrict__ w2, const float* __restrict__ u2,
              const float* __restrict__ w3, const float* __restrict__ u3,
              float* __restrict__ v_all, float* __restrict__ ss){
  __shared__ float red[4];
  int b = blockIdx.x, tid = threadIdx.x;
  const float* w; const float* u; int O, C, off, c, widx;
  if(b==0){ w=w1; u=u1; O=64;  C=15;   off=0;   c=tid;            widx=0; }
  else if(b<3){ w=w2; u=u2; O=128; C=448; off=16;  c=(b-1)*256+tid; widx=1; }
  else { w=w3; u=u3; O=256; C=1152; off=464; c=(b-3)*256+tid;      widx=2; }
  float vv = 0.f;
  if(c < C){
    for(int o=0;o<O;o+=4){
      vv += w[(o+0)*C+c]*u[o+0] + w[(o+1)*C+c]*u[o+1]
          + w[(o+2)*C+c]*u[o+2] + w[(o+3)*C+c]*u[o+3];
    }
    v_all[off + c] = vv;
  }
  float ps = (c < C) ? vv*vv : 0.f;
  float tot = block_reduce_sum(ps, red);
  if(tid==0) atomicAdd(&ss[widx], tot);
}

// ---------- SN pass 2: Sun[w] = sum_o (w_row . v)^2 (unnormalized) ----------
// one wave per output row. blocks: 0-15 w1(64 rows), 16-47 w2(128), 48-111 w3(256)
__global__ __launch_bounds__(256)
void sn_pass2(const float* __restrict__ w1, const float* __restrict__ w2,
              const float* __restrict__ w3, const float* __restrict__ v_all,
              float* __restrict__ Sun){
  int b = blockIdx.x, tid = threadIdx.x;
  int lane = tid & 63, wv = tid >> 6;
  const float* w; int C, off, o, widx;
  if(b < 16){ w=w1; C=15;   off=0;   o=b*4+wv;      widx=0; }
  else if(b < 48){ w=w2; C=448; off=16;  o=(b-16)*4+wv; widx=1; }
  else { w=w3; C=1152; off=464; o=(b-48)*4+wv;          widx=2; }
  float t = 0.f;
  for(int c=lane; c<C; c+=64) t += w[o*C+c]*v_all[off+c];
#pragma unroll
  for(int s=32; s>0; s>>=1) t += __shfl_down(t, s, 64);
  if(lane==0) atomicAdd(&Sun[widx], t*t);
}

// ---------- SN final: scale[w] = (sqrt(S)+eps)/S, S = Sun*inv_nv^2 ----------
__global__ void sn_final(const float* __restrict__ ss, const float* __restrict__ Sun,
                         float* __restrict__ scale){
  int tid = threadIdx.x;
  if(tid < 3){
    float inv = 1.f/(sqrtf(ss[tid])+1e-12f);
    float S = Sun[tid]*inv*inv;
    scale[tid] = (sqrtf(S)+1e-12f)/S;
  }
}

// ---------- weight prep: bf16 copies of scaled w2, w3 ----------
__global__ void wprep_kernel(const float* __restrict__ w2, const float* __restrict__ w3,
                             const float* __restrict__ scale,
                             unsigned short* __restrict__ w2bf, unsigned short* __restrict__ w3bf){
  int idx = blockIdx.x*256 + threadIdx.x;
  float s2 = scale[1], s3 = scale[2];
  if(idx < C2N*448)   w2bf[idx] = f2bf(w2[idx]*s2);
  if(idx < C3N*1152)  w3bf[idx] = f2bf(w3[idx]*s3);
}

// ---------- conv1: (NB,3,640) -> y1bf (NB,64,322) bf16 ----------
__global__ void conv1_kernel(const float* __restrict__ ecg, const float* __restrict__ w1,
                             const float* __restrict__ b1, const float* __restrict__ scale,
                             unsigned short* __restrict__ y1bf){
  __shared__ float xs[NLEADS*LIN];
  __shared__ float wsh[C1N*15];
  __shared__ float bsh[C1N];
  int n = blockIdx.x, tid = threadIdx.x;
  float s = scale[0];
  for(int idx=tid; idx<NLEADS*LIN; idx+=256){
    int lead = idx/LIN, l = idx-lead*LIN;
    xs[idx] = ecg[(n*LIN + l)*NLEADS + lead];
  }
  for(int idx=tid; idx<C1N*15; idx+=256) wsh[idx] = w1[idx]*s;
  if(tid<C1N) bsh[tid] = b1[tid];
  __syncthreads();
  for(int idx=tid; idx<C1N*L1O; idx+=256){
    int o = idx/L1O, t = idx-o*L1O;
    float acc = 0.f;
    int base = 2*t - 4;
#pragma unroll
    for(int i=0;i<NLEADS;i++){
#pragma unroll
      for(int k=0;k<5;k++){
        int p = base+k;
        if((unsigned)p < (unsigned)LIN) acc += xs[i*LIN+p]*wsh[o*15+i*5+k];
      }
    }
    acc += bsh[o];
    float r = acc>=0.f ? acc : 0.2f*acc;
    y1bf[(size_t)n*20608 + o*L1O + t] = f2bf(r);
  }
}

// ---------- conv2 MFMA: per-batch GEMM (128 x 448) @ (448 x 176pad) ----------
__global__ __launch_bounds__(256)
void conv2_mfma(const unsigned short* __restrict__ y1bf, const unsigned short* __restrict__ w2bf,
                const float* __restrict__ b2, unsigned short* __restrict__ y2bf){
  __shared__ unsigned short ys[C1N*L1O];
  __shared__ unsigned short As[C2N*32];
  __shared__ unsigned short Bs[176*32];
  int n = blockIdx.x, tid = threadIdx.x;
  int lane = tid & 63, w = tid >> 6;
  {
    const uint4* src = (const uint4*)(y1bf + (size_t)n*20608);
    uint4* dst = (uint4*)ys;
#pragma unroll
    for(int q=0;q<11;q++){
      int f = q*256 + tid;
      if(f < 2576) dst[f] = src[f];
    }
  }
  f32x4 zero = {0.f,0.f,0.f,0.f};
  f32x4 acc[2][11];
#pragma unroll
  for(int i=0;i<2;i++)
#pragma unroll
    for(int j=0;j<11;j++) acc[i][j] = zero;
  __syncthreads();

  for(int ck=0; ck<14; ck++){
    int kc = ck*32;
    __syncthreads();
    {
      const char* wb = (const char*)w2bf;
      uint4* dst = (uint4*)As;
#pragma unroll
      for(int q=0;q<2;q++){
        int f = q*256 + tid;
        int row = f >> 2, col = f & 3;
        dst[f] = *(const uint4*)(wb + row*896 + kc*2 + col*16);
      }
    }
#pragma unroll
    for(int q=0;q<22;q++){
      int e = q*256 + tid;
      int t = e >> 5, kk = e & 31;
      int k = kc + kk;
      int i = k / 7;
      int r = k - i*7;
      int p = 2*t - 3 + r;
      unsigned short v = 0;
      if(t < L2O && (unsigned)p < (unsigned)L1O) v = ys[i*L1O + p];
      Bs[t*32 + kk] = v;
    }
    __syncthreads();
    short8 a[2], b[11];
#pragma unroll
    for(int mm=0;mm<2;mm++)
      a[mm] = *(const short8*)(As + ((w*2+mm)*16 + (lane&15))*32 + (lane>>4)*8);
#pragma unroll
    for(int nt=0;nt<11;nt++)
      b[nt] = *(const short8*)(Bs + (nt*16 + (lane&15))*32 + (lane>>4)*8);
#pragma unroll
    for(int mm=0;mm<2;mm++)
#pragma unroll
      for(int nt=0;nt<11;nt++)
        acc[mm][nt] = __builtin_amdgcn_mfma_f32_16x16x32_bf16(a[mm], b[nt], acc[mm][nt], 0, 0, 0);
  }
#pragma unroll
  for(int mm=0;mm<2;mm++){
#pragma unroll
    for(int reg=0;reg<4;reg++){
      int o = (w*2+mm)*16 + (lane>>4)*4 + reg;
      float bias = b2[o];
#pragma unroll
      for(int nt=0;nt<11;nt++){
        int t = nt*16 + (lane&15);
        if(t < L2O){
          float v = acc[mm][nt][reg] + bias;
          v = v>=0.f ? v : 0.2f*v;
          y2bf[(size_t)n*20608 + o*L2O + t] = f2bf(v);
        }
      }
    }
  }
}

// ---------- conv3 MFMA: per-batch GEMM (256 x 1152) @ (1152 x 80pad) -> flatbf ----------
__global__ __launch_bounds__(256)
void conv3_mfma(const unsigned short* __restrict__ y2bf, const unsigned short* __restrict__ w3bf,
                const float* __restrict__ b3, unsigned short* __restrict__ flatbf){
  __shared__ unsigned short ys[C2N*L2O];
  __shared__ unsigned short As[C3N*32];
  __shared__ unsigned short Bs[80*32];
  int n = blockIdx.x, tid = threadIdx.x;
  int lane = tid & 63, w = tid >> 6;
  {
    const uint4* src = (const uint4*)(y2bf + (size_t)n*20608);
    uint4* dst = (uint4*)ys;
#pragma unroll
    for(int q=0;q<11;q++){
      int f = q*256 + tid;
      if(f < 2576) dst[f] = src[f];
    }
  }
  f32x4 zero = {0.f,0.f,0.f,0.f};
  f32x4 acc[4][5];
#pragma unroll
  for(int i=0;i<4;i++)
#pragma unroll
    for(int j=0;j<5;j++) acc[i][j] = zero;
  __syncthreads();

  for(int ck=0; ck<36; ck++){
    int kc = ck*32;
    __syncthreads();
    {
      const char* wb = (const char*)w3bf;
      uint4* dst = (uint4*)As;
#pragma unroll
      for(int q=0;q<4;q++){
        int f = q*256 + tid;
        int row = f >> 2, col = f & 3;
        dst[f] = *(const uint4*)(wb + row*2304 + kc*2 + col*16);
      }
    }
#pragma unroll
    for(int q=0;q<10;q++){
      int e = q*256 + tid;
      int t = e >> 5, kk = e & 31;
      int k = kc + kk;
      int i = k / 9;
      int r = k - i*9;
      int p = 2*t - 2 + r;
      unsigned short v = 0;
      if(t < L3O && (unsigned)p < (unsigned)L2O) v = ys[i*L2O + p];
      Bs[t*32 + kk] = v;
    }
    __syncthreads();
    short8 a[4], b[5];
#pragma unroll
    for(int mm=0;mm<4;mm++)
      a[mm] = *(const short8*)(As + ((w*4+mm)*16 + (lane&15))*32 + (lane>>4)*8);
#pragma unroll
    for(int nt=0;nt<5;nt++)
      b[nt] = *(const short8*)(Bs + (nt*16 + (lane&15))*32 + (lane>>4)*8);
#pragma unroll
    for(int mm=0;mm<4;mm++)
#pragma unroll
      for(int nt=0;nt<5;nt++)
        acc[mm][nt] = __builtin_amdgcn_mfma_f32_16x16x32_bf16(a[mm], b[nt], acc[mm][nt], 0, 0, 0);
  }
#pragma unroll
  for(int mm=0;mm<4;mm++){
#pragma unroll
    for(int reg=0;reg<4;reg++){
      int o = (w*4+mm)*16 + (lane>>4)*4 + reg;
      float bias = b3[o];
#pragma unroll
      for(int nt=0;nt<5;nt++){
        int t = nt*16 + (lane&15);
        if(t < L3O){
          float v = acc[mm][nt][reg] + bias;
          v = v>=0.f ? v : 0.2f*v;
          flatbf[(size_t)n*FLATSZ + o*L3O + t] = f2bf(v);
        }
      }
    }
  }
}

// ---------- transpose + bf16: mbwT[n][k] = bf16(mbw[k][n]), n padded to 512 ----------
__global__ __launch_bounds__(256)
void mbw_transpose(const float* __restrict__ mbw, unsigned short* __restrict__ mbwT){
  __shared__ unsigned short tile[32][36];
  int k0 = blockIdx.x*32, n0 = blockIdx.y*32, tid = threadIdx.x;
  int r = tid >> 3, c4 = (tid & 7) * 4;
  int nbase = n0 + c4;
  if(nbase + 3 < 500){
    float4 v = *(const float4*)(mbw + (size_t)(k0+r)*500 + nbase);
    tile[r][c4+0] = f2bf(v.x);
    tile[r][c4+1] = f2bf(v.y);
    tile[r][c4+2] = f2bf(v.z);
    tile[r][c4+3] = f2bf(v.w);
  } else {
#pragma unroll
    for(int j=0;j<4;j++){
      int nn = nbase + j;
      float v = (nn < 500) ? mbw[(size_t)(k0+r)*500 + nn] : 0.f;
      tile[r][c4+j] = f2bf(v);
    }
  }
  __syncthreads();
  int nl = tid >> 3, kq = (tid & 7) * 4;
  unsigned short t0 = tile[kq+0][nl], t1 = tile[kq+1][nl];
  unsigned short t2 = tile[kq+2][nl], t3 = tile[kq+3][nl];
  uint2 p;
  p.x = (unsigned)t0 | ((unsigned)t1 << 16);
  p.y = (unsigned)t2 | ((unsigned)t3 << 16);
  *(uint2*)(mbwT + (size_t)(n0+nl)*FLATSZ + k0 + kq) = p;
}

// ---------- split-K MFMA GEMM: part[z] = flatbf(64m x Kc) @ mbwT^T(Kc x 64n) ----------
__global__ __launch_bounds__(256)
void mb_gemm_mfma(const unsigned short* __restrict__ flatbf, const unsigned short* __restrict__ mbwT,
                  float* __restrict__ part){
  __shared__ unsigned short As[64*32];
  __shared__ unsigned short Bs[64*32];
  int tid = threadIdx.x;
  int lane = tid & 63, w = tid >> 6;
  int m0 = blockIdx.x*64, n0 = blockIdx.y*64, bz = blockIdx.z;
  int t_start = bz*39 + (bz<8 ? bz : 8);
  int t_count = 39 + (bz<8 ? 1 : 0);
  int k0 = t_start*32;
  f32x4 zero = {0.f,0.f,0.f,0.f};
  f32x4 acc[4];
#pragma unroll
  for(int i=0;i<4;i++) acc[i] = zero;
  int arow = tid >> 2, acol = (tid & 3) * 8;
  for(int t=0; t<t_count; t++, k0+=32){
    __syncthreads();
    ((uint4*)As)[tid] = *(const uint4*)(flatbf + (size_t)(m0+arow)*FLATSZ + k0 + acol);
    ((uint4*)Bs)[tid] = *(const uint4*)(mbwT  + (size_t)(n0+arow)*FLATSZ + k0 + acol);
    __syncthreads();
    short8 a = *(const short8*)(As + (w*16 + (lane&15))*32 + (lane>>4)*8);
#pragma unroll
    for(int nt=0;nt<4;nt++){
      short8 b = *(const short8*)(Bs + (nt*16 + (lane&15))*32 + (lane>>4)*8);
      acc[nt] = __builtin_amdgcn_mfma_f32_16x16x32_bf16(a, b, acc[nt], 0, 0, 0);
    }
  }
  float* po = part + (size_t)bz*NB*500;
#pragma unroll
  for(int nt=0;nt<4;nt++){
#pragma unroll
    for(int reg=0;reg<4;reg++){
      int m = m0 + w*16 + (lane>>4)*4 + reg;
      int c = n0 + nt*16 + (lane&15);
      if(c < 500) po[(size_t)m*500 + c] = acc[nt][reg];
    }
  }
}

__global__ void mb_reduce_kernel(const float* __restrict__ part, float* __restrict__ act){
  int idx = blockIdx.x*256 + threadIdx.x;
  float s = 0.f;
#pragma unroll
  for(int z=0;z<SPLITK;z++) s += part[(size_t)z*NB*500 + idx];
  act[idx] = s;
}

// ---------- minibatch features ----------
__global__ void feats_kernel(const float* __restrict__ act, float* __restrict__ feats){
  int i = blockIdx.x, k = threadIdx.x;
  if(k >= NUMK) return;
  const float* ai = act + (size_t)i*500 + k*5;
  float a0=ai[0],a1=ai[1],a2=ai[2],a3=ai[3],a4=ai[4];
  float f = 0.f;
  for(int j=0;j<NB;j++){
    const float* aj = act + (size_t)j*500 + k*5;
    float l1 = fabsf(a0-aj[0]) + fabsf(a1-aj[1]) + fabsf(a2-aj[2])
             + fabsf(a3-aj[3]) + fabsf(a4-aj[4]);
    f += expf(-l1);
  }
  feats[i*NUMK + k] = f;
}

// ---------- final: out[n] = [flat|feats|cond] . fc_w + fc_b ----------
__global__ void final_kernel(const unsigned short* __restrict__ flatbf, const float* __restrict__ feats,
                             const int* __restrict__ condition, const float* __restrict__ emb,
                             const float* __restrict__ cond_w, const float* __restrict__ cond_b,
                             const float* __restrict__ fc_w, const float* __restrict__ fc_b,
                             float* __restrict__ out){
  __shared__ float red[4];
  int n = blockIdx.x, tid = threadIdx.x;
  float s = 0.f;
  const unsigned short* fr = flatbf + (size_t)n*FLATSZ;
  for(int q=tid; q<FLATSZ/8; q+=256){
    uint4 u = *(const uint4*)(fr + q*8);
    float4 wa = *(const float4*)(fc_w + q*8);
    float4 wb = *(const float4*)(fc_w + q*8 + 4);
    s += bf2f((unsigned short)(u.x & 0xffff))*wa.x + bf2f((unsigned short)(u.x >> 16))*wa.y
       + bf2f((unsigned short)(u.y & 0xffff))*wa.z + bf2f((unsigned short)(u.y >> 16))*wa.w
       + bf2f((unsigned short)(u.z & 0xffff))*wb.x + bf2f((unsigned short)(u.z >> 16))*wb.y
       + bf2f((unsigned short)(u.w & 0xffff))*wb.z + bf2f((unsigned short)(u.w >> 16))*wb.w;
  }
  for(int k=tid;k<NUMK;k+=256) s += feats[n*NUMK+k]*fc_w[FLATSZ+k];
  float ce = emb[condition[n]];
  for(int j=tid;j<50;j+=256) s += (ce*cond_w[j]+cond_b[j])*fc_w[FLATSZ+NUMK+j];
  s = block_reduce_sum(s, red);
  if(tid==0) out[n] = s + fc_b[0];
}

extern "C" void kernel_launch(void* const* d_in, const int* in_sizes, int n_in,
                              void* d_out, int out_size, void* d_ws, size_t ws_size,
                              hipStream_t stream) {
  const float* ecg   = (const float*)d_in[0];
  const int*   cond  = (const int*)  d_in[1];
  const float* w1    = (const float*)d_in[2];
  const float* b1    = (const float*)d_in[3];
  const float* u1    = (const float*)d_in[4];
  const float* w2    = (const float*)d_in[5];
  const float* b2    = (const float*)d_in[6];
  const float* u2    = (const float*)d_in[7];
  const float* w3    = (const float*)d_in[8];
  const float* b3    = (const float*)d_in[9];
  const float* u3    = (const float*)d_in[10];
  const float* emb   = (const float*)d_in[11];
  const float* condw = (const float*)d_in[12];
  const float* condb = (const float*)d_in[13];
  const float* mbw   = (const float*)d_in[14];
  const float* fcw   = (const float*)d_in[15];
  const float* fcb   = (const float*)d_in[16];

  float* ws = (float*)d_ws;
  float* scale = ws;                                    // 0..16
  float* ssbuf = ws + 16;                               // 3 floats
  float* Sunbuf= ws + 24;                               // 3 floats
  float* v_all = ws + 32;                               // 1616 -> ends 1648
  unsigned short* w2bf = (unsigned short*)(ws + 1648);  // 28672 f -> 30320
  unsigned short* w3bf = (unsigned short*)(ws + 30320); // 147456 f -> 177776
  unsigned short* y1bf = (unsigned short*)(ws + 177776);   // 5,275,648 f -> 5,453,424
  unsigned short* y2bf = (unsigned short*)(ws + 5453424);  // 5,275,648 f -> 10,729,072
  unsigned short* mbwT = (unsigned short*)(ws + 5453424);  // overlays y2bf (dead after conv3)
  unsigned short* flatbf = (unsigned short*)(ws + 10729072); // 5,177,344 f -> 15,906,416
  float* part  = ws + 177776;    // overlays y1bf (dead after conv2): 4,096,000
  float* act   = ws + 4273776;   // 256,000
  float* feats = ws + 4529776;   // 51,200 (ends 4,580,976 < 5,453,424)

  hipMemsetAsync((char*)d_ws + 64, 0, 64, stream);   // zero ssbuf/Sunbuf
  sn_pass1<<<8, 256, 0, stream>>>(w1,u1,w2,u2,w3,u3, v_all, ssbuf);
  sn_pass2<<<112, 256, 0, stream>>>(w1,w2,w3, v_all, Sunbuf);
  sn_final<<<1, 64, 0, stream>>>(ssbuf, Sunbuf, scale);
  wprep_kernel<<<1152, 256, 0, stream>>>(w2, w3, scale, w2bf, w3bf);
  conv1_kernel<<<NB, 256, 0, stream>>>(ecg, w1, b1, scale, y1bf);
  conv2_mfma<<<NB, 256, 0, stream>>>(y1bf, w2bf, b2, y2bf);
  conv3_mfma<<<NB, 256, 0, stream>>>(y2bf, w3bf, b3, flatbf);
  mbw_transpose<<<dim3(632,16), 256, 0, stream>>>(mbw, mbwT);
  mb_gemm_mfma<<<dim3(8,8,SPLITK), 256, 0, stream>>>(flatbf, mbwT, part);
  mb_reduce_kernel<<<1000, 256, 0, stream>>>(part, act);
  feats_kernel<<<NB, 128, 0, stream>>>(act, feats);
  final_kernel<<<NB, 256, 0, stream>>>(flatbf, feats, cond, emb, condw, condb, fcw, fcb, (float*)d_out);
}

// Round 5
// 410.124 us; speedup vs baseline: 9.1730x; 1.0919x over previous
//
#include <hip/hip_runtime.h>
#include <math.h>

#define NB 512
#define LIN 640
#define NLEADS 3
#define L1O 322
#define L2O 161
#define L3O 79
#define C1N 64
#define C2N 128
#define C3N 256
#define FLATSZ 20224   // 256*79
#define NUMK 100
#define DIMK 5
#define SPLITK 16

typedef __attribute__((ext_vector_type(8))) short short8;
typedef __attribute__((ext_vector_type(4))) float f32x4;

__device__ __forceinline__ unsigned short f2bf(float x){
  unsigned u = __builtin_bit_cast(unsigned, x);
  unsigned r = u + 0x7FFFu + ((u >> 16) & 1u);
  return (unsigned short)(r >> 16);
}
__device__ __forceinline__ float bf2f(unsigned short x){
  unsigned u = ((unsigned)x) << 16;
  return __builtin_bit_cast(float, u);
}

__device__ __forceinline__ float block_reduce_sum(float val, float* red){
#pragma unroll
  for(int off=32; off>0; off>>=1) val += __shfl_down(val, off, 64);
  int lane = threadIdx.x & 63;
  int wv = threadIdx.x >> 6;
  if(lane==0) red[wv] = val;
  __syncthreads();
  int nw = blockDim.x >> 6;
  float r = red[0];
  for(int i=1;i<nw;i++) r += red[i];
  __syncthreads();
  return r;
}

// ---------- SN pass 1: v = W^T u per weight, ss[w] = ||v||^2 ----------
__global__ __launch_bounds__(256)
void sn_pass1(const float* __restrict__ w1, const float* __restrict__ u1,
              const float* __restrict__ w2, const float* __restrict__ u2,
              const float* __restrict__ w3, const float* __restrict__ u3,
              float* __restrict__ v_all, float* __restrict__ ss){
  __shared__ float red[4];
  int b = blockIdx.x, tid = threadIdx.x;
  const float* w; const float* u; int O, C, off, c, widx;
  if(b==0){ w=w1; u=u1; O=64;  C=15;   off=0;   c=tid;            widx=0; }
  else if(b<3){ w=w2; u=u2; O=128; C=448; off=16;  c=(b-1)*256+tid; widx=1; }
  else { w=w3; u=u3; O=256; C=1152; off=464; c=(b-3)*256+tid;      widx=2; }
  float vv = 0.f;
  if(c < C){
    for(int o=0;o<O;o+=4){
      vv += w[(o+0)*C+c]*u[o+0] + w[(o+1)*C+c]*u[o+1]
          + w[(o+2)*C+c]*u[o+2] + w[(o+3)*C+c]*u[o+3];
    }
    v_all[off + c] = vv;
  }
  float ps = (c < C) ? vv*vv : 0.f;
  float tot = block_reduce_sum(ps, red);
  if(tid==0) atomicAdd(&ss[widx], tot);
}

// ---------- SN pass 2: Sun[w] = sum_o (w_row . v)^2 ----------
__global__ __launch_bounds__(256)
void sn_pass2(const float* __restrict__ w1, const float* __restrict__ w2,
              const float* __restrict__ w3, const float* __restrict__ v_all,
              float* __restrict__ Sun){
  int b = blockIdx.x, tid = threadIdx.x;
  int lane = tid & 63, wv = tid >> 6;
  const float* w; int C, off, o, widx;
  if(b < 16){ w=w1; C=15;   off=0;   o=b*4+wv;      widx=0; }
  else if(b < 48){ w=w2; C=448; off=16;  o=(b-16)*4+wv; widx=1; }
  else { w=w3; C=1152; off=464; o=(b-48)*4+wv;          widx=2; }
  float t = 0.f;
  for(int c=lane; c<C; c+=64) t += w[o*C+c]*v_all[off+c];
#pragma unroll
  for(int s=32; s>0; s>>=1) t += __shfl_down(t, s, 64);
  if(lane==0) atomicAdd(&Sun[widx], t*t);
}

__global__ void sn_final(const float* __restrict__ ss, const float* __restrict__ Sun,
                         float* __restrict__ scale){
  int tid = threadIdx.x;
  if(tid < 3){
    float inv = 1.f/(sqrtf(ss[tid])+1e-12f);
    float S = Sun[tid]*inv*inv;
    scale[tid] = (sqrtf(S)+1e-12f)/S;
  }
}

// ---------- weight prep ----------
__global__ void wprep_kernel(const float* __restrict__ w2, const float* __restrict__ w3,
                             const float* __restrict__ scale,
                             unsigned short* __restrict__ w2bf, unsigned short* __restrict__ w3bf){
  int idx = blockIdx.x*256 + threadIdx.x;
  float s2 = scale[1], s3 = scale[2];
  if(idx < C2N*448)   w2bf[idx] = f2bf(w2[idx]*s2);
  if(idx < C3N*1152)  w3bf[idx] = f2bf(w3[idx]*s3);
}

// ---------- conv1 ----------
__global__ void conv1_kernel(const float* __restrict__ ecg, const float* __restrict__ w1,
                             const float* __restrict__ b1, const float* __restrict__ scale,
                             unsigned short* __restrict__ y1bf){
  __shared__ float xs[NLEADS*LIN];
  __shared__ float wsh[C1N*15];
  __shared__ float bsh[C1N];
  int n = blockIdx.x, tid = threadIdx.x;
  float s = scale[0];
  for(int idx=tid; idx<NLEADS*LIN; idx+=256){
    int lead = idx/LIN, l = idx-lead*LIN;
    xs[idx] = ecg[(n*LIN + l)*NLEADS + lead];
  }
  for(int idx=tid; idx<C1N*15; idx+=256) wsh[idx] = w1[idx]*s;
  if(tid<C1N) bsh[tid] = b1[tid];
  __syncthreads();
  for(int idx=tid; idx<C1N*L1O; idx+=256){
    int o = idx/L1O, t = idx-o*L1O;
    float acc = 0.f;
    int base = 2*t - 4;
#pragma unroll
    for(int i=0;i<NLEADS;i++){
#pragma unroll
      for(int k=0;k<5;k++){
        int p = base+k;
        if((unsigned)p < (unsigned)LIN) acc += xs[i*LIN+p]*wsh[o*15+i*5+k];
      }
    }
    acc += bsh[o];
    float r = acc>=0.f ? acc : 0.2f*acc;
    y1bf[(size_t)n*20608 + o*L1O + t] = f2bf(r);
  }
}

// ---------- conv2 MFMA ----------
__global__ __launch_bounds__(256)
void conv2_mfma(const unsigned short* __restrict__ y1bf, const unsigned short* __restrict__ w2bf,
                const float* __restrict__ b2, unsigned short* __restrict__ y2bf){
  __shared__ unsigned short ys[C1N*L1O];
  __shared__ unsigned short As[C2N*32];
  __shared__ unsigned short Bs[176*32];
  int n = blockIdx.x, tid = threadIdx.x;
  int lane = tid & 63, w = tid >> 6;
  {
    const uint4* src = (const uint4*)(y1bf + (size_t)n*20608);
    uint4* dst = (uint4*)ys;
#pragma unroll
    for(int q=0;q<11;q++){
      int f = q*256 + tid;
      if(f < 2576) dst[f] = src[f];
    }
  }
  f32x4 zero = {0.f,0.f,0.f,0.f};
  f32x4 acc[2][11];
#pragma unroll
  for(int i=0;i<2;i++)
#pragma unroll
    for(int j=0;j<11;j++) acc[i][j] = zero;
  __syncthreads();

  for(int ck=0; ck<14; ck++){
    int kc = ck*32;
    __syncthreads();
    {
      const char* wb = (const char*)w2bf;
      uint4* dst = (uint4*)As;
#pragma unroll
      for(int q=0;q<2;q++){
        int f = q*256 + tid;
        int row = f >> 2, col = f & 3;
        dst[f] = *(const uint4*)(wb + row*896 + kc*2 + col*16);
      }
    }
#pragma unroll
    for(int q=0;q<22;q++){
      int e = q*256 + tid;
      int t = e >> 5, kk = e & 31;
      int k = kc + kk;
      int i = k / 7;
      int r = k - i*7;
      int p = 2*t - 3 + r;
      unsigned short v = 0;
      if(t < L2O && (unsigned)p < (unsigned)L1O) v = ys[i*L1O + p];
      Bs[t*32 + kk] = v;
    }
    __syncthreads();
    short8 a[2], b[11];
#pragma unroll
    for(int mm=0;mm<2;mm++)
      a[mm] = *(const short8*)(As + ((w*2+mm)*16 + (lane&15))*32 + (lane>>4)*8);
#pragma unroll
    for(int nt=0;nt<11;nt++)
      b[nt] = *(const short8*)(Bs + (nt*16 + (lane&15))*32 + (lane>>4)*8);
#pragma unroll
    for(int mm=0;mm<2;mm++)
#pragma unroll
      for(int nt=0;nt<11;nt++)
        acc[mm][nt] = __builtin_amdgcn_mfma_f32_16x16x32_bf16(a[mm], b[nt], acc[mm][nt], 0, 0, 0);
  }
#pragma unroll
  for(int mm=0;mm<2;mm++){
#pragma unroll
    for(int reg=0;reg<4;reg++){
      int o = (w*2+mm)*16 + (lane>>4)*4 + reg;
      float bias = b2[o];
#pragma unroll
      for(int nt=0;nt<11;nt++){
        int t = nt*16 + (lane&15);
        if(t < L2O){
          float v = acc[mm][nt][reg] + bias;
          v = v>=0.f ? v : 0.2f*v;
          y2bf[(size_t)n*20608 + o*L2O + t] = f2bf(v);
        }
      }
    }
  }
}

// ---------- conv3 MFMA -> flatbf ----------
__global__ __launch_bounds__(256)
void conv3_mfma(const unsigned short* __restrict__ y2bf, const unsigned short* __restrict__ w3bf,
                const float* __restrict__ b3, unsigned short* __restrict__ flatbf){
  __shared__ unsigned short ys[C2N*L2O];
  __shared__ unsigned short As[C3N*32];
  __shared__ unsigned short Bs[80*32];
  int n = blockIdx.x, tid = threadIdx.x;
  int lane = tid & 63, w = tid >> 6;
  {
    const uint4* src = (const uint4*)(y2bf + (size_t)n*20608);
    uint4* dst = (uint4*)ys;
#pragma unroll
    for(int q=0;q<11;q++){
      int f = q*256 + tid;
      if(f < 2576) dst[f] = src[f];
    }
  }
  f32x4 zero = {0.f,0.f,0.f,0.f};
  f32x4 acc[4][5];
#pragma unroll
  for(int i=0;i<4;i++)
#pragma unroll
    for(int j=0;j<5;j++) acc[i][j] = zero;
  __syncthreads();

  for(int ck=0; ck<36; ck++){
    int kc = ck*32;
    __syncthreads();
    {
      const char* wb = (const char*)w3bf;
      uint4* dst = (uint4*)As;
#pragma unroll
      for(int q=0;q<4;q++){
        int f = q*256 + tid;
        int row = f >> 2, col = f & 3;
        dst[f] = *(const uint4*)(wb + row*2304 + kc*2 + col*16);
      }
    }
#pragma unroll
    for(int q=0;q<10;q++){
      int e = q*256 + tid;
      int t = e >> 5, kk = e & 31;
      int k = kc + kk;
      int i = k / 9;
      int r = k - i*9;
      int p = 2*t - 2 + r;
      unsigned short v = 0;
      if(t < L3O && (unsigned)p < (unsigned)L2O) v = ys[i*L2O + p];
      Bs[t*32 + kk] = v;
    }
    __syncthreads();
    short8 a[4], b[5];
#pragma unroll
    for(int mm=0;mm<4;mm++)
      a[mm] = *(const short8*)(As + ((w*4+mm)*16 + (lane&15))*32 + (lane>>4)*8);
#pragma unroll
    for(int nt=0;nt<5;nt++)
      b[nt] = *(const short8*)(Bs + (nt*16 + (lane&15))*32 + (lane>>4)*8);
#pragma unroll
    for(int mm=0;mm<4;mm++)
#pragma unroll
      for(int nt=0;nt<5;nt++)
        acc[mm][nt] = __builtin_amdgcn_mfma_f32_16x16x32_bf16(a[mm], b[nt], acc[mm][nt], 0, 0, 0);
  }
#pragma unroll
  for(int mm=0;mm<4;mm++){
#pragma unroll
    for(int reg=0;reg<4;reg++){
      int o = (w*4+mm)*16 + (lane>>4)*4 + reg;
      float bias = b3[o];
#pragma unroll
      for(int nt=0;nt<5;nt++){
        int t = nt*16 + (lane&15);
        if(t < L3O){
          float v = acc[mm][nt][reg] + bias;
          v = v>=0.f ? v : 0.2f*v;
          flatbf[(size_t)n*FLATSZ + o*L3O + t] = f2bf(v);
        }
      }
    }
  }
}

// ---------- transpose + bf16: mbwT[n][k] ----------
__global__ __launch_bounds__(256)
void mbw_transpose(const float* __restrict__ mbw, unsigned short* __restrict__ mbwT){
  __shared__ unsigned short tile[32][36];
  int k0 = blockIdx.x*32, n0 = blockIdx.y*32, tid = threadIdx.x;
  int r = tid >> 3, c4 = (tid & 7) * 4;
  int nbase = n0 + c4;
  if(nbase + 3 < 500){
    float4 v = *(const float4*)(mbw + (size_t)(k0+r)*500 + nbase);
    tile[r][c4+0] = f2bf(v.x);
    tile[r][c4+1] = f2bf(v.y);
    tile[r][c4+2] = f2bf(v.z);
    tile[r][c4+3] = f2bf(v.w);
  } else {
#pragma unroll
    for(int j=0;j<4;j++){
      int nn = nbase + j;
      float v = (nn < 500) ? mbw[(size_t)(k0+r)*500 + nn] : 0.f;
      tile[r][c4+j] = f2bf(v);
    }
  }
  __syncthreads();
  int nl = tid >> 3, kq = (tid & 7) * 4;
  unsigned short t0 = tile[kq+0][nl], t1 = tile[kq+1][nl];
  unsigned short t2 = tile[kq+2][nl], t3 = tile[kq+3][nl];
  uint2 p;
  p.x = (unsigned)t0 | ((unsigned)t1 << 16);
  p.y = (unsigned)t2 | ((unsigned)t3 << 16);
  *(uint2*)(mbwT + (size_t)(n0+nl)*FLATSZ + k0 + kq) = p;
}

// ---------- split-K MFMA GEMM ----------
__global__ __launch_bounds__(256)
void mb_gemm_mfma(const unsigned short* __restrict__ flatbf, const unsigned short* __restrict__ mbwT,
                  float* __restrict__ part){
  __shared__ unsigned short As[64*32];
  __shared__ unsigned short Bs[64*32];
  int tid = threadIdx.x;
  int lane = tid & 63, w = tid >> 6;
  int m0 = blockIdx.x*64, n0 = blockIdx.y*64, bz = blockIdx.z;
  int t_start = bz*39 + (bz<8 ? bz : 8);
  int t_count = 39 + (bz<8 ? 1 : 0);
  int k0 = t_start*32;
  f32x4 zero = {0.f,0.f,0.f,0.f};
  f32x4 acc[4];
#pragma unroll
  for(int i=0;i<4;i++) acc[i] = zero;
  int arow = tid >> 2, acol = (tid & 3) * 8;
  for(int t=0; t<t_count; t++, k0+=32){
    __syncthreads();
    ((uint4*)As)[tid] = *(const uint4*)(flatbf + (size_t)(m0+arow)*FLATSZ + k0 + acol);
    ((uint4*)Bs)[tid] = *(const uint4*)(mbwT  + (size_t)(n0+arow)*FLATSZ + k0 + acol);
    __syncthreads();
    short8 a = *(const short8*)(As + (w*16 + (lane&15))*32 + (lane>>4)*8);
#pragma unroll
    for(int nt=0;nt<4;nt++){
      short8 b = *(const short8*)(Bs + (nt*16 + (lane&15))*32 + (lane>>4)*8);
      acc[nt] = __builtin_amdgcn_mfma_f32_16x16x32_bf16(a, b, acc[nt], 0, 0, 0);
    }
  }
  float* po = part + (size_t)bz*NB*500;
#pragma unroll
  for(int nt=0;nt<4;nt++){
#pragma unroll
    for(int reg=0;reg<4;reg++){
      int m = m0 + w*16 + (lane>>4)*4 + reg;
      int c = n0 + nt*16 + (lane&15);
      if(c < 500) po[(size_t)m*500 + c] = acc[nt][reg];
    }
  }
}

// ---------- reduce partials -> actT[c][n] (transposed for feats) ----------
__global__ void mb_reduce_kernel(const float* __restrict__ part, float* __restrict__ actT){
  int idx = blockIdx.x*256 + threadIdx.x;   // n*500+c
  float s = 0.f;
#pragma unroll
  for(int z=0;z<SPLITK;z++) s += part[(size_t)z*NB*500 + idx];
  int n = idx/500, c = idx - n*500;
  actT[(size_t)c*NB + n] = s;
}

// ---------- minibatch features: block = 4 i's x 10 k's, lanes = j ----------
__global__ __launch_bounds__(256)
void feats_kernel(const float* __restrict__ actT, float* __restrict__ feats){
  __shared__ float ash[4][50];
  __shared__ float pred[4][4];   // [wave][ii]
  int i0 = blockIdx.x*4, k0 = blockIdx.y*10;
  int tid = threadIdx.x, lane = tid & 63, wv = tid >> 6;
  if(tid < 200){
    int ii = tid/50, c = tid - ii*50;
    ash[ii][c] = actT[(size_t)(k0*5+c)*NB + i0 + ii];
  }
  __syncthreads();
  const float LOG2E = 1.4426950408889634f;
  int j1 = tid, j2 = tid + 256;
  for(int kk=0; kk<10; kk++){
    const float* r0 = actT + (size_t)(k0+kk)*5*NB;
    float xa0=r0[j1], xa1=r0[NB+j1], xa2=r0[2*NB+j1], xa3=r0[3*NB+j1], xa4=r0[4*NB+j1];
    float xb0=r0[j2], xb1=r0[NB+j2], xb2=r0[2*NB+j2], xb3=r0[3*NB+j2], xb4=r0[4*NB+j2];
    float f[4];
#pragma unroll
    for(int ii=0; ii<4; ii++){
      float a0=ash[ii][kk*5+0], a1=ash[ii][kk*5+1], a2=ash[ii][kk*5+2],
            a3=ash[ii][kk*5+3], a4=ash[ii][kk*5+4];
      float la = fabsf(xa0-a0)+fabsf(xa1-a1)+fabsf(xa2-a2)+fabsf(xa3-a3)+fabsf(xa4-a4);
      float lb = fabsf(xb0-a0)+fabsf(xb1-a1)+fabsf(xb2-a2)+fabsf(xb3-a3)+fabsf(xb4-a4);
      f[ii] = exp2f(-LOG2E*la) + exp2f(-LOG2E*lb);
    }
#pragma unroll
    for(int ii=0; ii<4; ii++){
      float v = f[ii];
#pragma unroll
      for(int s=32; s>0; s>>=1) v += __shfl_down(v, s, 64);
      if(lane==0) pred[wv][ii] = v;
    }
    __syncthreads();
    if(tid < 4){
      float v = pred[0][tid] + pred[1][tid] + pred[2][tid] + pred[3][tid];
      feats[(size_t)(i0+tid)*NUMK + k0 + kk] = v;
    }
    __syncthreads();
  }
}

// ---------- final ----------
__global__ void final_kernel(const unsigned short* __restrict__ flatbf, const float* __restrict__ feats,
                             const int* __restrict__ condition, const float* __restrict__ emb,
                             const float* __restrict__ cond_w, const float* __restrict__ cond_b,
                             const float* __restrict__ fc_w, const float* __restrict__ fc_b,
                             float* __restrict__ out){
  __shared__ float red[4];
  int n = blockIdx.x, tid = threadIdx.x;
  float s = 0.f;
  const unsigned short* fr = flatbf + (size_t)n*FLATSZ;
  for(int q=tid; q<FLATSZ/8; q+=256){
    uint4 u = *(const uint4*)(fr + q*8);
    float4 wa = *(const float4*)(fc_w + q*8);
    float4 wb = *(const float4*)(fc_w + q*8 + 4);
    s += bf2f((unsigned short)(u.x & 0xffff))*wa.x + bf2f((unsigned short)(u.x >> 16))*wa.y
       + bf2f((unsigned short)(u.y & 0xffff))*wa.z + bf2f((unsigned short)(u.y >> 16))*wa.w
       + bf2f((unsigned short)(u.z & 0xffff))*wb.x + bf2f((unsigned short)(u.z >> 16))*wb.y
       + bf2f((unsigned short)(u.w & 0xffff))*wb.z + bf2f((unsigned short)(u.w >> 16))*wb.w;
  }
  for(int k=tid;k<NUMK;k+=256) s += feats[n*NUMK+k]*fc_w[FLATSZ+k];
  float ce = emb[condition[n]];
  for(int j=tid;j<50;j+=256) s += (ce*cond_w[j]+cond_b[j])*fc_w[FLATSZ+NUMK+j];
  s = block_reduce_sum(s, red);
  if(tid==0) out[n] = s + fc_b[0];
}

extern "C" void kernel_launch(void* const* d_in, const int* in_sizes, int n_in,
                              void* d_out, int out_size, void* d_ws, size_t ws_size,
                              hipStream_t stream) {
  const float* ecg   = (const float*)d_in[0];
  const int*   cond  = (const int*)  d_in[1];
  const float* w1    = (const float*)d_in[2];
  const float* b1    = (const float*)d_in[3];
  const float* u1    = (const float*)d_in[4];
  const float* w2    = (const float*)d_in[5];
  const float* b2    = (const float*)d_in[6];
  const float* u2    = (const float*)d_in[7];
  const float* w3    = (const float*)d_in[8];
  const float* b3    = (const float*)d_in[9];
  const float* u3    = (const float*)d_in[10];
  const float* emb   = (const float*)d_in[11];
  const float* condw = (const float*)d_in[12];
  const float* condb = (const float*)d_in[13];
  const float* mbw   = (const float*)d_in[14];
  const float* fcw   = (const float*)d_in[15];
  const float* fcb   = (const float*)d_in[16];

  float* ws = (float*)d_ws;
  float* scale = ws;                                    // 0..16
  float* ssbuf = ws + 16;                               // 3 floats
  float* Sunbuf= ws + 24;                               // 3 floats
  float* v_all = ws + 32;                               // 1616 -> ends 1648
  unsigned short* w2bf = (unsigned short*)(ws + 1648);  // 28672 f -> 30320
  unsigned short* w3bf = (unsigned short*)(ws + 30320); // 147456 f -> 177776
  unsigned short* y1bf = (unsigned short*)(ws + 177776);   // 5,275,648 f -> 5,453,424
  unsigned short* y2bf = (unsigned short*)(ws + 5453424);  // 5,275,648 f -> 10,729,072
  unsigned short* mbwT = (unsigned short*)(ws + 5453424);  // overlays y2bf (dead after conv3)
  unsigned short* flatbf = (unsigned short*)(ws + 10729072); // 5,177,344 f -> 15,906,416
  float* part  = ws + 177776;    // overlays y1bf (dead after conv2): 4,096,000
  float* actT  = ws + 4273776;   // 256,000 (transposed [c][n])
  float* feats = ws + 4529776;   // 51,200 (ends 4,580,976 < 5,453,424)

  hipMemsetAsync((char*)d_ws + 64, 0, 64, stream);   // zero ssbuf/Sunbuf
  sn_pass1<<<8, 256, 0, stream>>>(w1,u1,w2,u2,w3,u3, v_all, ssbuf);
  sn_pass2<<<112, 256, 0, stream>>>(w1,w2,w3, v_all, Sunbuf);
  sn_final<<<1, 64, 0, stream>>>(ssbuf, Sunbuf, scale);
  wprep_kernel<<<1152, 256, 0, stream>>>(w2, w3, scale, w2bf, w3bf);
  conv1_kernel<<<NB, 256, 0, stream>>>(ecg, w1, b1, scale, y1bf);
  conv2_mfma<<<NB, 256, 0, stream>>>(y1bf, w2bf, b2, y2bf);
  conv3_mfma<<<NB, 256, 0, stream>>>(y2bf, w3bf, b3, flatbf);
  mbw_transpose<<<dim3(632,16), 256, 0, stream>>>(mbw, mbwT);
  mb_gemm_mfma<<<dim3(8,8,SPLITK), 256, 0, stream>>>(flatbf, mbwT, part);
  mb_reduce_kernel<<<1000, 256, 0, stream>>>(part, actT);
  feats_kernel<<<dim3(128,10), 256, 0, stream>>>(actT, feats);
  final_kernel<<<NB, 256, 0, stream>>>(flatbf, feats, cond, emb, condw, condb, fcw, fcb, (float*)d_out);
}

// Round 6
// 373.296 us; speedup vs baseline: 10.0780x; 1.0987x over previous
//
#include <hip/hip_runtime.h>
#include <math.h>

#define NB 512
#define LIN 640
#define NLEADS 3
#define L1O 322
#define L2O 161
#define L3O 79
#define C1N 64
#define C2N 128
#define C3N 256
#define FLATSZ 20224   // 256*79
#define NUMK 100
#define DIMK 5
#define SPLITK 16

typedef __attribute__((ext_vector_type(8))) short short8;
typedef __attribute__((ext_vector_type(4))) float f32x4;

__device__ __forceinline__ unsigned short f2bf(float x){
  unsigned u = __builtin_bit_cast(unsigned, x);
  unsigned r = u + 0x7FFFu + ((u >> 16) & 1u);
  return (unsigned short)(r >> 16);
}
__device__ __forceinline__ float bf2f(unsigned short x){
  unsigned u = ((unsigned)x) << 16;
  return __builtin_bit_cast(float, u);
}

__device__ __forceinline__ float block_reduce_sum(float val, float* red){
#pragma unroll
  for(int off=32; off>0; off>>=1) val += __shfl_down(val, off, 64);
  int lane = threadIdx.x & 63;
  int wv = threadIdx.x >> 6;
  if(lane==0) red[wv] = val;
  __syncthreads();
  int nw = blockDim.x >> 6;
  float r = red[0];
  for(int i=1;i<nw;i++) r += red[i];
  __syncthreads();
  return r;
}

// ---------- SN pass 1 ----------
__global__ __launch_bounds__(256)
void sn_pass1(const float* __restrict__ w1, const float* __restrict__ u1,
              const float* __restrict__ w2, const float* __restrict__ u2,
              const float* __restrict__ w3, const float* __restrict__ u3,
              float* __restrict__ v_all, float* __restrict__ ss){
  __shared__ float red[4];
  int b = blockIdx.x, tid = threadIdx.x;
  const float* w; const float* u; int O, C, off, c, widx;
  if(b==0){ w=w1; u=u1; O=64;  C=15;   off=0;   c=tid;            widx=0; }
  else if(b<3){ w=w2; u=u2; O=128; C=448; off=16;  c=(b-1)*256+tid; widx=1; }
  else { w=w3; u=u3; O=256; C=1152; off=464; c=(b-3)*256+tid;      widx=2; }
  float vv = 0.f;
  if(c < C){
    for(int o=0;o<O;o+=4){
      vv += w[(o+0)*C+c]*u[o+0] + w[(o+1)*C+c]*u[o+1]
          + w[(o+2)*C+c]*u[o+2] + w[(o+3)*C+c]*u[o+3];
    }
    v_all[off + c] = vv;
  }
  float ps = (c < C) ? vv*vv : 0.f;
  float tot = block_reduce_sum(ps, red);
  if(tid==0) atomicAdd(&ss[widx], tot);
}

// ---------- SN pass 2 ----------
__global__ __launch_bounds__(256)
void sn_pass2(const float* __restrict__ w1, const float* __restrict__ w2,
              const float* __restrict__ w3, const float* __restrict__ v_all,
              float* __restrict__ Sun){
  int b = blockIdx.x, tid = threadIdx.x;
  int lane = tid & 63, wv = tid >> 6;
  const float* w; int C, off, o, widx;
  if(b < 16){ w=w1; C=15;   off=0;   o=b*4+wv;      widx=0; }
  else if(b < 48){ w=w2; C=448; off=16;  o=(b-16)*4+wv; widx=1; }
  else { w=w3; C=1152; off=464; o=(b-48)*4+wv;          widx=2; }
  float t = 0.f;
  for(int c=lane; c<C; c+=64) t += w[o*C+c]*v_all[off+c];
#pragma unroll
  for(int s=32; s>0; s>>=1) t += __shfl_down(t, s, 64);
  if(lane==0) atomicAdd(&Sun[widx], t*t);
}

__global__ void sn_final(const float* __restrict__ ss, const float* __restrict__ Sun,
                         float* __restrict__ scale){
  int tid = threadIdx.x;
  if(tid < 3){
    float inv = 1.f/(sqrtf(ss[tid])+1e-12f);
    float S = Sun[tid]*inv*inv;
    scale[tid] = (sqrtf(S)+1e-12f)/S;
  }
}

// ---------- weight prep: bf16 scaled w1 (K-padded to 32), w2, w3 ----------
__global__ void wprep_kernel(const float* __restrict__ w1, const float* __restrict__ w2,
                             const float* __restrict__ w3, const float* __restrict__ scale,
                             unsigned short* __restrict__ w1p, unsigned short* __restrict__ w2bf,
                             unsigned short* __restrict__ w3bf){
  int idx = blockIdx.x*256 + threadIdx.x;
  float s1 = scale[0], s2 = scale[1], s3 = scale[2];
  if(idx < C1N*32){
    int o = idx >> 5, kk = idx & 31;
    w1p[idx] = (kk < 15) ? f2bf(w1[o*15+kk]*s1) : 0;
  }
  if(idx < C2N*448)   w2bf[idx] = f2bf(w2[idx]*s2);
  if(idx < C3N*1152)  w3bf[idx] = f2bf(w3[idx]*s3);
}

// ---------- fused conv1+conv2 MFMA: ecg -> y1 (LDS only) -> y2bf ----------
__global__ __launch_bounds__(256)
void conv12_mfma(const float* __restrict__ ecg, const unsigned short* __restrict__ w1p,
                 const float* __restrict__ b1, const unsigned short* __restrict__ w2bf,
                 const float* __restrict__ b2, unsigned short* __restrict__ y2bf){
  __shared__ unsigned short ys[C1N*L1O];     // 41216 B — y1 for this batch
  __shared__ unsigned short scratch[10752];  // 21504 B — B1 (phase1) / As+Bs (phase2)
  unsigned short* B1 = scratch;              // 336*32
  unsigned short* As = scratch;              // 128*32
  unsigned short* Bs = scratch + C2N*32;     // 176*32
  int n = blockIdx.x, tid = threadIdx.x;
  int lane = tid & 63, w = tid >> 6;

  // ---- phase 1a: build conv1 im2col B1[t][kk] from global ecg (L1-hot 7.7KB) ----
  const float* eb = ecg + (size_t)n*LIN*NLEADS;
#pragma unroll
  for(int q=0;q<42;q++){
    int e = q*256 + tid;          // t*32+kk, t<336
    int t = e >> 5, kk = e & 31;
    unsigned short v = 0;
    if(kk < 15 && t < L1O){
      int i = kk/5, r = kk - i*5;
      int p = 2*t - 4 + r;
      if((unsigned)p < (unsigned)LIN) v = f2bf(eb[p*NLEADS + i]);
    }
    B1[t*32 + kk] = v;
  }
  __syncthreads();

  // ---- phase 1b: conv1 MFMA — wave w owns m-tile w (o = w*16..w*16+15) ----
  {
    short8 a1 = *(const short8*)(w1p + ((w*16 + (lane&15))<<5) + (lane>>4)*8);
    f32x4 zero = {0.f,0.f,0.f,0.f};
    f32x4 c1[21];
#pragma unroll
    for(int nt=0;nt<21;nt++){
      short8 b = *(const short8*)(B1 + ((nt*16 + (lane&15))<<5) + (lane>>4)*8);
      c1[nt] = __builtin_amdgcn_mfma_f32_16x16x32_bf16(a1, b, zero, 0, 0, 0);
    }
    // epilogue: bias + leaky -> ys (LDS)
#pragma unroll
    for(int reg=0;reg<4;reg++){
      int o = w*16 + (lane>>4)*4 + reg;
      float bias = b1[o];
#pragma unroll
      for(int nt=0;nt<21;nt++){
        int t = nt*16 + (lane&15);
        if(t < L1O){
          float v = c1[nt][reg] + bias;
          v = v>=0.f ? v : 0.2f*v;
          ys[o*L1O + t] = f2bf(v);
        }
      }
    }
  }
  // (first K-loop barrier protects scratch reuse + ys visibility)

  // ---- phase 2: conv2 K-loop (identical to conv2_mfma, ys already resident) ----
  f32x4 zero = {0.f,0.f,0.f,0.f};
  f32x4 acc[2][11];
#pragma unroll
  for(int i=0;i<2;i++)
#pragma unroll
    for(int j=0;j<11;j++) acc[i][j] = zero;

  for(int ck=0; ck<14; ck++){
    int kc = ck*32;
    __syncthreads();
    {
      const char* wb = (const char*)w2bf;
      uint4* dst = (uint4*)As;
#pragma unroll
      for(int q=0;q<2;q++){
        int f = q*256 + tid;
        int row = f >> 2, col = f & 3;
        dst[f] = *(const uint4*)(wb + row*896 + kc*2 + col*16);
      }
    }
#pragma unroll
    for(int q=0;q<22;q++){
      int e = q*256 + tid;
      int t = e >> 5, kk = e & 31;
      int k = kc + kk;
      int i = k / 7;
      int r = k - i*7;
      int p = 2*t - 3 + r;
      unsigned short v = 0;
      if(t < L2O && (unsigned)p < (unsigned)L1O) v = ys[i*L1O + p];
      Bs[t*32 + kk] = v;
    }
    __syncthreads();
    short8 a[2], b[11];
#pragma unroll
    for(int mm=0;mm<2;mm++)
      a[mm] = *(const short8*)(As + ((w*2+mm)*16 + (lane&15))*32 + (lane>>4)*8);
#pragma unroll
    for(int nt=0;nt<11;nt++)
      b[nt] = *(const short8*)(Bs + (nt*16 + (lane&15))*32 + (lane>>4)*8);
#pragma unroll
    for(int mm=0;mm<2;mm++)
#pragma unroll
      for(int nt=0;nt<11;nt++)
        acc[mm][nt] = __builtin_amdgcn_mfma_f32_16x16x32_bf16(a[mm], b[nt], acc[mm][nt], 0, 0, 0);
  }
#pragma unroll
  for(int mm=0;mm<2;mm++){
#pragma unroll
    for(int reg=0;reg<4;reg++){
      int o = (w*2+mm)*16 + (lane>>4)*4 + reg;
      float bias = b2[o];
#pragma unroll
      for(int nt=0;nt<11;nt++){
        int t = nt*16 + (lane&15);
        if(t < L2O){
          float v = acc[mm][nt][reg] + bias;
          v = v>=0.f ? v : 0.2f*v;
          y2bf[(size_t)n*20608 + o*L2O + t] = f2bf(v);
        }
      }
    }
  }
}

// ---------- conv3 MFMA -> flatbf ----------
__global__ __launch_bounds__(256)
void conv3_mfma(const unsigned short* __restrict__ y2bf, const unsigned short* __restrict__ w3bf,
                const float* __restrict__ b3, unsigned short* __restrict__ flatbf){
  __shared__ unsigned short ys[C2N*L2O];
  __shared__ unsigned short As[C3N*32];
  __shared__ unsigned short Bs[80*32];
  int n = blockIdx.x, tid = threadIdx.x;
  int lane = tid & 63, w = tid >> 6;
  {
    const uint4* src = (const uint4*)(y2bf + (size_t)n*20608);
    uint4* dst = (uint4*)ys;
#pragma unroll
    for(int q=0;q<11;q++){
      int f = q*256 + tid;
      if(f < 2576) dst[f] = src[f];
    }
  }
  f32x4 zero = {0.f,0.f,0.f,0.f};
  f32x4 acc[4][5];
#pragma unroll
  for(int i=0;i<4;i++)
#pragma unroll
    for(int j=0;j<5;j++) acc[i][j] = zero;
  __syncthreads();

  for(int ck=0; ck<36; ck++){
    int kc = ck*32;
    __syncthreads();
    {
      const char* wb = (const char*)w3bf;
      uint4* dst = (uint4*)As;
#pragma unroll
      for(int q=0;q<4;q++){
        int f = q*256 + tid;
        int row = f >> 2, col = f & 3;
        dst[f] = *(const uint4*)(wb + row*2304 + kc*2 + col*16);
      }
    }
#pragma unroll
    for(int q=0;q<10;q++){
      int e = q*256 + tid;
      int t = e >> 5, kk = e & 31;
      int k = kc + kk;
      int i = k / 9;
      int r = k - i*9;
      int p = 2*t - 2 + r;
      unsigned short v = 0;
      if(t < L3O && (unsigned)p < (unsigned)L2O) v = ys[i*L2O + p];
      Bs[t*32 + kk] = v;
    }
    __syncthreads();
    short8 a[4], b[5];
#pragma unroll
    for(int mm=0;mm<4;mm++)
      a[mm] = *(const short8*)(As + ((w*4+mm)*16 + (lane&15))*32 + (lane>>4)*8);
#pragma unroll
    for(int nt=0;nt<5;nt++)
      b[nt] = *(const short8*)(Bs + (nt*16 + (lane&15))*32 + (lane>>4)*8);
#pragma unroll
    for(int mm=0;mm<4;mm++)
#pragma unroll
      for(int nt=0;nt<5;nt++)
        acc[mm][nt] = __builtin_amdgcn_mfma_f32_16x16x32_bf16(a[mm], b[nt], acc[mm][nt], 0, 0, 0);
  }
#pragma unroll
  for(int mm=0;mm<4;mm++){
#pragma unroll
    for(int reg=0;reg<4;reg++){
      int o = (w*4+mm)*16 + (lane>>4)*4 + reg;
      float bias = b3[o];
#pragma unroll
      for(int nt=0;nt<5;nt++){
        int t = nt*16 + (lane&15);
        if(t < L3O){
          float v = acc[mm][nt][reg] + bias;
          v = v>=0.f ? v : 0.2f*v;
          flatbf[(size_t)n*FLATSZ + o*L3O + t] = f2bf(v);
        }
      }
    }
  }
}

// ---------- transpose + bf16: mbwT[n][k] ----------
__global__ __launch_bounds__(256)
void mbw_transpose(const float* __restrict__ mbw, unsigned short* __restrict__ mbwT){
  __shared__ unsigned short tile[32][36];
  int k0 = blockIdx.x*32, n0 = blockIdx.y*32, tid = threadIdx.x;
  int r = tid >> 3, c4 = (tid & 7) * 4;
  int nbase = n0 + c4;
  if(nbase + 3 < 500){
    float4 v = *(const float4*)(mbw + (size_t)(k0+r)*500 + nbase);
    tile[r][c4+0] = f2bf(v.x);
    tile[r][c4+1] = f2bf(v.y);
    tile[r][c4+2] = f2bf(v.z);
    tile[r][c4+3] = f2bf(v.w);
  } else {
#pragma unroll
    for(int j=0;j<4;j++){
      int nn = nbase + j;
      float v = (nn < 500) ? mbw[(size_t)(k0+r)*500 + nn] : 0.f;
      tile[r][c4+j] = f2bf(v);
    }
  }
  __syncthreads();
  int nl = tid >> 3, kq = (tid & 7) * 4;
  unsigned short t0 = tile[kq+0][nl], t1 = tile[kq+1][nl];
  unsigned short t2 = tile[kq+2][nl], t3 = tile[kq+3][nl];
  uint2 p;
  p.x = (unsigned)t0 | ((unsigned)t1 << 16);
  p.y = (unsigned)t2 | ((unsigned)t3 << 16);
  *(uint2*)(mbwT + (size_t)(n0+nl)*FLATSZ + k0 + kq) = p;
}

// ---------- split-K MFMA GEMM ----------
__global__ __launch_bounds__(256)
void mb_gemm_mfma(const unsigned short* __restrict__ flatbf, const unsigned short* __restrict__ mbwT,
                  float* __restrict__ part){
  __shared__ unsigned short As[64*32];
  __shared__ unsigned short Bs[64*32];
  int tid = threadIdx.x;
  int lane = tid & 63, w = tid >> 6;
  int m0 = blockIdx.x*64, n0 = blockIdx.y*64, bz = blockIdx.z;
  int t_start = bz*39 + (bz<8 ? bz : 8);
  int t_count = 39 + (bz<8 ? 1 : 0);
  int k0 = t_start*32;
  f32x4 zero = {0.f,0.f,0.f,0.f};
  f32x4 acc[4];
#pragma unroll
  for(int i=0;i<4;i++) acc[i] = zero;
  int arow = tid >> 2, acol = (tid & 3) * 8;
  for(int t=0; t<t_count; t++, k0+=32){
    __syncthreads();
    ((uint4*)As)[tid] = *(const uint4*)(flatbf + (size_t)(m0+arow)*FLATSZ + k0 + acol);
    ((uint4*)Bs)[tid] = *(const uint4*)(mbwT  + (size_t)(n0+arow)*FLATSZ + k0 + acol);
    __syncthreads();
    short8 a = *(const short8*)(As + (w*16 + (lane&15))*32 + (lane>>4)*8);
#pragma unroll
    for(int nt=0;nt<4;nt++){
      short8 b = *(const short8*)(Bs + (nt*16 + (lane&15))*32 + (lane>>4)*8);
      acc[nt] = __builtin_amdgcn_mfma_f32_16x16x32_bf16(a, b, acc[nt], 0, 0, 0);
    }
  }
  float* po = part + (size_t)bz*NB*500;
#pragma unroll
  for(int nt=0;nt<4;nt++){
#pragma unroll
    for(int reg=0;reg<4;reg++){
      int m = m0 + w*16 + (lane>>4)*4 + reg;
      int c = n0 + nt*16 + (lane&15);
      if(c < 500) po[(size_t)m*500 + c] = acc[nt][reg];
    }
  }
}

// ---------- reduce partials -> actT[c][n] ----------
__global__ void mb_reduce_kernel(const float* __restrict__ part, float* __restrict__ actT){
  int idx = blockIdx.x*256 + threadIdx.x;   // n*500+c
  float s = 0.f;
#pragma unroll
  for(int z=0;z<SPLITK;z++) s += part[(size_t)z*NB*500 + idx];
  int n = idx/500, c = idx - n*500;
  actT[(size_t)c*NB + n] = s;
}

// ---------- minibatch features ----------
__global__ __launch_bounds__(256)
void feats_kernel(const float* __restrict__ actT, float* __restrict__ feats){
  __shared__ float ash[4][50];
  __shared__ float pred[4][4];
  int i0 = blockIdx.x*4, k0 = blockIdx.y*10;
  int tid = threadIdx.x, lane = tid & 63, wv = tid >> 6;
  if(tid < 200){
    int ii = tid/50, c = tid - ii*50;
    ash[ii][c] = actT[(size_t)(k0*5+c)*NB + i0 + ii];
  }
  __syncthreads();
  const float LOG2E = 1.4426950408889634f;
  int j1 = tid, j2 = tid + 256;
  for(int kk=0; kk<10; kk++){
    const float* r0 = actT + (size_t)(k0+kk)*5*NB;
    float xa0=r0[j1], xa1=r0[NB+j1], xa2=r0[2*NB+j1], xa3=r0[3*NB+j1], xa4=r0[4*NB+j1];
    float xb0=r0[j2], xb1=r0[NB+j2], xb2=r0[2*NB+j2], xb3=r0[3*NB+j2], xb4=r0[4*NB+j2];
    float f[4];
#pragma unroll
    for(int ii=0; ii<4; ii++){
      float a0=ash[ii][kk*5+0], a1=ash[ii][kk*5+1], a2=ash[ii][kk*5+2],
            a3=ash[ii][kk*5+3], a4=ash[ii][kk*5+4];
      float la = fabsf(xa0-a0)+fabsf(xa1-a1)+fabsf(xa2-a2)+fabsf(xa3-a3)+fabsf(xa4-a4);
      float lb = fabsf(xb0-a0)+fabsf(xb1-a1)+fabsf(xb2-a2)+fabsf(xb3-a3)+fabsf(xb4-a4);
      f[ii] = exp2f(-LOG2E*la) + exp2f(-LOG2E*lb);
    }
#pragma unroll
    for(int ii=0; ii<4; ii++){
      float v = f[ii];
#pragma unroll
      for(int s=32; s>0; s>>=1) v += __shfl_down(v, s, 64);
      if(lane==0) pred[wv][ii] = v;
    }
    __syncthreads();
    if(tid < 4){
      float v = pred[0][tid] + pred[1][tid] + pred[2][tid] + pred[3][tid];
      feats[(size_t)(i0+tid)*NUMK + k0 + kk] = v;
    }
    __syncthreads();
  }
}

// ---------- final ----------
__global__ void final_kernel(const unsigned short* __restrict__ flatbf, const float* __restrict__ feats,
                             const int* __restrict__ condition, const float* __restrict__ emb,
                             const float* __restrict__ cond_w, const float* __restrict__ cond_b,
                             const float* __restrict__ fc_w, const float* __restrict__ fc_b,
                             float* __restrict__ out){
  __shared__ float red[4];
  int n = blockIdx.x, tid = threadIdx.x;
  float s = 0.f;
  const unsigned short* fr = flatbf + (size_t)n*FLATSZ;
  for(int q=tid; q<FLATSZ/8; q+=256){
    uint4 u = *(const uint4*)(fr + q*8);
    float4 wa = *(const float4*)(fc_w + q*8);
    float4 wb = *(const float4*)(fc_w + q*8 + 4);
    s += bf2f((unsigned short)(u.x & 0xffff))*wa.x + bf2f((unsigned short)(u.x >> 16))*wa.y
       + bf2f((unsigned short)(u.y & 0xffff))*wa.z + bf2f((unsigned short)(u.y >> 16))*wa.w
       + bf2f((unsigned short)(u.z & 0xffff))*wb.x + bf2f((unsigned short)(u.z >> 16))*wb.y
       + bf2f((unsigned short)(u.w & 0xffff))*wb.z + bf2f((unsigned short)(u.w >> 16))*wb.w;
  }
  for(int k=tid;k<NUMK;k+=256) s += feats[n*NUMK+k]*fc_w[FLATSZ+k];
  float ce = emb[condition[n]];
  for(int j=tid;j<50;j+=256) s += (ce*cond_w[j]+cond_b[j])*fc_w[FLATSZ+NUMK+j];
  s = block_reduce_sum(s, red);
  if(tid==0) out[n] = s + fc_b[0];
}

extern "C" void kernel_launch(void* const* d_in, const int* in_sizes, int n_in,
                              void* d_out, int out_size, void* d_ws, size_t ws_size,
                              hipStream_t stream) {
  const float* ecg   = (const float*)d_in[0];
  const int*   cond  = (const int*)  d_in[1];
  const float* w1    = (const float*)d_in[2];
  const float* b1    = (const float*)d_in[3];
  const float* u1    = (const float*)d_in[4];
  const float* w2    = (const float*)d_in[5];
  const float* b2    = (const float*)d_in[6];
  const float* u2    = (const float*)d_in[7];
  const float* w3    = (const float*)d_in[8];
  const float* b3    = (const float*)d_in[9];
  const float* u3    = (const float*)d_in[10];
  const float* emb   = (const float*)d_in[11];
  const float* condw = (const float*)d_in[12];
  const float* condb = (const float*)d_in[13];
  const float* mbw   = (const float*)d_in[14];
  const float* fcw   = (const float*)d_in[15];
  const float* fcb   = (const float*)d_in[16];

  float* ws = (float*)d_ws;
  float* scale = ws;                                      // 0..16
  float* ssbuf = ws + 16;
  float* Sunbuf= ws + 24;
  float* v_all = ws + 32;                                 // ends 1648
  unsigned short* w1p  = (unsigned short*)(ws + 1648);    // 2048 sh = 1024 f -> 2672
  unsigned short* w2bf = (unsigned short*)(ws + 2672);    // 57344 sh -> 31344
  unsigned short* w3bf = (unsigned short*)(ws + 31344);   // 294912 sh -> 178800
  float* part  = ws + 178800;                             // 4,096,000 f -> 4,274,800
  float* actT  = ws + 4274800;                            // 256,000 -> 4,530,800
  float* feats = ws + 4530800;                            // 51,200 -> 4,582,000
  unsigned short* y2bf = (unsigned short*)(ws + 4582000); // 10,551,296 sh -> 9,857,648
  unsigned short* mbwT = (unsigned short*)(ws + 4582000); // overlays y2bf (dead after conv3)
  unsigned short* flatbf = (unsigned short*)(ws + 9857648); // 10,354,688 sh -> 15,034,992 f

  hipMemsetAsync((char*)d_ws + 64, 0, 64, stream);   // zero ssbuf/Sunbuf
  sn_pass1<<<8, 256, 0, stream>>>(w1,u1,w2,u2,w3,u3, v_all, ssbuf);
  sn_pass2<<<112, 256, 0, stream>>>(w1,w2,w3, v_all, Sunbuf);
  sn_final<<<1, 64, 0, stream>>>(ssbuf, Sunbuf, scale);
  wprep_kernel<<<1152, 256, 0, stream>>>(w1, w2, w3, scale, w1p, w2bf, w3bf);
  conv12_mfma<<<NB, 256, 0, stream>>>(ecg, w1p, b1, w2bf, b2, y2bf);
  conv3_mfma<<<NB, 256, 0, stream>>>(y2bf, w3bf, b3, flatbf);
  mbw_transpose<<<dim3(632,16), 256, 0, stream>>>(mbw, mbwT);
  mb_gemm_mfma<<<dim3(8,8,SPLITK), 256, 0, stream>>>(flatbf, mbwT, part);
  mb_reduce_kernel<<<1000, 256, 0, stream>>>(part, actT);
  feats_kernel<<<dim3(128,10), 256, 0, stream>>>(actT, feats);
  final_kernel<<<NB, 256, 0, stream>>>(flatbf, feats, cond, emb, condw, condb, fcw, fcb, (float*)d_out);
}

// Round 7
// 371.140 us; speedup vs baseline: 10.1365x; 1.0058x over previous
//
#include <hip/hip_runtime.h>
#include <math.h>

#define NB 512
#define LIN 640
#define NLEADS 3
#define L1O 322
#define L2O 161
#define L2P 208    // padded row stride for y2bf
#define L3O 79
#define C1N 64
#define C2N 128
#define C3N 256
#define FLATSZ 20224   // 256*79
#define NUMK 100
#define DIMK 5
#define SPLITK 16

typedef __attribute__((ext_vector_type(8))) short short8;
typedef __attribute__((ext_vector_type(4))) float f32x4;

__device__ __forceinline__ unsigned short f2bf(float x){
  unsigned u = __builtin_bit_cast(unsigned, x);
  unsigned r = u + 0x7FFFu + ((u >> 16) & 1u);
  return (unsigned short)(r >> 16);
}
__device__ __forceinline__ float bf2f(unsigned short x){
  unsigned u = ((unsigned)x) << 16;
  return __builtin_bit_cast(float, u);
}

__device__ __forceinline__ float block_reduce_sum(float val, float* red){
#pragma unroll
  for(int off=32; off>0; off>>=1) val += __shfl_down(val, off, 64);
  int lane = threadIdx.x & 63;
  int wv = threadIdx.x >> 6;
  if(lane==0) red[wv] = val;
  __syncthreads();
  int nw = blockDim.x >> 6;
  float r = red[0];
  for(int i=1;i<nw;i++) r += red[i];
  __syncthreads();
  return r;
}

// ---------- SN pass 1 ----------
__global__ __launch_bounds__(256)
void sn_pass1(const float* __restrict__ w1, const float* __restrict__ u1,
              const float* __restrict__ w2, const float* __restrict__ u2,
              const float* __restrict__ w3, const float* __restrict__ u3,
              float* __restrict__ v_all, float* __restrict__ ss){
  __shared__ float red[4];
  int b = blockIdx.x, tid = threadIdx.x;
  const float* w; const float* u; int O, C, off, c, widx;
  if(b==0){ w=w1; u=u1; O=64;  C=15;   off=0;   c=tid;            widx=0; }
  else if(b<3){ w=w2; u=u2; O=128; C=448; off=16;  c=(b-1)*256+tid; widx=1; }
  else { w=w3; u=u3; O=256; C=1152; off=464; c=(b-3)*256+tid;      widx=2; }
  float vv = 0.f;
  if(c < C){
    for(int o=0;o<O;o+=4){
      vv += w[(o+0)*C+c]*u[o+0] + w[(o+1)*C+c]*u[o+1]
          + w[(o+2)*C+c]*u[o+2] + w[(o+3)*C+c]*u[o+3];
    }
    v_all[off + c] = vv;
  }
  float ps = (c < C) ? vv*vv : 0.f;
  float tot = block_reduce_sum(ps, red);
  if(tid==0) atomicAdd(&ss[widx], tot);
}

// ---------- SN pass 2 ----------
__global__ __launch_bounds__(256)
void sn_pass2(const float* __restrict__ w1, const float* __restrict__ w2,
              const float* __restrict__ w3, const float* __restrict__ v_all,
              float* __restrict__ Sun){
  int b = blockIdx.x, tid = threadIdx.x;
  int lane = tid & 63, wv = tid >> 6;
  const float* w; int C, off, o, widx;
  if(b < 16){ w=w1; C=15;   off=0;   o=b*4+wv;      widx=0; }
  else if(b < 48){ w=w2; C=448; off=16;  o=(b-16)*4+wv; widx=1; }
  else { w=w3; C=1152; off=464; o=(b-48)*4+wv;          widx=2; }
  float t = 0.f;
  for(int c=lane; c<C; c+=64) t += w[o*C+c]*v_all[off+c];
#pragma unroll
  for(int s=32; s>0; s>>=1) t += __shfl_down(t, s, 64);
  if(lane==0) atomicAdd(&Sun[widx], t*t);
}

__global__ void sn_final(const float* __restrict__ ss, const float* __restrict__ Sun,
                         float* __restrict__ scale){
  int tid = threadIdx.x;
  if(tid < 3){
    float inv = 1.f/(sqrtf(ss[tid])+1e-12f);
    float S = Sun[tid]*inv*inv;
    scale[tid] = (sqrtf(S)+1e-12f)/S;
  }
}

// ---------- weight prep: bf16 scaled w1 (K-padded to 32), w2, w3 ----------
__global__ void wprep_kernel(const float* __restrict__ w1, const float* __restrict__ w2,
                             const float* __restrict__ w3, const float* __restrict__ scale,
                             unsigned short* __restrict__ w1p, unsigned short* __restrict__ w2bf,
                             unsigned short* __restrict__ w3bf){
  int idx = blockIdx.x*256 + threadIdx.x;
  float s1 = scale[0], s2 = scale[1], s3 = scale[2];
  if(idx < C1N*32){
    int o = idx >> 5, kk = idx & 31;
    w1p[idx] = (kk < 15) ? f2bf(w1[o*15+kk]*s1) : 0;
  }
  if(idx < C2N*448)   w2bf[idx] = f2bf(w2[idx]*s2);
  if(idx < C3N*1152)  w3bf[idx] = f2bf(w3[idx]*s3);
}

// ---------- fused conv1+conv2 MFMA, t-split 2 ways ----------
// grid (NB, 2): tile0 -> t 0..95, tile1 -> t 96..160
// y1 window: 208 cols starting at c0 (0 / 189); cols with tc>=322 written as 0
__global__ __launch_bounds__(256, 4)
void conv12_mfma(const float* __restrict__ ecg, const unsigned short* __restrict__ w1p,
                 const float* __restrict__ b1, const unsigned short* __restrict__ w2bf,
                 const float* __restrict__ b2, unsigned short* __restrict__ y2bf){
  __shared__ unsigned short ysw[C1N*208];    // 26624 B — y1 window
  __shared__ unsigned short scratch[7168];   // 14336 B — B1 (phase1) / As+Bs (phase2)
  unsigned short* B1 = scratch;              // 208*32
  unsigned short* As = scratch;              // 128*32
  unsigned short* Bs = scratch + C2N*32;     // 96*32
  int n = blockIdx.x, tile = blockIdx.y, tid = threadIdx.x;
  int lane = tid & 63, w = tid >> 6;
  int c0    = tile ? 189 : 0;
  int tbase = tile ? 96  : 0;
  int D     = tile ? 0   : -3;    // = 2*tbase - 3 - c0

  // ---- phase 1a: build conv1 im2col B1[t'][kk] from global ecg ----
  const float* eb = ecg + (size_t)n*LIN*NLEADS;
#pragma unroll
  for(int q=0;q<26;q++){
    int e = q*256 + tid;          // t'*32+kk, t'<208
    int tp = e >> 5, kk = e & 31;
    unsigned short v = 0;
    if(kk < 15){
      int i = kk/5, r = kk - i*5;
      int p = 2*(c0 + tp) - 4 + r;
      if((unsigned)p < (unsigned)LIN) v = f2bf(eb[p*NLEADS + i]);
    }
    B1[tp*32 + kk] = v;
  }
  __syncthreads();

  // ---- phase 1b: conv1 MFMA in two halves (caps register pressure) ----
  {
    short8 a1 = *(const short8*)(w1p + ((w*16 + (lane&15))<<5) + (lane>>4)*8);
    f32x4 zero = {0.f,0.f,0.f,0.f};
#pragma unroll
    for(int half=0; half<2; half++){
      int nt0 = half*7, ntc = half ? 6 : 7;
      f32x4 c1[7];
      for(int j=0;j<ntc;j++){
        short8 b = *(const short8*)(B1 + (((nt0+j)*16 + (lane&15))<<5) + (lane>>4)*8);
        c1[j] = __builtin_amdgcn_mfma_f32_16x16x32_bf16(a1, b, zero, 0, 0, 0);
      }
#pragma unroll
      for(int reg=0;reg<4;reg++){
        int o = w*16 + (lane>>4)*4 + reg;
        float bias = b1[o];
        for(int j=0;j<ntc;j++){
          int tp = (nt0+j)*16 + (lane&15);
          int tc = c0 + tp;
          float v = 0.f;
          if(tc < L1O){
            v = c1[j][reg] + bias;
            v = v>=0.f ? v : 0.2f*v;
          }
          ysw[o*208 + tp] = (tc < L1O) ? f2bf(v) : (unsigned short)0;
        }
      }
    }
  }

  // ---- phase 2: conv2 K-loop over window ----
  f32x4 zero = {0.f,0.f,0.f,0.f};
  f32x4 acc[2][6];
#pragma unroll
  for(int i=0;i<2;i++)
#pragma unroll
    for(int j=0;j<6;j++) acc[i][j] = zero;

  for(int ck=0; ck<14; ck++){
    int kc = ck*32;
    __syncthreads();
    {
      const char* wb = (const char*)w2bf;
      uint4* dst = (uint4*)As;
#pragma unroll
      for(int q=0;q<2;q++){
        int f = q*256 + tid;
        int row = f >> 2, col = f & 3;
        dst[f] = *(const uint4*)(wb + row*896 + kc*2 + col*16);
      }
    }
    // Bs[tt][kk]: col = 2*tt + r + D in window
#pragma unroll
    for(int q=0;q<12;q++){
      int e = q*256 + tid;            // 96*32 = 3072
      int tt = e >> 5, kk = e & 31;
      int k = kc + kk;
      int i = k / 7;
      int r = k - i*7;
      int col = 2*tt + r + D;
      unsigned short v = 0;
      if((unsigned)col < 208u) v = ysw[i*208 + col];
      Bs[tt*32 + kk] = v;
    }
    __syncthreads();
    short8 a[2], b[6];
#pragma unroll
    for(int mm=0;mm<2;mm++)
      a[mm] = *(const short8*)(As + ((w*2+mm)*16 + (lane&15))*32 + (lane>>4)*8);
#pragma unroll
    for(int nt=0;nt<6;nt++)
      b[nt] = *(const short8*)(Bs + (nt*16 + (lane&15))*32 + (lane>>4)*8);
#pragma unroll
    for(int mm=0;mm<2;mm++)
#pragma unroll
      for(int nt=0;nt<6;nt++)
        acc[mm][nt] = __builtin_amdgcn_mfma_f32_16x16x32_bf16(a[mm], b[nt], acc[mm][nt], 0, 0, 0);
  }
  // epilogue: y2bf row stride L2P=208 (pad cols stay zero from memset)
#pragma unroll
  for(int mm=0;mm<2;mm++){
#pragma unroll
    for(int reg=0;reg<4;reg++){
      int o = (w*2+mm)*16 + (lane>>4)*4 + reg;
      float bias = b2[o];
#pragma unroll
      for(int nt=0;nt<6;nt++){
        int t = tbase + nt*16 + (lane&15);
        if(t < L2O){
          float v = acc[mm][nt][reg] + bias;
          v = v>=0.f ? v : 0.2f*v;
          y2bf[(size_t)n*(C2N*L2P) + o*L2P + t] = f2bf(v);
        }
      }
    }
  }
}

// ---------- conv3 MFMA, t-split 2 ways -> flatbf ----------
// grid (NB, 2): tile0 -> t 0..47, tile1 -> t 48..78
// y2 window: 112 cols starting at c0 (0 / 88); pad cols are zeros (memset)
__global__ __launch_bounds__(256, 3)
void conv3_mfma(const unsigned short* __restrict__ y2bf, const unsigned short* __restrict__ w3bf,
                const float* __restrict__ b3, unsigned short* __restrict__ flatbf){
  __shared__ unsigned short ysw[C2N*112];   // 28672 B
  __shared__ unsigned short As[C3N*32];     // 16384 B
  __shared__ unsigned short Bs[48*32];      // 3072 B
  int n = blockIdx.x, tile = blockIdx.y, tid = threadIdx.x;
  int lane = tid & 63, w = tid >> 6;
  int c0    = tile ? 88 : 0;
  int tbase = tile ? 48 : 0;
  int D3    = tile ? 6  : -2;   // = 2*tbase - 2 - c0

  // stage window: 128 rows x 112 u16 = 1792 uint4 (aligned: 208*2 and 88*2 are 16B multiples)
  {
    const unsigned short* src = y2bf + (size_t)n*(C2N*L2P) + c0;
#pragma unroll
    for(int q=0;q<8;q++){
      int idx = q*256 + tid;
      int row = idx >> 4, c8 = idx & 15;
      if(c8 < 14)
        *(uint4*)(ysw + row*112 + c8*8) = *(const uint4*)(src + row*L2P + c8*8);
    }
  }
  f32x4 zero = {0.f,0.f,0.f,0.f};
  f32x4 acc[4][3];
#pragma unroll
  for(int i=0;i<4;i++)
#pragma unroll
    for(int j=0;j<3;j++) acc[i][j] = zero;
  __syncthreads();

  for(int ck=0; ck<36; ck++){
    int kc = ck*32;
    __syncthreads();
    {
      const char* wb = (const char*)w3bf;
      uint4* dst = (uint4*)As;
#pragma unroll
      for(int q=0;q<4;q++){
        int f = q*256 + tid;
        int row = f >> 2, col = f & 3;
        dst[f] = *(const uint4*)(wb + row*2304 + kc*2 + col*16);
      }
    }
    // Bs[tt][kk]: col = 2*tt + r + D3 in window
#pragma unroll
    for(int q=0;q<6;q++){
      int e = q*256 + tid;            // 48*32 = 1536
      int tt = e >> 5, kk = e & 31;
      int k = kc + kk;
      int i = k / 9;
      int r = k - i*9;
      int col = 2*tt + r + D3;
      unsigned short v = 0;
      if((unsigned)col < 112u) v = ysw[i*112 + col];
      Bs[tt*32 + kk] = v;
    }
    __syncthreads();
    short8 a[4], b[3];
#pragma unroll
    for(int mm=0;mm<4;mm++)
      a[mm] = *(const short8*)(As + ((w*4+mm)*16 + (lane&15))*32 + (lane>>4)*8);
#pragma unroll
    for(int nt=0;nt<3;nt++)
      b[nt] = *(const short8*)(Bs + (nt*16 + (lane&15))*32 + (lane>>4)*8);
#pragma unroll
    for(int mm=0;mm<4;mm++)
#pragma unroll
      for(int nt=0;nt<3;nt++)
        acc[mm][nt] = __builtin_amdgcn_mfma_f32_16x16x32_bf16(a[mm], b[nt], acc[mm][nt], 0, 0, 0);
  }
#pragma unroll
  for(int mm=0;mm<4;mm++){
#pragma unroll
    for(int reg=0;reg<4;reg++){
      int o = (w*4+mm)*16 + (lane>>4)*4 + reg;
      float bias = b3[o];
#pragma unroll
      for(int nt=0;nt<3;nt++){
        int t = tbase + nt*16 + (lane&15);
        if(t < L3O){
          float v = acc[mm][nt][reg] + bias;
          v = v>=0.f ? v : 0.2f*v;
          flatbf[(size_t)n*FLATSZ + o*L3O + t] = f2bf(v);
        }
      }
    }
  }
}

// ---------- transpose + bf16: mbwT[n][k] ----------
__global__ __launch_bounds__(256)
void mbw_transpose(const float* __restrict__ mbw, unsigned short* __restrict__ mbwT){
  __shared__ unsigned short tile[32][36];
  int k0 = blockIdx.x*32, n0 = blockIdx.y*32, tid = threadIdx.x;
  int r = tid >> 3, c4 = (tid & 7) * 4;
  int nbase = n0 + c4;
  if(nbase + 3 < 500){
    float4 v = *(const float4*)(mbw + (size_t)(k0+r)*500 + nbase);
    tile[r][c4+0] = f2bf(v.x);
    tile[r][c4+1] = f2bf(v.y);
    tile[r][c4+2] = f2bf(v.z);
    tile[r][c4+3] = f2bf(v.w);
  } else {
#pragma unroll
    for(int j=0;j<4;j++){
      int nn = nbase + j;
      float v = (nn < 500) ? mbw[(size_t)(k0+r)*500 + nn] : 0.f;
      tile[r][c4+j] = f2bf(v);
    }
  }
  __syncthreads();
  int nl = tid >> 3, kq = (tid & 7) * 4;
  unsigned short t0 = tile[kq+0][nl], t1 = tile[kq+1][nl];
  unsigned short t2 = tile[kq+2][nl], t3 = tile[kq+3][nl];
  uint2 p;
  p.x = (unsigned)t0 | ((unsigned)t1 << 16);
  p.y = (unsigned)t2 | ((unsigned)t3 << 16);
  *(uint2*)(mbwT + (size_t)(n0+nl)*FLATSZ + k0 + kq) = p;
}

// ---------- split-K MFMA GEMM ----------
__global__ __launch_bounds__(256)
void mb_gemm_mfma(const unsigned short* __restrict__ flatbf, const unsigned short* __restrict__ mbwT,
                  float* __restrict__ part){
  __shared__ unsigned short As[64*32];
  __shared__ unsigned short Bs[64*32];
  int tid = threadIdx.x;
  int lane = tid & 63, w = tid >> 6;
  int m0 = blockIdx.x*64, n0 = blockIdx.y*64, bz = blockIdx.z;
  int t_start = bz*39 + (bz<8 ? bz : 8);
  int t_count = 39 + (bz<8 ? 1 : 0);
  int k0 = t_start*32;
  f32x4 zero = {0.f,0.f,0.f,0.f};
  f32x4 acc[4];
#pragma unroll
  for(int i=0;i<4;i++) acc[i] = zero;
  int arow = tid >> 2, acol = (tid & 3) * 8;
  for(int t=0; t<t_count; t++, k0+=32){
    __syncthreads();
    ((uint4*)As)[tid] = *(const uint4*)(flatbf + (size_t)(m0+arow)*FLATSZ + k0 + acol);
    ((uint4*)Bs)[tid] = *(const uint4*)(mbwT  + (size_t)(n0+arow)*FLATSZ + k0 + acol);
    __syncthreads();
    short8 a = *(const short8*)(As + (w*16 + (lane&15))*32 + (lane>>4)*8);
#pragma unroll
    for(int nt=0;nt<4;nt++){
      short8 b = *(const short8*)(Bs + (nt*16 + (lane&15))*32 + (lane>>4)*8);
      acc[nt] = __builtin_amdgcn_mfma_f32_16x16x32_bf16(a, b, acc[nt], 0, 0, 0);
    }
  }
  float* po = part + (size_t)bz*NB*500;
#pragma unroll
  for(int nt=0;nt<4;nt++){
#pragma unroll
    for(int reg=0;reg<4;reg++){
      int m = m0 + w*16 + (lane>>4)*4 + reg;
      int c = n0 + nt*16 + (lane&15);
      if(c < 500) po[(size_t)m*500 + c] = acc[nt][reg];
    }
  }
}

// ---------- reduce partials -> actT[c][n] ----------
__global__ void mb_reduce_kernel(const float* __restrict__ part, float* __restrict__ actT){
  int idx = blockIdx.x*256 + threadIdx.x;   // n*500+c
  float s = 0.f;
#pragma unroll
  for(int z=0;z<SPLITK;z++) s += part[(size_t)z*NB*500 + idx];
  int n = idx/500, c = idx - n*500;
  actT[(size_t)c*NB + n] = s;
}

// ---------- minibatch features ----------
__global__ __launch_bounds__(256)
void feats_kernel(const float* __restrict__ actT, float* __restrict__ feats){
  __shared__ float ash[4][50];
  __shared__ float pred[4][4];
  int i0 = blockIdx.x*4, k0 = blockIdx.y*10;
  int tid = threadIdx.x, lane = tid & 63, wv = tid >> 6;
  if(tid < 200){
    int ii = tid/50, c = tid - ii*50;
    ash[ii][c] = actT[(size_t)(k0*5+c)*NB + i0 + ii];
  }
  __syncthreads();
  const float LOG2E = 1.4426950408889634f;
  int j1 = tid, j2 = tid + 256;
  for(int kk=0; kk<10; kk++){
    const float* r0 = actT + (size_t)(k0+kk)*5*NB;
    float xa0=r0[j1], xa1=r0[NB+j1], xa2=r0[2*NB+j1], xa3=r0[3*NB+j1], xa4=r0[4*NB+j1];
    float xb0=r0[j2], xb1=r0[NB+j2], xb2=r0[2*NB+j2], xb3=r0[3*NB+j2], xb4=r0[4*NB+j2];
    float f[4];
#pragma unroll
    for(int ii=0; ii<4; ii++){
      float a0=ash[ii][kk*5+0], a1=ash[ii][kk*5+1], a2=ash[ii][kk*5+2],
            a3=ash[ii][kk*5+3], a4=ash[ii][kk*5+4];
      float la = fabsf(xa0-a0)+fabsf(xa1-a1)+fabsf(xa2-a2)+fabsf(xa3-a3)+fabsf(xa4-a4);
      float lb = fabsf(xb0-a0)+fabsf(xb1-a1)+fabsf(xb2-a2)+fabsf(xb3-a3)+fabsf(xb4-a4);
      f[ii] = exp2f(-LOG2E*la) + exp2f(-LOG2E*lb);
    }
#pragma unroll
    for(int ii=0; ii<4; ii++){
      float v = f[ii];
#pragma unroll
      for(int s=32; s>0; s>>=1) v += __shfl_down(v, s, 64);
      if(lane==0) pred[wv][ii] = v;
    }
    __syncthreads();
    if(tid < 4){
      float v = pred[0][tid] + pred[1][tid] + pred[2][tid] + pred[3][tid];
      feats[(size_t)(i0+tid)*NUMK + k0 + kk] = v;
    }
    __syncthreads();
  }
}

// ---------- final ----------
__global__ void final_kernel(const unsigned short* __restrict__ flatbf, const float* __restrict__ feats,
                             const int* __restrict__ condition, const float* __restrict__ emb,
                             const float* __restrict__ cond_w, const float* __restrict__ cond_b,
                             const float* __restrict__ fc_w, const float* __restrict__ fc_b,
                             float* __restrict__ out){
  __shared__ float red[4];
  int n = blockIdx.x, tid = threadIdx.x;
  float s = 0.f;
  const unsigned short* fr = flatbf + (size_t)n*FLATSZ;
  for(int q=tid; q<FLATSZ/8; q+=256){
    uint4 u = *(const uint4*)(fr + q*8);
    float4 wa = *(const float4*)(fc_w + q*8);
    float4 wb = *(const float4*)(fc_w + q*8 + 4);
    s += bf2f((unsigned short)(u.x & 0xffff))*wa.x + bf2f((unsigned short)(u.x >> 16))*wa.y
       + bf2f((unsigned short)(u.y & 0xffff))*wa.z + bf2f((unsigned short)(u.y >> 16))*wa.w
       + bf2f((unsigned short)(u.z & 0xffff))*wb.x + bf2f((unsigned short)(u.z >> 16))*wb.y
       + bf2f((unsigned short)(u.w & 0xffff))*wb.z + bf2f((unsigned short)(u.w >> 16))*wb.w;
  }
  for(int k=tid;k<NUMK;k+=256) s += feats[n*NUMK+k]*fc_w[FLATSZ+k];
  float ce = emb[condition[n]];
  for(int j=tid;j<50;j+=256) s += (ce*cond_w[j]+cond_b[j])*fc_w[FLATSZ+NUMK+j];
  s = block_reduce_sum(s, red);
  if(tid==0) out[n] = s + fc_b[0];
}

extern "C" void kernel_launch(void* const* d_in, const int* in_sizes, int n_in,
                              void* d_out, int out_size, void* d_ws, size_t ws_size,
                              hipStream_t stream) {
  const float* ecg   = (const float*)d_in[0];
  const int*   cond  = (const int*)  d_in[1];
  const float* w1    = (const float*)d_in[2];
  const float* b1    = (const float*)d_in[3];
  const float* u1    = (const float*)d_in[4];
  const float* w2    = (const float*)d_in[5];
  const float* b2    = (const float*)d_in[6];
  const float* u2    = (const float*)d_in[7];
  const float* w3    = (const float*)d_in[8];
  const float* b3    = (const float*)d_in[9];
  const float* u3    = (const float*)d_in[10];
  const float* emb   = (const float*)d_in[11];
  const float* condw = (const float*)d_in[12];
  const float* condb = (const float*)d_in[13];
  const float* mbw   = (const float*)d_in[14];
  const float* fcw   = (const float*)d_in[15];
  const float* fcb   = (const float*)d_in[16];

  float* ws = (float*)d_ws;
  float* scale = ws;                                      // 0..16
  float* ssbuf = ws + 16;
  float* Sunbuf= ws + 24;
  float* v_all = ws + 32;                                 // ends 1648
  unsigned short* w1p  = (unsigned short*)(ws + 1648);    // -> 2672
  unsigned short* w2bf = (unsigned short*)(ws + 2672);    // -> 31344
  unsigned short* w3bf = (unsigned short*)(ws + 31344);   // -> 178800
  // region A (13,631,488 f): y2bf during convs; {mbwT, part} after conv3
  unsigned short* y2bf = (unsigned short*)(ws + 178800);  // 512*128*208 sh = 27,262,976 B
  unsigned short* mbwT = (unsigned short*)(ws + 178800);  // overlays y2bf
  float* part  = ws + 5356144;                            // overlays y2bf tail: 4,096,000 f
  float* actT  = ws + 13810288;                           // 256,000 f
  float* feats = ws + 14066288;                           // 51,200 f
  unsigned short* flatbf = (unsigned short*)(ws + 14117488); // 10,354,688 sh -> ends 19,294,832 f

  hipMemsetAsync((char*)d_ws + 64, 0, 64, stream);                 // zero ssbuf/Sunbuf
  hipMemsetAsync((char*)d_ws + 178800*4, 0, 27262976, stream);     // zero y2bf (padded rows)
  sn_pass1<<<8, 256, 0, stream>>>(w1,u1,w2,u2,w3,u3, v_all, ssbuf);
  sn_pass2<<<112, 256, 0, stream>>>(w1,w2,w3, v_all, Sunbuf);
  sn_final<<<1, 64, 0, stream>>>(ssbuf, Sunbuf, scale);
  wprep_kernel<<<1152, 256, 0, stream>>>(w1, w2, w3, scale, w1p, w2bf, w3bf);
  conv12_mfma<<<dim3(NB,2), 256, 0, stream>>>(ecg, w1p, b1, w2bf, b2, y2bf);
  conv3_mfma<<<dim3(NB,2), 256, 0, stream>>>(y2bf, w3bf, b3, flatbf);
  mbw_transpose<<<dim3(632,16), 256, 0, stream>>>(mbw, mbwT);
  mb_gemm_mfma<<<dim3(8,8,SPLITK), 256, 0, stream>>>(flatbf, mbwT, part);
  mb_reduce_kernel<<<1000, 256, 0, stream>>>(part, actT);
  feats_kernel<<<dim3(128,10), 256, 0, stream>>>(actT, feats);
  final_kernel<<<NB, 256, 0, stream>>>(flatbf, feats, cond, emb, condw, condb, fcw, fcb, (float*)d_out);
}

// Round 8
// 326.729 us; speedup vs baseline: 11.5143x; 1.1359x over previous
//
#include <hip/hip_runtime.h>
#include <math.h>

#define NB 512
#define LIN 640
#define NLEADS 3
#define L1O 322
#define L2O 161
#define L3O 79
#define C1N 64
#define C2N 128
#define C3N 256
#define FLATSZ 20224   // 256*79
#define NUMK 100
#define DIMK 5
#define SPLITK 16

typedef __attribute__((ext_vector_type(8))) short short8;
typedef __attribute__((ext_vector_type(4))) float f32x4;

__device__ __forceinline__ unsigned short f2bf(float x){
  unsigned u = __builtin_bit_cast(unsigned, x);
  unsigned r = u + 0x7FFFu + ((u >> 16) & 1u);
  return (unsigned short)(r >> 16);
}
__device__ __forceinline__ float bf2f(unsigned short x){
  unsigned u = ((unsigned)x) << 16;
  return __builtin_bit_cast(float, u);
}

__device__ __forceinline__ float block_reduce_sum(float val, float* red){
#pragma unroll
  for(int off=32; off>0; off>>=1) val += __shfl_down(val, off, 64);
  int lane = threadIdx.x & 63;
  int wv = threadIdx.x >> 6;
  if(lane==0) red[wv] = val;
  __syncthreads();
  int nw = blockDim.x >> 6;
  float r = red[0];
  for(int i=1;i<nw;i++) r += red[i];
  __syncthreads();
  return r;
}

// ---------- SN pass 1 ----------
__global__ __launch_bounds__(256)
void sn_pass1(const float* __restrict__ w1, const float* __restrict__ u1,
              const float* __restrict__ w2, const float* __restrict__ u2,
              const float* __restrict__ w3, const float* __restrict__ u3,
              float* __restrict__ v_all, float* __restrict__ ss){
  __shared__ float red[4];
  int b = blockIdx.x, tid = threadIdx.x;
  const float* w; const float* u; int O, C, off, c, widx;
  if(b==0){ w=w1; u=u1; O=64;  C=15;   off=0;   c=tid;            widx=0; }
  else if(b<3){ w=w2; u=u2; O=128; C=448; off=16;  c=(b-1)*256+tid; widx=1; }
  else { w=w3; u=u3; O=256; C=1152; off=464; c=(b-3)*256+tid;      widx=2; }
  float vv = 0.f;
  if(c < C){
    for(int o=0;o<O;o+=4){
      vv += w[(o+0)*C+c]*u[o+0] + w[(o+1)*C+c]*u[o+1]
          + w[(o+2)*C+c]*u[o+2] + w[(o+3)*C+c]*u[o+3];
    }
    v_all[off + c] = vv;
  }
  float ps = (c < C) ? vv*vv : 0.f;
  float tot = block_reduce_sum(ps, red);
  if(tid==0) atomicAdd(&ss[widx], tot);
}

// ---------- SN pass 2 ----------
__global__ __launch_bounds__(256)
void sn_pass2(const float* __restrict__ w1, const float* __restrict__ w2,
              const float* __restrict__ w3, const float* __restrict__ v_all,
              float* __restrict__ Sun){
  int b = blockIdx.x, tid = threadIdx.x;
  int lane = tid & 63, wv = tid >> 6;
  const float* w; int C, off, o, widx;
  if(b < 16){ w=w1; C=15;   off=0;   o=b*4+wv;      widx=0; }
  else if(b < 48){ w=w2; C=448; off=16;  o=(b-16)*4+wv; widx=1; }
  else { w=w3; C=1152; off=464; o=(b-48)*4+wv;          widx=2; }
  float t = 0.f;
  for(int c=lane; c<C; c+=64) t += w[o*C+c]*v_all[off+c];
#pragma unroll
  for(int s=32; s>0; s>>=1) t += __shfl_down(t, s, 64);
  if(lane==0) atomicAdd(&Sun[widx], t*t);
}

__global__ void sn_final(const float* __restrict__ ss, const float* __restrict__ Sun,
                         float* __restrict__ scale){
  int tid = threadIdx.x;
  if(tid < 3){
    float inv = 1.f/(sqrtf(ss[tid])+1e-12f);
    float S = Sun[tid]*inv*inv;
    scale[tid] = (sqrtf(S)+1e-12f)/S;
  }
}

// ---------- weight prep: w1 padded; w2 plain; w3 K-PERMUTED (k' = r*128 + i) ----------
__global__ void wprep_kernel(const float* __restrict__ w1, const float* __restrict__ w2,
                             const float* __restrict__ w3, const float* __restrict__ scale,
                             unsigned short* __restrict__ w1p, unsigned short* __restrict__ w2bf,
                             unsigned short* __restrict__ w3p){
  int idx = blockIdx.x*256 + threadIdx.x;
  float s1 = scale[0], s2 = scale[1], s3 = scale[2];
  if(idx < C1N*32){
    int o = idx >> 5, kk = idx & 31;
    w1p[idx] = (kk < 15) ? f2bf(w1[o*15+kk]*s1) : 0;
  }
  if(idx < C2N*448)   w2bf[idx] = f2bf(w2[idx]*s2);
  if(idx < C3N*1152){
    int o = idx / 1152, k2 = idx - o*1152;
    int r = k2 >> 7, i = k2 & 127;
    w3p[idx] = f2bf(w3[o*1152 + i*9 + r]*s3);
  }
}

// ---------- fused conv1+conv2 MFMA, t-split 2 ways; writes y2t[n][t][ch] ----------
// grid (NB, 2): tile0 -> t 0..95, tile1 -> t 96..160
__global__ __launch_bounds__(256, 4)
void conv12_mfma(const float* __restrict__ ecg, const unsigned short* __restrict__ w1p,
                 const float* __restrict__ b1, const unsigned short* __restrict__ w2bf,
                 const float* __restrict__ b2, unsigned short* __restrict__ y2t){
  __shared__ unsigned short ysw[C1N*208];    // 26624 B — y1 window; reused as trans (96*136=26112 B)
  __shared__ unsigned short scratch[7168];   // 14336 B — B1 (phase1) / As+Bs (phase2)
  unsigned short* B1 = scratch;              // 208*32
  unsigned short* As = scratch;              // 128*32
  unsigned short* Bs = scratch + C2N*32;     // 96*32
  int n = blockIdx.x, tile = blockIdx.y, tid = threadIdx.x;
  int lane = tid & 63, w = tid >> 6;
  int c0    = tile ? 189 : 0;
  int tbase = tile ? 96  : 0;
  int D     = tile ? 0   : -3;    // = 2*tbase - 3 - c0

  // ---- phase 1a: build conv1 im2col B1[t'][kk] from global ecg ----
  const float* eb = ecg + (size_t)n*LIN*NLEADS;
#pragma unroll
  for(int q=0;q<26;q++){
    int e = q*256 + tid;          // t'*32+kk, t'<208
    int tp = e >> 5, kk = e & 31;
    unsigned short v = 0;
    if(kk < 15){
      int i = kk/5, r = kk - i*5;
      int p = 2*(c0 + tp) - 4 + r;
      if((unsigned)p < (unsigned)LIN) v = f2bf(eb[p*NLEADS + i]);
    }
    B1[tp*32 + kk] = v;
  }
  __syncthreads();

  // ---- phase 1b: conv1 MFMA in two halves ----
  {
    short8 a1 = *(const short8*)(w1p + ((w*16 + (lane&15))<<5) + (lane>>4)*8);
    f32x4 zero = {0.f,0.f,0.f,0.f};
#pragma unroll
    for(int half=0; half<2; half++){
      int nt0 = half*7, ntc = half ? 6 : 7;
      f32x4 c1[7];
      for(int j=0;j<ntc;j++){
        short8 b = *(const short8*)(B1 + (((nt0+j)*16 + (lane&15))<<5) + (lane>>4)*8);
        c1[j] = __builtin_amdgcn_mfma_f32_16x16x32_bf16(a1, b, zero, 0, 0, 0);
      }
#pragma unroll
      for(int reg=0;reg<4;reg++){
        int o = w*16 + (lane>>4)*4 + reg;
        float bias = b1[o];
        for(int j=0;j<ntc;j++){
          int tp = (nt0+j)*16 + (lane&15);
          int tc = c0 + tp;
          float v = 0.f;
          if(tc < L1O){
            v = c1[j][reg] + bias;
            v = v>=0.f ? v : 0.2f*v;
          }
          ysw[o*208 + tp] = (tc < L1O) ? f2bf(v) : (unsigned short)0;
        }
      }
    }
  }

  // ---- phase 2: conv2 K-loop over window ----
  f32x4 zero = {0.f,0.f,0.f,0.f};
  f32x4 acc[2][6];
#pragma unroll
  for(int i=0;i<2;i++)
#pragma unroll
    for(int j=0;j<6;j++) acc[i][j] = zero;

  for(int ck=0; ck<14; ck++){
    int kc = ck*32;
    __syncthreads();
    {
      const char* wb = (const char*)w2bf;
      uint4* dst = (uint4*)As;
#pragma unroll
      for(int q=0;q<2;q++){
        int f = q*256 + tid;
        int row = f >> 2, col = f & 3;
        dst[f] = *(const uint4*)(wb + row*896 + kc*2 + col*16);
      }
    }
#pragma unroll
    for(int q=0;q<12;q++){
      int e = q*256 + tid;            // 96*32 = 3072
      int tt = e >> 5, kk = e & 31;
      int k = kc + kk;
      int i = k / 7;
      int r = k - i*7;
      int col = 2*tt + r + D;
      unsigned short v = 0;
      if((unsigned)col < 208u) v = ysw[i*208 + col];
      Bs[tt*32 + kk] = v;
    }
    __syncthreads();
    short8 a[2], b[6];
#pragma unroll
    for(int mm=0;mm<2;mm++)
      a[mm] = *(const short8*)(As + ((w*2+mm)*16 + (lane&15))*32 + (lane>>4)*8);
#pragma unroll
    for(int nt=0;nt<6;nt++)
      b[nt] = *(const short8*)(Bs + (nt*16 + (lane&15))*32 + (lane>>4)*8);
#pragma unroll
    for(int mm=0;mm<2;mm++)
#pragma unroll
      for(int nt=0;nt<6;nt++)
        acc[mm][nt] = __builtin_amdgcn_mfma_f32_16x16x32_bf16(a[mm], b[nt], acc[mm][nt], 0, 0, 0);
  }

  // ---- epilogue: bias+leaky -> trans[tloc][o] (LDS) -> coalesced y2t[n][t][o] ----
  unsigned short* trans = ysw;   // safe: all ysw reads done at final inner barrier
#pragma unroll
  for(int mm=0;mm<2;mm++){
#pragma unroll
    for(int reg=0;reg<4;reg++){
      int o = (w*2+mm)*16 + (lane>>4)*4 + reg;
      float bias = b2[o];
#pragma unroll
      for(int nt=0;nt<6;nt++){
        int tl = nt*16 + (lane&15);
        int t = tbase + tl;
        if(t < L2O){
          float v = acc[mm][nt][reg] + bias;
          v = v>=0.f ? v : 0.2f*v;
          trans[tl*136 + o] = f2bf(v);
        }
      }
    }
  }
  __syncthreads();
  {
    int rows = tile ? 65 : 96;
    uint4* dstg = (uint4*)(y2t + (size_t)n*20608 + tbase*128);
#pragma unroll
    for(int q=0;q<6;q++){
      int f = q*256 + tid;
      int row = f >> 4, c8 = f & 15;
      if(row < rows)
        dstg[row*16 + c8] = *(const uint4*)(trans + row*136 + c8*8);
    }
  }
}

// ---------- conv3 MFMA, K-permuted, barrier-free K-loop ----------
// grid (NB): M=256, N=80(79 valid), K=1152 (k' = r*128+i). B-frags direct from
// parity-split y2t slab in LDS; A-frags streamed from global w3p with prefetch.
__global__ __launch_bounds__(256, 2)
void conv3_mfma(const unsigned short* __restrict__ y2t, const unsigned short* __restrict__ w3p,
                const float* __restrict__ b3, unsigned short* __restrict__ flatbf){
  __shared__ unsigned short lds[22712];  // even slab 84*136 @0; odd slab 83*136 @11424
  int n = blockIdx.x, tid = threadIdx.x;
  int lane = tid & 63, w = tid >> 6;

  // zero pad rows (conv boundary + overread rows)
  if(tid < 136){
    lds[tid] = 0;                       // even row 0   (t' = -2)
    lds[82*136 + tid] = 0;              // even row 82  (t' = 162)
    lds[83*136 + tid] = 0;              // even row 83  (overread)
    lds[11424 + tid] = 0;               // odd  row 0   (t' = -1)
    lds[11424 + 81*136 + tid] = 0;      // odd  row 81  (t' = 161)
    lds[11424 + 82*136 + tid] = 0;      // odd  row 82  (overread)
  }
  // stage y2t[n] rows: g even -> even[g/2+1], g odd -> odd[(g+1)/2]
  {
    const uint4* src = (const uint4*)(y2t + (size_t)n*20608);
#pragma unroll
    for(int q=0;q<11;q++){
      int f = q*256 + tid;
      if(f < 2576){
        int g = f >> 4, c8 = f & 15;
        int sub = g >> 1, p = g & 1;
        *(uint4*)(lds + (p ? 11424 : 0) + (sub+1)*136 + c8*8) = src[(size_t)g*16 + c8];
      }
    }
  }

  f32x4 zero = {0.f,0.f,0.f,0.f};
  f32x4 acc[4][5];
#pragma unroll
  for(int i=0;i<4;i++)
#pragma unroll
    for(int j=0;j<5;j++) acc[i][j] = zero;

  // A-frag base: row o = w*64 + mm*16 + (lane&15), cols ck*32 + (lane>>4)*8
  const unsigned short* wbase = w3p + ((size_t)(w*64) + (lane&15))*1152 + (lane>>4)*8;
  short8 a_cur[4];
#pragma unroll
  for(int mm=0;mm<4;mm++)
    a_cur[mm] = *(const short8*)(wbase + mm*16*1152);
  __syncthreads();

  for(int ck=0; ck<36; ck++){
    short8 a_nxt[4];
    if(ck < 35){
      int kc = (ck+1)*32;
#pragma unroll
      for(int mm=0;mm<4;mm++)
        a_nxt[mm] = *(const short8*)(wbase + mm*16*1152 + kc);
    }
    int r = ck >> 2, i0 = (ck & 3) * 32;
    int cbase = ((r & 1) ? 11424 : 0) + (r >> 1)*136 + i0 + (lane>>4)*8;
    short8 b[5];
#pragma unroll
    for(int nt=0;nt<5;nt++){
      int t = nt*16 + (lane&15);
      b[nt] = *(const short8*)(lds + cbase + t*136);   // subrow = t + (r>>1)
    }
#pragma unroll
    for(int mm=0;mm<4;mm++)
#pragma unroll
      for(int nt=0;nt<5;nt++)
        acc[mm][nt] = __builtin_amdgcn_mfma_f32_16x16x32_bf16(a_cur[mm], b[nt], acc[mm][nt], 0, 0, 0);
    if(ck < 35){
#pragma unroll
      for(int mm=0;mm<4;mm++) a_cur[mm] = a_nxt[mm];
    }
  }
#pragma unroll
  for(int mm=0;mm<4;mm++){
#pragma unroll
    for(int reg=0;reg<4;reg++){
      int o = w*64 + mm*16 + (lane>>4)*4 + reg;
      float bias = b3[o];
#pragma unroll
      for(int nt=0;nt<5;nt++){
        int t = nt*16 + (lane&15);
        if(t < L3O){
          float v = acc[mm][nt][reg] + bias;
          v = v>=0.f ? v : 0.2f*v;
          flatbf[(size_t)n*FLATSZ + o*L3O + t] = f2bf(v);
        }
      }
    }
  }
}

// ---------- transpose + bf16: mbwT[n][k] ----------
__global__ __launch_bounds__(256)
void mbw_transpose(const float* __restrict__ mbw, unsigned short* __restrict__ mbwT){
  __shared__ unsigned short tile[32][36];
  int k0 = blockIdx.x*32, n0 = blockIdx.y*32, tid = threadIdx.x;
  int r = tid >> 3, c4 = (tid & 7) * 4;
  int nbase = n0 + c4;
  if(nbase + 3 < 500){
    float4 v = *(const float4*)(mbw + (size_t)(k0+r)*500 + nbase);
    tile[r][c4+0] = f2bf(v.x);
    tile[r][c4+1] = f2bf(v.y);
    tile[r][c4+2] = f2bf(v.z);
    tile[r][c4+3] = f2bf(v.w);
  } else {
#pragma unroll
    for(int j=0;j<4;j++){
      int nn = nbase + j;
      float v = (nn < 500) ? mbw[(size_t)(k0+r)*500 + nn] : 0.f;
      tile[r][c4+j] = f2bf(v);
    }
  }
  __syncthreads();
  int nl = tid >> 3, kq = (tid & 7) * 4;
  unsigned short t0 = tile[kq+0][nl], t1 = tile[kq+1][nl];
  unsigned short t2 = tile[kq+2][nl], t3 = tile[kq+3][nl];
  uint2 p;
  p.x = (unsigned)t0 | ((unsigned)t1 << 16);
  p.y = (unsigned)t2 | ((unsigned)t3 << 16);
  *(uint2*)(mbwT + (size_t)(n0+nl)*FLATSZ + k0 + kq) = p;
}

// ---------- split-K MFMA GEMM ----------
__global__ __launch_bounds__(256)
void mb_gemm_mfma(const unsigned short* __restrict__ flatbf, const unsigned short* __restrict__ mbwT,
                  float* __restrict__ part){
  __shared__ unsigned short As[64*32];
  __shared__ unsigned short Bs[64*32];
  int tid = threadIdx.x;
  int lane = tid & 63, w = tid >> 6;
  int m0 = blockIdx.x*64, n0 = blockIdx.y*64, bz = blockIdx.z;
  int t_start = bz*39 + (bz<8 ? bz : 8);
  int t_count = 39 + (bz<8 ? 1 : 0);
  int k0 = t_start*32;
  f32x4 zero = {0.f,0.f,0.f,0.f};
  f32x4 acc[4];
#pragma unroll
  for(int i=0;i<4;i++) acc[i] = zero;
  int arow = tid >> 2, acol = (tid & 3) * 8;
  for(int t=0; t<t_count; t++, k0+=32){
    __syncthreads();
    ((uint4*)As)[tid] = *(const uint4*)(flatbf + (size_t)(m0+arow)*FLATSZ + k0 + acol);
    ((uint4*)Bs)[tid] = *(const uint4*)(mbwT  + (size_t)(n0+arow)*FLATSZ + k0 + acol);
    __syncthreads();
    short8 a = *(const short8*)(As + (w*16 + (lane&15))*32 + (lane>>4)*8);
#pragma unroll
    for(int nt=0;nt<4;nt++){
      short8 b = *(const short8*)(Bs + (nt*16 + (lane&15))*32 + (lane>>4)*8);
      acc[nt] = __builtin_amdgcn_mfma_f32_16x16x32_bf16(a, b, acc[nt], 0, 0, 0);
    }
  }
  float* po = part + (size_t)bz*NB*500;
#pragma unroll
  for(int nt=0;nt<4;nt++){
#pragma unroll
    for(int reg=0;reg<4;reg++){
      int m = m0 + w*16 + (lane>>4)*4 + reg;
      int c = n0 + nt*16 + (lane&15);
      if(c < 500) po[(size_t)m*500 + c] = acc[nt][reg];
    }
  }
}

// ---------- reduce partials -> actT[c][n] ----------
__global__ void mb_reduce_kernel(const float* __restrict__ part, float* __restrict__ actT){
  int idx = blockIdx.x*256 + threadIdx.x;   // n*500+c
  float s = 0.f;
#pragma unroll
  for(int z=0;z<SPLITK;z++) s += part[(size_t)z*NB*500 + idx];
  int n = idx/500, c = idx - n*500;
  actT[(size_t)c*NB + n] = s;
}

// ---------- minibatch features ----------
__global__ __launch_bounds__(256)
void feats_kernel(const float* __restrict__ actT, float* __restrict__ feats){
  __shared__ float ash[4][50];
  __shared__ float pred[4][4];
  int i0 = blockIdx.x*4, k0 = blockIdx.y*10;
  int tid = threadIdx.x, lane = tid & 63, wv = tid >> 6;
  if(tid < 200){
    int ii = tid/50, c = tid - ii*50;
    ash[ii][c] = actT[(size_t)(k0*5+c)*NB + i0 + ii];
  }
  __syncthreads();
  const float LOG2E = 1.4426950408889634f;
  int j1 = tid, j2 = tid + 256;
  for(int kk=0; kk<10; kk++){
    const float* r0 = actT + (size_t)(k0+kk)*5*NB;
    float xa0=r0[j1], xa1=r0[NB+j1], xa2=r0[2*NB+j1], xa3=r0[3*NB+j1], xa4=r0[4*NB+j1];
    float xb0=r0[j2], xb1=r0[NB+j2], xb2=r0[2*NB+j2], xb3=r0[3*NB+j2], xb4=r0[4*NB+j2];
    float f[4];
#pragma unroll
    for(int ii=0; ii<4; ii++){
      float a0=ash[ii][kk*5+0], a1=ash[ii][kk*5+1], a2=ash[ii][kk*5+2],
            a3=ash[ii][kk*5+3], a4=ash[ii][kk*5+4];
      float la = fabsf(xa0-a0)+fabsf(xa1-a1)+fabsf(xa2-a2)+fabsf(xa3-a3)+fabsf(xa4-a4);
      float lb = fabsf(xb0-a0)+fabsf(xb1-a1)+fabsf(xb2-a2)+fabsf(xb3-a3)+fabsf(xb4-a4);
      f[ii] = exp2f(-LOG2E*la) + exp2f(-LOG2E*lb);
    }
#pragma unroll
    for(int ii=0; ii<4; ii++){
      float v = f[ii];
#pragma unroll
      for(int s=32; s>0; s>>=1) v += __shfl_down(v, s, 64);
      if(lane==0) pred[wv][ii] = v;
    }
    __syncthreads();
    if(tid < 4){
      float v = pred[0][tid] + pred[1][tid] + pred[2][tid] + pred[3][tid];
      feats[(size_t)(i0+tid)*NUMK + k0 + kk] = v;
    }
    __syncthreads();
  }
}

// ---------- final ----------
__global__ void final_kernel(const unsigned short* __restrict__ flatbf, const float* __restrict__ feats,
                             const int* __restrict__ condition, const float* __restrict__ emb,
                             const float* __restrict__ cond_w, const float* __restrict__ cond_b,
                             const float* __restrict__ fc_w, const float* __restrict__ fc_b,
                             float* __restrict__ out){
  __shared__ float red[4];
  int n = blockIdx.x, tid = threadIdx.x;
  float s = 0.f;
  const unsigned short* fr = flatbf + (size_t)n*FLATSZ;
  for(int q=tid; q<FLATSZ/8; q+=256){
    uint4 u = *(const uint4*)(fr + q*8);
    float4 wa = *(const float4*)(fc_w + q*8);
    float4 wb = *(const float4*)(fc_w + q*8 + 4);
    s += bf2f((unsigned short)(u.x & 0xffff))*wa.x + bf2f((unsigned short)(u.x >> 16))*wa.y
       + bf2f((unsigned short)(u.y & 0xffff))*wa.z + bf2f((unsigned short)(u.y >> 16))*wa.w
       + bf2f((unsigned short)(u.z & 0xffff))*wb.x + bf2f((unsigned short)(u.z >> 16))*wb.y
       + bf2f((unsigned short)(u.w & 0xffff))*wb.z + bf2f((unsigned short)(u.w >> 16))*wb.w;
  }
  for(int k=tid;k<NUMK;k+=256) s += feats[n*NUMK+k]*fc_w[FLATSZ+k];
  float ce = emb[condition[n]];
  for(int j=tid;j<50;j+=256) s += (ce*cond_w[j]+cond_b[j])*fc_w[FLATSZ+NUMK+j];
  s = block_reduce_sum(s, red);
  if(tid==0) out[n] = s + fc_b[0];
}

extern "C" void kernel_launch(void* const* d_in, const int* in_sizes, int n_in,
                              void* d_out, int out_size, void* d_ws, size_t ws_size,
                              hipStream_t stream) {
  const float* ecg   = (const float*)d_in[0];
  const int*   cond  = (const int*)  d_in[1];
  const float* w1    = (const float*)d_in[2];
  const float* b1    = (const float*)d_in[3];
  const float* u1    = (const float*)d_in[4];
  const float* w2    = (const float*)d_in[5];
  const float* b2    = (const float*)d_in[6];
  const float* u2    = (const float*)d_in[7];
  const float* w3    = (const float*)d_in[8];
  const float* b3    = (const float*)d_in[9];
  const float* u3    = (const float*)d_in[10];
  const float* emb   = (const float*)d_in[11];
  const float* condw = (const float*)d_in[12];
  const float* condb = (const float*)d_in[13];
  const float* mbw   = (const float*)d_in[14];
  const float* fcw   = (const float*)d_in[15];
  const float* fcb   = (const float*)d_in[16];

  float* ws = (float*)d_ws;
  float* scale = ws;                                      // 0..16
  float* ssbuf = ws + 16;
  float* Sunbuf= ws + 24;
  float* v_all = ws + 32;                                 // ends 1648
  unsigned short* w1p  = (unsigned short*)(ws + 1648);    // -> 2672
  unsigned short* w2bf = (unsigned short*)(ws + 2672);    // -> 31344
  unsigned short* w3p  = (unsigned short*)(ws + 31344);   // -> 178800
  unsigned short* y2t  = (unsigned short*)(ws + 178800);  // 512*161*128 sh = 5,275,648 f -> 5,454,448
  unsigned short* mbwT = (unsigned short*)(ws + 178800);  // overlays y2t (dead after conv3)
  float* part  = ws + 5454448;                            // 4,096,000 f -> 9,550,448
  float* actT  = ws + 9550448;                            // 256,000 f -> 9,806,448
  float* feats = ws + 9806448;                            // 51,200 f -> 9,857,648
  unsigned short* flatbf = (unsigned short*)(ws + 9857648); // 5,177,344 f -> ends 15,034,992

  hipMemsetAsync((char*)d_ws + 64, 0, 64, stream);   // zero ssbuf/Sunbuf
  sn_pass1<<<8, 256, 0, stream>>>(w1,u1,w2,u2,w3,u3, v_all, ssbuf);
  sn_pass2<<<112, 256, 0, stream>>>(w1,w2,w3, v_all, Sunbuf);
  sn_final<<<1, 64, 0, stream>>>(ssbuf, Sunbuf, scale);
  wprep_kernel<<<1152, 256, 0, stream>>>(w1, w2, w3, scale, w1p, w2bf, w3p);
  conv12_mfma<<<dim3(NB,2), 256, 0, stream>>>(ecg, w1p, b1, w2bf, b2, y2t);
  conv3_mfma<<<NB, 256, 0, stream>>>(y2t, w3p, b3, flatbf);
  mbw_transpose<<<dim3(632,16), 256, 0, stream>>>(mbw, mbwT);
  mb_gemm_mfma<<<dim3(8,8,SPLITK), 256, 0, stream>>>(flatbf, mbwT, part);
  mb_reduce_kernel<<<1000, 256, 0, stream>>>(part, actT);
  feats_kernel<<<dim3(128,10), 256, 0, stream>>>(actT, feats);
  final_kernel<<<NB, 256, 0, stream>>>(flatbf, feats, cond, emb, condw, condb, fcw, fcb, (float*)d_out);
}

// Round 10
// 300.114 us; speedup vs baseline: 12.5355x; 1.0887x over previous
//
#include <hip/hip_runtime.h>
#include <math.h>

#define NB 512
#define LIN 640
#define NLEADS 3
#define L1O 322
#define L2O 161
#define L3O 79
#define C1N 64
#define C2N 128
#define C3N 256
#define FLATSZ 20224   // 256*79
#define NUMK 100
#define DIMK 5
#define SPLITK 16

typedef __attribute__((ext_vector_type(8))) short short8;
typedef __attribute__((ext_vector_type(4))) float f32x4;

__device__ __forceinline__ unsigned short f2bf(float x){
  unsigned u = __builtin_bit_cast(unsigned, x);
  unsigned r = u + 0x7FFFu + ((u >> 16) & 1u);
  return (unsigned short)(r >> 16);
}
__device__ __forceinline__ float bf2f(unsigned short x){
  unsigned u = ((unsigned)x) << 16;
  return __builtin_bit_cast(float, u);
}

__device__ __forceinline__ float block_reduce_sum(float val, float* red){
#pragma unroll
  for(int off=32; off>0; off>>=1) val += __shfl_down(val, off, 64);
  int lane = threadIdx.x & 63;
  int wv = threadIdx.x >> 6;
  if(lane==0) red[wv] = val;
  __syncthreads();
  int nw = blockDim.x >> 6;
  float r = red[0];
  for(int i=1;i<nw;i++) r += red[i];
  __syncthreads();
  return r;
}

// ---------- SN pass 1 ----------
__global__ __launch_bounds__(256)
void sn_pass1(const float* __restrict__ w1, const float* __restrict__ u1,
              const float* __restrict__ w2, const float* __restrict__ u2,
              const float* __restrict__ w3, const float* __restrict__ u3,
              float* __restrict__ v_all, float* __restrict__ ss){
  __shared__ float red[4];
  int b = blockIdx.x, tid = threadIdx.x;
  const float* w; const float* u; int O, C, off, c, widx;
  if(b==0){ w=w1; u=u1; O=64;  C=15;   off=0;   c=tid;            widx=0; }
  else if(b<3){ w=w2; u=u2; O=128; C=448; off=16;  c=(b-1)*256+tid; widx=1; }
  else { w=w3; u=u3; O=256; C=1152; off=464; c=(b-3)*256+tid;      widx=2; }
  float vv = 0.f;
  if(c < C){
    for(int o=0;o<O;o+=4){
      vv += w[(o+0)*C+c]*u[o+0] + w[(o+1)*C+c]*u[o+1]
          + w[(o+2)*C+c]*u[o+2] + w[(o+3)*C+c]*u[o+3];
    }
    v_all[off + c] = vv;
  }
  float ps = (c < C) ? vv*vv : 0.f;
  float tot = block_reduce_sum(ps, red);
  if(tid==0) atomicAdd(&ss[widx], tot);
}

// ---------- SN pass 2 ----------
__global__ __launch_bounds__(256)
void sn_pass2(const float* __restrict__ w1, const float* __restrict__ w2,
              const float* __restrict__ w3, const float* __restrict__ v_all,
              float* __restrict__ Sun){
  int b = blockIdx.x, tid = threadIdx.x;
  int lane = tid & 63, wv = tid >> 6;
  const float* w; int C, off, o, widx;
  if(b < 16){ w=w1; C=15;   off=0;   o=b*4+wv;      widx=0; }
  else if(b < 48){ w=w2; C=448; off=16;  o=(b-16)*4+wv; widx=1; }
  else { w=w3; C=1152; off=464; o=(b-48)*4+wv;          widx=2; }
  float t = 0.f;
  for(int c=lane; c<C; c+=64) t += w[o*C+c]*v_all[off+c];
#pragma unroll
  for(int s=32; s>0; s>>=1) t += __shfl_down(t, s, 64);
  if(lane==0) atomicAdd(&Sun[widx], t*t);
}

__global__ void sn_final(const float* __restrict__ ss, const float* __restrict__ Sun,
                         float* __restrict__ scale){
  int tid = threadIdx.x;
  if(tid < 3){
    float inv = 1.f/(sqrtf(ss[tid])+1e-12f);
    float S = Sun[tid]*inv*inv;
    scale[tid] = (sqrtf(S)+1e-12f)/S;
  }
}

// ---------- weight prep: w1 padded; w2 K-PERMUTED (k'=r*64+i); w3 K-PERMUTED (k'=r*128+i) ----------
__global__ void wprep_kernel(const float* __restrict__ w1, const float* __restrict__ w2,
                             const float* __restrict__ w3, const float* __restrict__ scale,
                             unsigned short* __restrict__ w1p, unsigned short* __restrict__ w2p,
                             unsigned short* __restrict__ w3p){
  int idx = blockIdx.x*256 + threadIdx.x;
  float s1 = scale[0], s2 = scale[1], s3 = scale[2];
  if(idx < C1N*32){
    int o = idx >> 5, kk = idx & 31;
    w1p[idx] = (kk < 15) ? f2bf(w1[o*15+kk]*s1) : 0;
  }
  if(idx < C2N*448){
    int o = idx / 448, k2 = idx - o*448;
    int r = k2 >> 6, i = k2 & 63;
    w2p[idx] = f2bf(w2[o*448 + i*7 + r]*s2);
  }
  if(idx < C3N*1152){
    int o = idx / 1152, k2 = idx - o*1152;
    int r = k2 >> 7, i = k2 & 127;
    w3p[idx] = f2bf(w3[o*1152 + i*9 + r]*s3);
  }
}

// ---------- fused conv1+conv2 MFMA, t-split 2 ways; K-permuted conv2, barrier-lite ----------
// grid (NB, 2): tile0 -> t2 0..95, tile1 -> t2 96..160
// y1 stored time-major in parity slabs: slab[t1&1][(t1>>1)+suboff][ch], row stride 68
__global__ __launch_bounds__(256, 4)
void conv12_mfma(const float* __restrict__ ecg, const unsigned short* __restrict__ w1p,
                 const float* __restrict__ b1, const unsigned short* __restrict__ w2p,
                 const float* __restrict__ b2, unsigned short* __restrict__ y2t){
  __shared__ unsigned short slabs[13600];   // even [100][68] @0, odd @6800; reused as trans[96][136]
  __shared__ unsigned short B1s[6656];      // 208*32 — conv1 im2col
  int n = blockIdx.x, tile = blockIdx.y, tid = threadIdx.x;
  int lane = tid & 63, w = tid >> 6;
  int c0    = tile ? 189 : 0;
  int tbase = tile ? 96  : 0;
  int suboff= tile ? -94 : 2;

  // zero slabs (pre-pads conv boundaries): 1700 uint4
  {
    uint4 z = {0u,0u,0u,0u};
    uint4* zd = (uint4*)slabs;
#pragma unroll
    for(int q=0;q<7;q++){
      int f = q*256 + tid;
      if(f < 1700) zd[f] = z;
    }
  }
  // build conv1 im2col B1s[t'][kk]
  const float* eb = ecg + (size_t)n*LIN*NLEADS;
#pragma unroll
  for(int q=0;q<26;q++){
    int e = q*256 + tid;
    int tp = e >> 5, kk = e & 31;
    unsigned short v = 0;
    if(kk < 15){
      int i = kk/5, r = kk - i*5;
      int p = 2*(c0 + tp) - 4 + r;
      if((unsigned)p < (unsigned)LIN) v = f2bf(eb[p*NLEADS + i]);
    }
    B1s[tp*32 + kk] = v;
  }
  __syncthreads();

  // conv1 MFMA -> parity slabs
  // BUG FIX (r9): guard sub < 100 — tile0's t1 >= 196 (sub >= 100) isn't needed by
  // conv2 (max needed t1 = 193) and overflowed the even slab into the odd slab's
  // zero-pad/early rows, corrupting small-t2 outputs.
  {
    short8 a1 = *(const short8*)(w1p + ((w*16 + (lane&15))<<5) + (lane>>4)*8);
    f32x4 zero = {0.f,0.f,0.f,0.f};
#pragma unroll
    for(int half=0; half<2; half++){
      int nt0 = half*7, ntc = half ? 6 : 7;
      f32x4 c1[7];
      for(int j=0;j<ntc;j++){
        short8 b = *(const short8*)(B1s + (((nt0+j)*16 + (lane&15))<<5) + (lane>>4)*8);
        c1[j] = __builtin_amdgcn_mfma_f32_16x16x32_bf16(a1, b, zero, 0, 0, 0);
      }
#pragma unroll
      for(int reg=0;reg<4;reg++){
        int o = w*16 + (lane>>4)*4 + reg;
        float bias = b1[o];
        for(int j=0;j<ntc;j++){
          int tp = (nt0+j)*16 + (lane&15);
          int t1 = c0 + tp;
          int sub = (t1>>1) + suboff;
          if(t1 < L1O && sub < 100){
            float v = c1[j][reg] + bias;
            v = v>=0.f ? v : 0.2f*v;
            slabs[((t1&1)?6800:0) + sub*68 + o] = f2bf(v);
          }
        }
      }
    }
  }
  __syncthreads();

  // conv2 K-loop: barrier-free. A from global w2p (prefetch), B = direct b128 from slabs.
  f32x4 zero = {0.f,0.f,0.f,0.f};
  f32x4 acc[2][6];
#pragma unroll
  for(int i=0;i<2;i++)
#pragma unroll
    for(int j=0;j<6;j++) acc[i][j] = zero;

  const unsigned short* w2base = w2p + ((size_t)(w*2*16 + (lane&15)))*448 + (lane>>4)*8;
  short8 a_cur[2];
  a_cur[0] = *(const short8*)(w2base);
  a_cur[1] = *(const short8*)(w2base + 16*448);

  for(int ck=0; ck<14; ck++){
    short8 a_nxt[2];
    if(ck < 13){
      a_nxt[0] = *(const short8*)(w2base + (ck+1)*32);
      a_nxt[1] = *(const short8*)(w2base + 16*448 + (ck+1)*32);
    }
    int r = ck >> 1, i0 = (ck & 1)*32;
    int p = (r+1) & 1;                 // t1 parity for this tap
    int m = ((r-3) - p) >> 1;          // row offset within slab
    int base = (p?6800:0) + (m+2 + (lane&15))*68 + i0 + (lane>>4)*8;
    short8 b[6];
#pragma unroll
    for(int nt=0;nt<6;nt++)
      b[nt] = *(const short8*)(slabs + base + nt*16*68);
#pragma unroll
    for(int mm=0;mm<2;mm++)
#pragma unroll
      for(int nt=0;nt<6;nt++)
        acc[mm][nt] = __builtin_amdgcn_mfma_f32_16x16x32_bf16(a_cur[mm], b[nt], acc[mm][nt], 0, 0, 0);
    if(ck < 13){ a_cur[0] = a_nxt[0]; a_cur[1] = a_nxt[1]; }
  }

  // epilogue: bias+leaky -> trans[tl][o] (reuse slabs) -> coalesced y2t[n][t][o]
  __syncthreads();
  unsigned short* trans = slabs;
#pragma unroll
  for(int mm=0;mm<2;mm++){
#pragma unroll
    for(int reg=0;reg<4;reg++){
      int o = (w*2+mm)*16 + (lane>>4)*4 + reg;
      float bias = b2[o];
#pragma unroll
      for(int nt=0;nt<6;nt++){
        int tl = nt*16 + (lane&15);
        int t = tbase + tl;
        if(t < L2O){
          float v = acc[mm][nt][reg] + bias;
          v = v>=0.f ? v : 0.2f*v;
          trans[tl*136 + o] = f2bf(v);
        }
      }
    }
  }
  __syncthreads();
  {
    int rows = tile ? 65 : 96;
    uint4* dstg = (uint4*)(y2t + (size_t)n*20608 + tbase*128);
#pragma unroll
    for(int q=0;q<6;q++){
      int f = q*256 + tid;
      int row = f >> 4, c8 = f & 15;
      if(row < rows)
        dstg[row*16 + c8] = *(const uint4*)(trans + row*136 + c8*8);
    }
  }
}

// ---------- conv3 MFMA, K-permuted, barrier-free K-loop ----------
__global__ __launch_bounds__(256, 2)
void conv3_mfma(const unsigned short* __restrict__ y2t, const unsigned short* __restrict__ w3p,
                const float* __restrict__ b3, unsigned short* __restrict__ flatbf){
  __shared__ unsigned short lds[22712];  // even slab 84*136 @0; odd slab 83*136 @11424
  int n = blockIdx.x, tid = threadIdx.x;
  int lane = tid & 63, w = tid >> 6;

  if(tid < 136){
    lds[tid] = 0;
    lds[82*136 + tid] = 0;
    lds[83*136 + tid] = 0;
    lds[11424 + tid] = 0;
    lds[11424 + 81*136 + tid] = 0;
    lds[11424 + 82*136 + tid] = 0;
  }
  {
    const uint4* src = (const uint4*)(y2t + (size_t)n*20608);
#pragma unroll
    for(int q=0;q<11;q++){
      int f = q*256 + tid;
      if(f < 2576){
        int g = f >> 4, c8 = f & 15;
        int sub = g >> 1, p = g & 1;
        *(uint4*)(lds + (p ? 11424 : 0) + (sub+1)*136 + c8*8) = src[(size_t)g*16 + c8];
      }
    }
  }

  f32x4 zero = {0.f,0.f,0.f,0.f};
  f32x4 acc[4][5];
#pragma unroll
  for(int i=0;i<4;i++)
#pragma unroll
    for(int j=0;j<5;j++) acc[i][j] = zero;

  const unsigned short* wbase = w3p + ((size_t)(w*64) + (lane&15))*1152 + (lane>>4)*8;
  short8 a_cur[4];
#pragma unroll
  for(int mm=0;mm<4;mm++)
    a_cur[mm] = *(const short8*)(wbase + mm*16*1152);
  __syncthreads();

  for(int ck=0; ck<36; ck++){
    short8 a_nxt[4];
    if(ck < 35){
      int kc = (ck+1)*32;
#pragma unroll
      for(int mm=0;mm<4;mm++)
        a_nxt[mm] = *(const short8*)(wbase + mm*16*1152 + kc);
    }
    int r = ck >> 2, i0 = (ck & 3) * 32;
    int cbase = ((r & 1) ? 11424 : 0) + (r >> 1)*136 + i0 + (lane>>4)*8;
    short8 b[5];
#pragma unroll
    for(int nt=0;nt<5;nt++){
      int t = nt*16 + (lane&15);
      b[nt] = *(const short8*)(lds + cbase + t*136);
    }
#pragma unroll
    for(int mm=0;mm<4;mm++)
#pragma unroll
      for(int nt=0;nt<5;nt++)
        acc[mm][nt] = __builtin_amdgcn_mfma_f32_16x16x32_bf16(a_cur[mm], b[nt], acc[mm][nt], 0, 0, 0);
    if(ck < 35){
#pragma unroll
      for(int mm=0;mm<4;mm++) a_cur[mm] = a_nxt[mm];
    }
  }
#pragma unroll
  for(int mm=0;mm<4;mm++){
#pragma unroll
    for(int reg=0;reg<4;reg++){
      int o = w*64 + mm*16 + (lane>>4)*4 + reg;
      float bias = b3[o];
#pragma unroll
      for(int nt=0;nt<5;nt++){
        int t = nt*16 + (lane&15);
        if(t < L3O){
          float v = acc[mm][nt][reg] + bias;
          v = v>=0.f ? v : 0.2f*v;
          flatbf[(size_t)n*FLATSZ + o*L3O + t] = f2bf(v);
        }
      }
    }
  }
}

// ---------- transpose + bf16: mbwT[n][k] ----------
__global__ __launch_bounds__(256)
void mbw_transpose(const float* __restrict__ mbw, unsigned short* __restrict__ mbwT){
  __shared__ unsigned short tile[32][36];
  int k0 = blockIdx.x*32, n0 = blockIdx.y*32, tid = threadIdx.x;
  int r = tid >> 3, c4 = (tid & 7) * 4;
  int nbase = n0 + c4;
  if(nbase + 3 < 500){
    float4 v = *(const float4*)(mbw + (size_t)(k0+r)*500 + nbase);
    tile[r][c4+0] = f2bf(v.x);
    tile[r][c4+1] = f2bf(v.y);
    tile[r][c4+2] = f2bf(v.z);
    tile[r][c4+3] = f2bf(v.w);
  } else {
#pragma unroll
    for(int j=0;j<4;j++){
      int nn = nbase + j;
      float v = (nn < 500) ? mbw[(size_t)(k0+r)*500 + nn] : 0.f;
      tile[r][c4+j] = f2bf(v);
    }
  }
  __syncthreads();
  int nl = tid >> 3, kq = (tid & 7) * 4;
  unsigned short t0 = tile[kq+0][nl], t1 = tile[kq+1][nl];
  unsigned short t2 = tile[kq+2][nl], t3 = tile[kq+3][nl];
  uint2 p;
  p.x = (unsigned)t0 | ((unsigned)t1 << 16);
  p.y = (unsigned)t2 | ((unsigned)t3 << 16);
  *(uint2*)(mbwT + (size_t)(n0+nl)*FLATSZ + k0 + kq) = p;
}

// ---------- split-K MFMA GEMM ----------
__global__ __launch_bounds__(256)
void mb_gemm_mfma(const unsigned short* __restrict__ flatbf, const unsigned short* __restrict__ mbwT,
                  float* __restrict__ part){
  __shared__ unsigned short As[64*32];
  __shared__ unsigned short Bs[64*32];
  int tid = threadIdx.x;
  int lane = tid & 63, w = tid >> 6;
  int m0 = blockIdx.x*64, n0 = blockIdx.y*64, bz = blockIdx.z;
  int t_start = bz*39 + (bz<8 ? bz : 8);
  int t_count = 39 + (bz<8 ? 1 : 0);
  int k0 = t_start*32;
  f32x4 zero = {0.f,0.f,0.f,0.f};
  f32x4 acc[4];
#pragma unroll
  for(int i=0;i<4;i++) acc[i] = zero;
  int arow = tid >> 2, acol = (tid & 3) * 8;
  for(int t=0; t<t_count; t++, k0+=32){
    __syncthreads();
    ((uint4*)As)[tid] = *(const uint4*)(flatbf + (size_t)(m0+arow)*FLATSZ + k0 + acol);
    ((uint4*)Bs)[tid] = *(const uint4*)(mbwT  + (size_t)(n0+arow)*FLATSZ + k0 + acol);
    __syncthreads();
    short8 a = *(const short8*)(As + (w*16 + (lane&15))*32 + (lane>>4)*8);
#pragma unroll
    for(int nt=0;nt<4;nt++){
      short8 b = *(const short8*)(Bs + (nt*16 + (lane&15))*32 + (lane>>4)*8);
      acc[nt] = __builtin_amdgcn_mfma_f32_16x16x32_bf16(a, b, acc[nt], 0, 0, 0);
    }
  }
  float* po = part + (size_t)bz*NB*500;
#pragma unroll
  for(int nt=0;nt<4;nt++){
#pragma unroll
    for(int reg=0;reg<4;reg++){
      int m = m0 + w*16 + (lane>>4)*4 + reg;
      int c = n0 + nt*16 + (lane&15);
      if(c < 500) po[(size_t)m*500 + c] = acc[nt][reg];
    }
  }
}

// ---------- reduce partials -> actT[c][n] ----------
__global__ void mb_reduce_kernel(const float* __restrict__ part, float* __restrict__ actT){
  int idx = blockIdx.x*256 + threadIdx.x;   // n*500+c
  float s = 0.f;
#pragma unroll
  for(int z=0;z<SPLITK;z++) s += part[(size_t)z*NB*500 + idx];
  int n = idx/500, c = idx - n*500;
  actT[(size_t)c*NB + n] = s;
}

// ---------- minibatch features ----------
__global__ __launch_bounds__(256)
void feats_kernel(const float* __restrict__ actT, float* __restrict__ feats){
  __shared__ float ash[4][50];
  __shared__ float pred[4][4];
  int i0 = blockIdx.x*4, k0 = blockIdx.y*10;
  int tid = threadIdx.x, lane = tid & 63, wv = tid >> 6;
  if(tid < 200){
    int ii = tid/50, c = tid - ii*50;
    ash[ii][c] = actT[(size_t)(k0*5+c)*NB + i0 + ii];
  }
  __syncthreads();
  const float LOG2E = 1.4426950408889634f;
  int j1 = tid, j2 = tid + 256;
  for(int kk=0; kk<10; kk++){
    const float* r0 = actT + (size_t)(k0+kk)*5*NB;
    float xa0=r0[j1], xa1=r0[NB+j1], xa2=r0[2*NB+j1], xa3=r0[3*NB+j1], xa4=r0[4*NB+j1];
    float xb0=r0[j2], xb1=r0[NB+j2], xb2=r0[2*NB+j2], xb3=r0[3*NB+j2], xb4=r0[4*NB+j2];
    float f[4];
#pragma unroll
    for(int ii=0; ii<4; ii++){
      float a0=ash[ii][kk*5+0], a1=ash[ii][kk*5+1], a2=ash[ii][kk*5+2],
            a3=ash[ii][kk*5+3], a4=ash[ii][kk*5+4];
      float la = fabsf(xa0-a0)+fabsf(xa1-a1)+fabsf(xa2-a2)+fabsf(xa3-a3)+fabsf(xa4-a4);
      float lb = fabsf(xb0-a0)+fabsf(xb1-a1)+fabsf(xb2-a2)+fabsf(xb3-a3)+fabsf(xb4-a4);
      f[ii] = exp2f(-LOG2E*la) + exp2f(-LOG2E*lb);
    }
#pragma unroll
    for(int ii=0; ii<4; ii++){
      float v = f[ii];
#pragma unroll
      for(int s=32; s>0; s>>=1) v += __shfl_down(v, s, 64);
      if(lane==0) pred[wv][ii] = v;
    }
    __syncthreads();
    if(tid < 4){
      float v = pred[0][tid] + pred[1][tid] + pred[2][tid] + pred[3][tid];
      feats[(size_t)(i0+tid)*NUMK + k0 + kk] = v;
    }
    __syncthreads();
  }
}

// ---------- final ----------
__global__ void final_kernel(const unsigned short* __restrict__ flatbf, const float* __restrict__ feats,
                             const int* __restrict__ condition, const float* __restrict__ emb,
                             const float* __restrict__ cond_w, const float* __restrict__ cond_b,
                             const float* __restrict__ fc_w, const float* __restrict__ fc_b,
                             float* __restrict__ out){
  __shared__ float red[4];
  int n = blockIdx.x, tid = threadIdx.x;
  float s = 0.f;
  const unsigned short* fr = flatbf + (size_t)n*FLATSZ;
  for(int q=tid; q<FLATSZ/8; q+=256){
    uint4 u = *(const uint4*)(fr + q*8);
    float4 wa = *(const float4*)(fc_w + q*8);
    float4 wb = *(const float4*)(fc_w + q*8 + 4);
    s += bf2f((unsigned short)(u.x & 0xffff))*wa.x + bf2f((unsigned short)(u.x >> 16))*wa.y
       + bf2f((unsigned short)(u.y & 0xffff))*wa.z + bf2f((unsigned short)(u.y >> 16))*wa.w
       + bf2f((unsigned short)(u.z & 0xffff))*wb.x + bf2f((unsigned short)(u.z >> 16))*wb.y
       + bf2f((unsigned short)(u.w & 0xffff))*wb.z + bf2f((unsigned short)(u.w >> 16))*wb.w;
  }
  for(int k=tid;k<NUMK;k+=256) s += feats[n*NUMK+k]*fc_w[FLATSZ+k];
  float ce = emb[condition[n]];
  for(int j=tid;j<50;j+=256) s += (ce*cond_w[j]+cond_b[j])*fc_w[FLATSZ+NUMK+j];
  s = block_reduce_sum(s, red);
  if(tid==0) out[n] = s + fc_b[0];
}

extern "C" void kernel_launch(void* const* d_in, const int* in_sizes, int n_in,
                              void* d_out, int out_size, void* d_ws, size_t ws_size,
                              hipStream_t stream) {
  const float* ecg   = (const float*)d_in[0];
  const int*   cond  = (const int*)  d_in[1];
  const float* w1    = (const float*)d_in[2];
  const float* b1    = (const float*)d_in[3];
  const float* u1    = (const float*)d_in[4];
  const float* w2    = (const float*)d_in[5];
  const float* b2    = (const float*)d_in[6];
  const float* u2    = (const float*)d_in[7];
  const float* w3    = (const float*)d_in[8];
  const float* b3    = (const float*)d_in[9];
  const float* u3    = (const float*)d_in[10];
  const float* emb   = (const float*)d_in[11];
  const float* condw = (const float*)d_in[12];
  const float* condb = (const float*)d_in[13];
  const float* mbw   = (const float*)d_in[14];
  const float* fcw   = (const float*)d_in[15];
  const float* fcb   = (const float*)d_in[16];

  float* ws = (float*)d_ws;
  float* scale = ws;                                      // 0..16
  float* ssbuf = ws + 16;
  float* Sunbuf= ws + 24;
  float* v_all = ws + 32;                                 // ends 1648
  unsigned short* w1p  = (unsigned short*)(ws + 1648);    // -> 2672
  unsigned short* w2p  = (unsigned short*)(ws + 2672);    // -> 31344
  unsigned short* w3p  = (unsigned short*)(ws + 31344);   // -> 178800
  unsigned short* y2t  = (unsigned short*)(ws + 178800);  // 5,275,648 f -> 5,454,448
  unsigned short* mbwT = (unsigned short*)(ws + 178800);  // overlays y2t (dead after conv3)
  float* part  = ws + 5454448;                            // 4,096,000 f -> 9,550,448
  float* actT  = ws + 9550448;                            // 256,000 f -> 9,806,448
  float* feats = ws + 9806448;                            // 51,200 f -> 9,857,648
  unsigned short* flatbf = (unsigned short*)(ws + 9857648); // 5,177,344 f -> ends 15,034,992

  hipMemsetAsync((char*)d_ws + 64, 0, 64, stream);   // zero ssbuf/Sunbuf
  sn_pass1<<<8, 256, 0, stream>>>(w1,u1,w2,u2,w3,u3, v_all, ssbuf);
  sn_pass2<<<112, 256, 0, stream>>>(w1,w2,w3, v_all, Sunbuf);
  sn_final<<<1, 64, 0, stream>>>(ssbuf, Sunbuf, scale);
  wprep_kernel<<<1152, 256, 0, stream>>>(w1, w2, w3, scale, w1p, w2p, w3p);
  conv12_mfma<<<dim3(NB,2), 256, 0, stream>>>(ecg, w1p, b1, w2p, b2, y2t);
  conv3_mfma<<<NB, 256, 0, stream>>>(y2t, w3p, b3, flatbf);
  mbw_transpose<<<dim3(632,16), 256, 0, stream>>>(mbw, mbwT);
  mb_gemm_mfma<<<dim3(8,8,SPLITK), 256, 0, stream>>>(flatbf, mbwT, part);
  mb_reduce_kernel<<<1000, 256, 0, stream>>>(part, actT);
  feats_kernel<<<dim3(128,10), 256, 0, stream>>>(actT, feats);
  final_kernel<<<NB, 256, 0, stream>>>(flatbf, feats, cond, emb, condw, condb, fcw, fcb, (float*)d_out);
}